// Round 6
// baseline (272.024 us; speedup 1.0000x reference)
//
#include <hip/hip_runtime.h>
#include <math.h>

// ---------------- dims ----------------
#define SQ 197           // tokens
#define DD 768           // hidden
#define NHH 12
#define DHH 64
#define BB_ 64           // batch
#define MTOK (BB_*SQ)    // 12608
#define MPATCH (BB_*196) // 12544
#define NOUT 1000
#define LNN (SQ*DD)      // 151296 elems per sample
#define SQP 256          // padded seq for vT

typedef unsigned short u16;
typedef __attribute__((ext_vector_type(8))) short bf16x8;
typedef __attribute__((ext_vector_type(4))) float f32x4;

__device__ __forceinline__ u16 f2bf(float x) {      // RNE f32->bf16
    unsigned u = __float_as_uint(x);
    u = (u + 0x7FFF + ((u >> 16) & 1)) >> 16;
    return (u16)u;
}
__device__ __forceinline__ float bf2f(u16 x) {
    return __uint_as_float(((unsigned)x) << 16);
}

// ---------------- pos emb (f64 for safety, tiny) ----------------
__global__ void pos_emb_kernel(float* __restrict__ pos) {
    int i = blockIdx.x * blockDim.x + threadIdx.x;
    if (i >= SQ * DD) return;
    int s = i / DD, d = i % DD;
    double e = (double)(d & ~1) / (double)DD;
    double ang = (double)s * pow(10000.0, -e);
    pos[i] = (d & 1) ? (float)cos(ang) : (float)sin(ang);
}

// ---------------- cls token row ----------------
__global__ void cls_kernel(const float* __restrict__ cls_tok,
                           const float* __restrict__ pos,
                           float* __restrict__ tokens) {
    int i = blockIdx.x * blockDim.x + threadIdx.x;
    if (i >= BB_ * DD) return;
    int b = i / DD, d = i % DD;
    tokens[(size_t)b * SQ * DD + d] = cls_tok[d] + pos[d];
}

// ---------------- f32 -> bf16 bulk convert (8 elems/thread) ----------------
__global__ __launch_bounds__(256) void conv_bf16_kernel(const float* __restrict__ in,
        u16* __restrict__ out, int n8) {
    int i = blockIdx.x * blockDim.x + threadIdx.x;
    if (i >= n8) return;
    float4 a = ((const float4*)in)[2*i];
    float4 b = ((const float4*)in)[2*i + 1];
    union { u16 u[8]; uint4 v; } r;
    r.u[0]=f2bf(a.x); r.u[1]=f2bf(a.y); r.u[2]=f2bf(a.z); r.u[3]=f2bf(a.w);
    r.u[4]=f2bf(b.x); r.u[5]=f2bf(b.y); r.u[6]=f2bf(b.z); r.u[7]=f2bf(b.w);
    ((uint4*)out)[i] = r.v;
}

// ---------------- 768x768 transpose + convert: out[n][k] = in[k][n] ----------------
__global__ __launch_bounds__(256) void transpose_bf16_kernel(const float* __restrict__ in,
        u16* __restrict__ out) {
    __shared__ float t[32][33];
    int bn = blockIdx.x * 32, bk = blockIdx.y * 32;
    int tx = threadIdx.x & 31;
#pragma unroll
    for (int r = 0; r < 4; ++r) {
        int kk = (threadIdx.x >> 5) * 4 + r;
        t[kk][tx] = in[(size_t)(bk + kk) * 768 + bn + tx];
    }
    __syncthreads();
#pragma unroll
    for (int r = 0; r < 4; ++r) {
        int nn = (threadIdx.x >> 5) * 4 + r;
        out[(size_t)(bn + nn) * 768 + bk + tx] = f2bf(t[tx][nn]);
    }
}

// ---------------- MFMA GEMM (embed): C[M,768] = A[M,768]bf16 * B, BT=[n][k] ----------------
__global__ __launch_bounds__(256) void gemm_mfma0(const u16* __restrict__ A,
        const u16* __restrict__ BT, const float* __restrict__ bias,
        const float* __restrict__ pos, float* __restrict__ outp, int M) {
    __shared__ u16 As[2][4096];   // [128 rows][32 k] bf16
    __shared__ u16 Bs[2][4096];
    const int tid = threadIdx.x;
    const int wv = tid >> 6, ln = tid & 63;
    const int m0 = blockIdx.x * 128, n0 = blockIdx.y * 128;
    const int wr = wv >> 1, wc = wv & 1;
    const int lrow = ln & 15, lk = ln >> 4;

    f32x4 acc[4][4];
#pragma unroll
    for (int i = 0; i < 4; ++i)
#pragma unroll
        for (int j = 0; j < 4; ++j) acc[i][j] = (f32x4){0.f, 0.f, 0.f, 0.f};

    auto stage = [&](const u16* __restrict__ src, int rowBase, int rowMax,
                     u16* lbase, int k0) {
#pragma unroll
        for (int rep = 0; rep < 2; ++rep) {
            int c = rep * 256 + wv * 64 + ln;
            int row = rowBase + (c >> 2);
            if (row > rowMax) row = rowMax;
            const void* g = (const char*)src + ((size_t)row * 768 + k0) * 2 + ((c & 3) << 4);
            void* l = (char*)lbase + rep * 4096 + wv * 1024;
            __builtin_amdgcn_global_load_lds(
                (const __attribute__((address_space(1))) unsigned int*)g,
                (__attribute__((address_space(3))) unsigned int*)l, 16, 0, 0);
        }
    };

    stage(A,  m0, M - 1,   &As[0][0], 0);
    stage(BT, n0, 767,     &Bs[0][0], 0);
    __syncthreads();

    int cur = 0;
    for (int t = 0; t < 24; ++t) {
        if (t < 23) {
            stage(A,  m0, M - 1, &As[cur ^ 1][0], (t + 1) * 32);
            stage(BT, n0, 767,   &Bs[cur ^ 1][0], (t + 1) * 32);
        }
        bf16x8 af[4], bfr[4];
#pragma unroll
        for (int i = 0; i < 4; ++i) {
            af[i]  = *(const bf16x8*)&As[cur][(wr * 64 + i * 16 + lrow) * 32 + lk * 8];
            bfr[i] = *(const bf16x8*)&Bs[cur][(wc * 64 + i * 16 + lrow) * 32 + lk * 8];
        }
#pragma unroll
        for (int i = 0; i < 4; ++i)
#pragma unroll
            for (int j = 0; j < 4; ++j)
                acc[i][j] = __builtin_amdgcn_mfma_f32_16x16x32_bf16(af[i], bfr[j], acc[i][j], 0, 0, 0);
        __syncthreads();
        cur ^= 1;
    }

#pragma unroll
    for (int i = 0; i < 4; ++i) {
        int gm = m0 + wr * 64 + i * 16 + (ln >> 4) * 4;
#pragma unroll
        for (int r = 0; r < 4; ++r) {
            int gmr = gm + r;
            if (gmr < M) {
#pragma unroll
                for (int j = 0; j < 4; ++j) {
                    int n = n0 + wc * 64 + j * 16 + (ln & 15);
                    float v = acc[i][j][r];
                    int bsmp = gmr / 196, p = gmr - bsmp * 196;
                    outp[(size_t)(gmr + bsmp + 1) * 768 + n] = v + bias[n] + pos[(size_t)(p + 1) * 768 + n];
                }
            }
        }
    }
}

// ---------------- LayerNorm1 over (S,D) per sample ----------------
__global__ __launch_bounds__(1024) void ln_stats(const float* __restrict__ x,
                                                 float* __restrict__ part) {
    int b = blockIdx.x, p = blockIdx.y;
    const float4* x4 = (const float4*)(x + (size_t)b*LNN + (size_t)p*(LNN/4));
    float s = 0.f, s2 = 0.f;
    for (int i = threadIdx.x; i < LNN/16; i += 1024) {
        float4 t = x4[i];
        s  += t.x + t.y + t.z + t.w;
        s2 += t.x*t.x + t.y*t.y + t.z*t.z + t.w*t.w;
    }
    for (int off = 32; off; off >>= 1) {
        s  += __shfl_down(s,  off);
        s2 += __shfl_down(s2, off);
    }
    __shared__ float r1[16], r2[16];
    int wid = threadIdx.x >> 6, lane = threadIdx.x & 63;
    if (lane == 0) { r1[wid] = s; r2[wid] = s2; }
    __syncthreads();
    if (threadIdx.x == 0) {
        float S1 = 0.f, S2 = 0.f;
        for (int i = 0; i < 16; ++i) { S1 += r1[i]; S2 += r2[i]; }
        part[b*8 + p*2 + 0] = S1;
        part[b*8 + p*2 + 1] = S2;
    }
}

__global__ __launch_bounds__(1024) void ln_apply_bf16(const float* __restrict__ x,
        const float* __restrict__ part, const float* __restrict__ g,
        const float* __restrict__ be, u16* __restrict__ yb) {
    int b = blockIdx.x, c = blockIdx.y;
    __shared__ float mu_s, rs_s;
    if (threadIdx.x == 0) {
        float S1 = part[b*8+0] + part[b*8+2] + part[b*8+4] + part[b*8+6];
        float S2 = part[b*8+1] + part[b*8+3] + part[b*8+5] + part[b*8+7];
        float mu = S1 * (1.f / (float)LNN);
        float var = S2 * (1.f / (float)LNN) - mu*mu;
        mu_s = mu; rs_s = rsqrtf(var + 1e-5f);
    }
    __syncthreads();
    float mu = mu_s, rstd = rs_s;
    size_t base = (size_t)b*LNN + (size_t)c*(LNN/16);
    const float4* x4 = (const float4*)(x + base);
    const float4* g4 = (const float4*)(g + (size_t)c*(LNN/16));
    const float4* b4 = (const float4*)(be + (size_t)c*(LNN/16));
    for (int i = threadIdx.x; i < LNN/64; i += 1024) {
        float4 xv = x4[i], gv = g4[i], bv = b4[i];
        union { u16 u[4]; uint2 v; } o;
        o.u[0]=f2bf((xv.x - mu)*rstd*gv.x + bv.x);
        o.u[1]=f2bf((xv.y - mu)*rstd*gv.y + bv.y);
        o.u[2]=f2bf((xv.z - mu)*rstd*gv.z + bv.z);
        o.u[3]=f2bf((xv.w - mu)*rstd*gv.w + bv.w);
        ((uint2*)(yb + base))[i] = o.v;
    }
}

// ---------------- QKV via MFMA: block = (sample b, head h), 4 waves ----------------
__global__ __launch_bounds__(256) void qkv_mfma(const u16* __restrict__ xb,
        const float* __restrict__ wq, const float* __restrict__ bq,
        const float* __restrict__ wk, const float* __restrict__ bk,
        const float* __restrict__ wv, const float* __restrict__ bv,
        u16* __restrict__ qb, u16* __restrict__ kb, u16* __restrict__ vT) {
    __shared__ u16 sh[32256];          // Xs [256][72] | Ws 3x[64][72]
    u16* Xs = sh;
    u16* Ws = sh + 18432;
    const int b = blockIdx.x, h = blockIdx.y;
    const int tid = threadIdx.x;
    const int w = tid >> 6, ln = tid & 63;
    const int lrow = ln & 15, lk = ln >> 4;

    {
        const u16* xrow = xb + (size_t)b * 197 * 768 + h * 64;
        for (int c = tid; c < 2048; c += 256) {
            int r = c >> 3, q8 = c & 7;
            int rr = r < 197 ? r : 196;
            *(uint4*)&Xs[r*72 + q8*8] = *(const uint4*)(xrow + (size_t)rr*768 + q8*8);
        }
    }
    {
        const float* s0 = wq + (size_t)h*4096;
        const float* s1 = wk + (size_t)h*4096;
        const float* s2 = wv + (size_t)h*4096;
#pragma unroll
        for (int m = 0; m < 3; ++m) {
            const float* s = (m == 0) ? s0 : (m == 1) ? s1 : s2;
            u16* wT = Ws + m * 4608;
            for (int qi = tid; qi < 1024; qi += 256) {
                int d = qi >> 4, e0 = (qi & 15) << 2;
                float4 t = *(const float4*)(s + d*64 + e0);
                wT[(e0+0)*72 + d] = f2bf(t.x);
                wT[(e0+1)*72 + d] = f2bf(t.y);
                wT[(e0+2)*72 + d] = f2bf(t.z);
                wT[(e0+3)*72 + d] = f2bf(t.w);
            }
        }
    }
    __syncthreads();

#pragma unroll
    for (int m = 0; m < 2; ++m) {
        const float* bias = ((m == 0) ? bq : bk) + h * 64;
        u16* dst = (m == 0) ? qb : kb;
        f32x4 acc[4][4];
#pragma unroll
        for (int i = 0; i < 4; ++i)
#pragma unroll
            for (int j = 0; j < 4; ++j) acc[i][j] = (f32x4){0.f,0.f,0.f,0.f};
#pragma unroll
        for (int s = 0; s < 2; ++s) {
            bf16x8 af[4], bfr[4];
#pragma unroll
            for (int i = 0; i < 4; ++i)
                af[i] = *(const bf16x8*)&Xs[(w*64 + i*16 + lrow)*72 + s*32 + lk*8];
#pragma unroll
            for (int j = 0; j < 4; ++j)
                bfr[j] = *(const bf16x8*)&Ws[m*4608 + (j*16 + lrow)*72 + s*32 + lk*8];
#pragma unroll
            for (int i = 0; i < 4; ++i)
#pragma unroll
                for (int j = 0; j < 4; ++j)
                    acc[i][j] = __builtin_amdgcn_mfma_f32_16x16x32_bf16(af[i], bfr[j], acc[i][j], 0, 0, 0);
        }
        float bj[4];
#pragma unroll
        for (int j = 0; j < 4; ++j) bj[j] = bias[j*16 + lrow];
#pragma unroll
        for (int i = 0; i < 4; ++i)
#pragma unroll
            for (int r = 0; r < 4; ++r) {
                int loc = w*64 + i*16 + lk*4 + r;
                if (loc < 197) {
                    size_t o = ((size_t)(b*197 + loc))*768 + h*64;
#pragma unroll
                    for (int j = 0; j < 4; ++j)
                        dst[o + j*16 + lrow] = f2bf(acc[i][j][r] + bj[j]);
                }
            }
    }

    {
        f32x4 acc[4][4];
#pragma unroll
        for (int i = 0; i < 4; ++i)
#pragma unroll
            for (int j = 0; j < 4; ++j) acc[i][j] = (f32x4){0.f,0.f,0.f,0.f};
#pragma unroll
        for (int s = 0; s < 2; ++s) {
            bf16x8 af[4], bfr[4];
#pragma unroll
            for (int i = 0; i < 4; ++i)
                af[i] = *(const bf16x8*)&Xs[(w*64 + i*16 + lrow)*72 + s*32 + lk*8];
#pragma unroll
            for (int j = 0; j < 4; ++j)
                bfr[j] = *(const bf16x8*)&Ws[2*4608 + (j*16 + lrow)*72 + s*32 + lk*8];
#pragma unroll
            for (int i = 0; i < 4; ++i)
#pragma unroll
                for (int j = 0; j < 4; ++j)
                    acc[i][j] = __builtin_amdgcn_mfma_f32_16x16x32_bf16(af[i], bfr[j], acc[i][j], 0, 0, 0);
        }
        float bj[4];
        const float* bias = bv + h * 64;
#pragma unroll
        for (int j = 0; j < 4; ++j) bj[j] = bias[j*16 + lrow];
        __syncthreads();
        u16* vs = Xs;                          // vstage [64 d][264 tok]
#pragma unroll
        for (int i = 0; i < 4; ++i)
#pragma unroll
            for (int j = 0; j < 4; ++j)
#pragma unroll
                for (int r = 0; r < 4; ++r)
                    vs[(j*16 + lrow)*264 + (w*64 + i*16 + lk*4 + r)] = f2bf(acc[i][j][r] + bj[j]);
        __syncthreads();
        const size_t vbase = (size_t)(b*NHH + h) * 64 * SQP;
        for (int t = tid; t < 4096; t += 256) {
            int d = t >> 6, tk0 = (t & 63) * 4;
            *(uint2*)&vT[vbase + (size_t)d*SQP + tk0] = *(const uint2*)&vs[d*264 + tk0];
        }
    }
}

// ---------------- attention v3: block per (b,h), 8 waves, K/V staged once ----------------
// Reads tokens (residual base) but does NOT write tokens: emits per-(b,h) LN2
// partial stats + cls-row final values only (head consumes only out[:,0]).
__global__ __launch_bounds__(512, 4) void attn_v3(const u16* __restrict__ qb,
        const u16* __restrict__ kb, const u16* __restrict__ vT,
        const float* __restrict__ tokens, float* __restrict__ cls_out,
        float* __restrict__ part2) {
    __shared__ u16 sh[34816];                 // Kall[256][68] | VTs[4][64][68]  (69632 B)
    __shared__ float redsm[16];
    u16* Kall = sh;
    u16* VTs  = sh + 17408;

    const int bh = blockIdx.x;
    const int b = bh / NHH, h = bh % NHH;
    const int tid = threadIdx.x;
    const int w = tid >> 6, l = tid & 63;
    const int g = l >> 4, lq = l & 15;

    // stage K [256 t][68] (clamp t>=197 to 196; masked later)
    {
        const u16* krow = kb + ((size_t)b*197)*768 + h*64;
        for (int idx = tid; idx < 4096; idx += 512) {
            int r = idx >> 4, c = idx & 15;
            int rr = r < 197 ? r : 196;
            *(uint2*)&Kall[r*68 + c*4] = *(const uint2*)(krow + (size_t)rr*768 + c*4);
        }
        const u16* vsrc = vT + (size_t)bh*64*SQP;
        for (int idx = tid; idx < 4096; idx += 512) {
            int d = idx >> 6, sc = idx & 63;
            int t = sc >> 4, sp = (sc & 15) * 4;
            *(uint2*)&VTs[t*4352 + d*68 + sp] = *(const uint2*)(vsrc + d*SQP + sc*4);
        }
    }
    // Q fragments in registers (wave w owns subtiles 2w, 2w+1 => q rows 32w..32w+31)
    bf16x8 qfr[2][2];
    {
        const u16* qbase = qb + ((size_t)b*197)*768 + h*64;
#pragma unroll
        for (int s2 = 0; s2 < 2; ++s2) {
            int qt = (2*w + s2)*16 + lq; if (qt > 196) qt = 196;
#pragma unroll
            for (int s = 0; s < 2; ++s)
                qfr[s2][s] = *(const bf16x8*)(qbase + (size_t)qt*768 + s*32 + g*8);
        }
    }
    __syncthreads();

    const int srcA = lq + ((l & 16) ? 32 : 0);
    float invS[2];
    f32x4 acco[2][4];

#pragma unroll
    for (int s2 = 0; s2 < 2; ++s2) {
        float S = 0.f;
#pragma unroll
        for (int i = 0; i < 4; ++i) acco[s2][i] = (f32x4){0.f,0.f,0.f,0.f};

        for (int kt = 0; kt < 4; ++kt) {
            const int t0 = kt * 64;
            f32x4 accp[4];
#pragma unroll
            for (int i = 0; i < 4; ++i) accp[i] = (f32x4){0.f,0.f,0.f,0.f};
#pragma unroll
            for (int s = 0; s < 2; ++s) {
                bf16x8 qf = qfr[s2][s];
#pragma unroll
                for (int tb = 0; tb < 4; ++tb) {
                    bf16x8 kf = *(const bf16x8*)&Kall[(t0 + tb*16 + lq)*68 + s*32 + g*8];
                    accp[tb] = __builtin_amdgcn_mfma_f32_16x16x32_bf16(kf, qf, accp[tb], 0, 0, 0);
                }
            }

            unsigned pk[4][2];
#pragma unroll
            for (int tb = 0; tb < 4; ++tb) {
                int tbase = t0 + tb*16 + g*4;
                float p0 = (tbase + 0 < 197) ? __expf(accp[tb][0] * 0.125f) : 0.f;
                float p1 = (tbase + 1 < 197) ? __expf(accp[tb][1] * 0.125f) : 0.f;
                float p2 = (tbase + 2 < 197) ? __expf(accp[tb][2] * 0.125f) : 0.f;
                float p3 = (tbase + 3 < 197) ? __expf(accp[tb][3] * 0.125f) : 0.f;
                S += (p0 + p1) + (p2 + p3);
                asm("v_cvt_pk_bf16_f32 %0, %1, %2" : "=v"(pk[tb][0]) : "v"(p0), "v"(p1));
                asm("v_cvt_pk_bf16_f32 %0, %1, %2" : "=v"(pk[tb][1]) : "v"(p2), "v"(p3));
            }

#pragma unroll
            for (int s = 0; s < 2; ++s) {
                union { unsigned u[4]; bf16x8 v; } bp;
#pragma unroll
                for (int c = 0; c < 4; ++c) {
                    int src = srcA + ((c >= 2) ? 16 : 0);
                    unsigned v0 = (unsigned)__shfl((int)pk[2*s + 0][c & 1], src);
                    unsigned v1 = (unsigned)__shfl((int)pk[2*s + 1][c & 1], src);
                    bp.u[c] = (l & 32) ? v1 : v0;
                }
#pragma unroll
                for (int dblk = 0; dblk < 4; ++dblk) {
                    bf16x8 vf = *(const bf16x8*)&VTs[kt*4352 + (dblk*16 + lq)*68 + s*32 + g*8];
                    acco[s2][dblk] = __builtin_amdgcn_mfma_f32_16x16x32_bf16(vf, bp.v, acco[s2][dblk], 0, 0, 0);
                }
            }
        }
        S += __shfl_xor(S, 16);
        S += __shfl_xor(S, 32);
        invS[s2] = 1.f / S;                  // inf for all-pad rows; masked below
    }

    __syncthreads();                          // all waves done with K/V LDS
    float* Osh = (float*)sh;                  // 8 x [16 q][72 d] f32 = 36864 B
    float* os = Osh + w * 1152;
    float ps = 0.f, ps2 = 0.f;

#pragma unroll
    for (int s2 = 0; s2 < 2; ++s2) {
        // transpose O^T(regs) -> os[q][d]
#pragma unroll
        for (int dblk = 0; dblk < 4; ++dblk)
#pragma unroll
            for (int r = 0; r < 4; ++r)
                os[lq*72 + dblk*16 + g*4 + r] = acco[s2][dblk][r] * invS[s2];
        asm volatile("s_waitcnt lgkmcnt(0)" ::: "memory");   // cross-lane, same wave

        int q_l = l >> 2, dc = l & 3;
        int q_tok = (2*w + s2)*16 + q_l;
        if (q_tok < 197) {
            const float* trow = tokens + ((size_t)(b*197 + q_tok))*768 + h*64;
            float* crow = cls_out + (size_t)b*768 + h*64;
#pragma unroll
            for (int c4 = 0; c4 < 4; ++c4) {
                float4 t = *(const float4*)(trow + dc*16 + c4*4);
                float4 o = *(const float4*)&os[q_l*72 + dc*16 + c4*4];
                float4 f;
                f.x = t.x + o.x; f.y = t.y + o.y; f.z = t.z + o.z; f.w = t.w + o.w;
                ps  += (f.x + f.y) + (f.z + f.w);
                ps2 += (f.x*f.x + f.y*f.y) + (f.z*f.z + f.w*f.w);
                if (q_tok == 0) *(float4*)(crow + dc*16 + c4*4) = f;
            }
        }
        asm volatile("s_waitcnt lgkmcnt(0)" ::: "memory");   // before os reuse
    }

    // block reduce ln2 partials -> part2[bh]
#pragma unroll
    for (int off = 1; off < 64; off <<= 1) {
        ps  += __shfl_xor(ps,  off);
        ps2 += __shfl_xor(ps2, off);
    }
    if (l == 0) { redsm[w*2] = ps; redsm[w*2 + 1] = ps2; }
    __syncthreads();
    if (tid == 0) {
        float a = 0.f, c = 0.f;
#pragma unroll
        for (int i = 0; i < 8; ++i) { a += redsm[2*i]; c += redsm[2*i+1]; }
        part2[bh*2]     = a;
        part2[bh*2 + 1] = c;
    }
}

// ---------------- fused ln2(row0) + MLP(row0) + residual: 64 rows only ----------------
__global__ __launch_bounds__(256) void mlp_cls(const float* __restrict__ cls_out,
        const float* __restrict__ part2, const float* __restrict__ ln2_g,
        const float* __restrict__ ln2_b, const u16* __restrict__ wt,
        const float* __restrict__ b_enc, float* __restrict__ mlp_out) {
    __shared__ float y0[768];
    const int b = blockIdx.x, tid = threadIdx.x;
    float s1 = 0.f, s2 = 0.f;
#pragma unroll
    for (int h = 0; h < NHH; ++h) {
        s1 += part2[(b*NHH + h)*2];
        s2 += part2[(b*NHH + h)*2 + 1];
    }
    float mu = s1 * (1.f / (float)LNN);
    float var = s2 * (1.f / (float)LNN) - mu*mu;
    float rstd = rsqrtf(var + 1e-5f);
    for (int d = tid; d < 768; d += 256)
        y0[d] = (cls_out[(size_t)b*768 + d] - mu) * rstd * ln2_g[d] + ln2_b[d];
    __syncthreads();
    for (int n = tid; n < 768; n += 256) {
        const u16* wr = wt + (size_t)n * 768;
        float acc = b_enc[n];
        for (int k = 0; k < 768; k += 8) {
            uint4 wv = *(const uint4*)(wr + k);
            acc += y0[k+0] * __uint_as_float(wv.x << 16)
                 + y0[k+1] * __uint_as_float(wv.x & 0xFFFF0000u)
                 + y0[k+2] * __uint_as_float(wv.y << 16)
                 + y0[k+3] * __uint_as_float(wv.y & 0xFFFF0000u)
                 + y0[k+4] * __uint_as_float(wv.z << 16)
                 + y0[k+5] * __uint_as_float(wv.z & 0xFFFF0000u)
                 + y0[k+6] * __uint_as_float(wv.w << 16)
                 + y0[k+7] * __uint_as_float(wv.w & 0xFFFF0000u);
        }
        mlp_out[(size_t)b*768 + n] = cls_out[(size_t)b*768 + n] + fmaxf(acc, 0.f);
    }
}

// ---------------- head: logits + softmax ----------------
__global__ __launch_bounds__(1024) void head_kernel(const float* __restrict__ xin,
        const float* __restrict__ w_head, const float* __restrict__ b_head,
        float* __restrict__ outp) {
    __shared__ float xr[768];
    __shared__ float red[16];
    const int b = blockIdx.x;
    const float* xrow = xin + (size_t)b * 768;
    for (int i = threadIdx.x; i < 768; i += 1024) xr[i] = xrow[i];
    __syncthreads();
    const int o = threadIdx.x;
    float lg = -1e30f;
    if (o < NOUT) {
        float acc = b_head[o];
#pragma unroll 8
        for (int d = 0; d < 768; ++d) acc += xr[d] * w_head[(size_t)d*NOUT + o];
        lg = acc;
    }
    const int wid = threadIdx.x >> 6, lane = threadIdx.x & 63;
    float mx = lg;
    for (int off = 32; off; off >>= 1) mx = fmaxf(mx, __shfl_xor(mx, off));
    if (lane == 0) red[wid] = mx;
    __syncthreads();
    if (threadIdx.x == 0) {
        float m = red[0];
        for (int i = 1; i < 16; ++i) m = fmaxf(m, red[i]);
        red[0] = m;
    }
    __syncthreads();
    const float m = red[0];
    float e = (o < NOUT) ? __expf(lg - m) : 0.f;
    float ss = e;
    for (int off = 32; off; off >>= 1) ss += __shfl_xor(ss, off);
    __syncthreads();
    if (lane == 0) red[wid] = ss;
    __syncthreads();
    if (threadIdx.x == 0) {
        float t = 0.f;
        for (int i = 0; i < 16; ++i) t += red[i];
        red[0] = t;
    }
    __syncthreads();
    const float inv = 1.f / red[0];
    if (o < NOUT) outp[(size_t)b*NOUT + o] = e * inv;
}

// ---------------- launch ----------------
extern "C" void kernel_launch(void* const* d_in, const int* in_sizes, int n_in,
                              void* d_out, int out_size, void* d_ws, size_t ws_size,
                              hipStream_t stream) {
    (void)in_sizes; (void)n_in; (void)out_size; (void)ws_size;
    const float* images = (const float*)d_in[0];
    const float* w_map  = (const float*)d_in[1];
    const float* b_map  = (const float*)d_in[2];
    const float* cls_tok= (const float*)d_in[3];
    const float* ln1_g  = (const float*)d_in[4];
    const float* ln1_b  = (const float*)d_in[5];
    const float* wq     = (const float*)d_in[6];
    const float* bq     = (const float*)d_in[7];
    const float* wk     = (const float*)d_in[8];
    const float* bk     = (const float*)d_in[9];
    const float* wv     = (const float*)d_in[10];
    const float* bv     = (const float*)d_in[11];
    const float* ln2_g  = (const float*)d_in[12];
    const float* ln2_b  = (const float*)d_in[13];
    const float* w_enc  = (const float*)d_in[14];
    const float* b_enc  = (const float*)d_in[15];
    const float* w_head = (const float*)d_in[16];
    const float* b_head = (const float*)d_in[17];
    float* out = (float*)d_out;
    float* ws = (float*)d_ws;

    float* pos    = ws;                     // 151296
    float* tokens = pos + 151296;           // 9682944 f32 (residual, read-only after attn)
    float* x      = tokens + 9682944;       // (u16*)x = ln1 bf16 out
    float* q      = x + 9682944;            // imb overlay, then qb
    float* kk     = q + 9682944;            // wt(w_map) overlay, then kb, then wt(w_enc)
    float* vv     = kk + 9682944;           // vT bf16 [768][64][256]
    float* part   = vv + 9682944;           // 512 (ln1 partial stats)
    float* cls_o  = part + 512;             // 49152 (post-attn cls rows, f32)
    float* part2  = cls_o + 49152;          // 1536 (ln2 per-(b,h) partials)
    float* mlp_o  = part2 + 1536;           // 49152 (final cls rows, f32)

    u16* imb = (u16*)q;
    u16* wt  = (u16*)kk;
    u16* xb  = (u16*)x;
    u16* qbp = (u16*)q;
    u16* kbp = (u16*)kk;
    u16* vTp = (u16*)vv;

    pos_emb_kernel<<<(SQ*DD + 255)/256, 256, 0, stream>>>(pos);
    cls_kernel<<<(BB_*DD + 255)/256, 256, 0, stream>>>(cls_tok, pos, tokens);
    conv_bf16_kernel<<<(MPATCH*768/8 + 255)/256, 256, 0, stream>>>(images, imb, MPATCH*768/8);
    transpose_bf16_kernel<<<dim3(24, 24), 256, 0, stream>>>(w_map, wt);
    gemm_mfma0<<<dim3(98, 6), 256, 0, stream>>>(imb, wt, b_map, pos, tokens, MPATCH);
    ln_stats<<<dim3(64, 4), 1024, 0, stream>>>(tokens, part);
    ln_apply_bf16<<<dim3(64, 16), 1024, 0, stream>>>(tokens, part, ln1_g, ln1_b, xb);
    qkv_mfma<<<dim3(BB_, NHH), 256, 0, stream>>>(xb, wq, bq, wk, bk, wv, bv, qbp, kbp, vTp);
    attn_v3<<<BB_*NHH, 512, 0, stream>>>(qbp, kbp, vTp, tokens, cls_o, part2);
    transpose_bf16_kernel<<<dim3(24, 24), 256, 0, stream>>>(w_enc, wt);
    mlp_cls<<<BB_, 256, 0, stream>>>(cls_o, part2, ln2_g, ln2_b, wt, b_enc, mlp_o);
    head_kernel<<<BB_, 1024, 0, stream>>>(mlp_o, w_head, b_head, out);
}

// Round 7
// 234.119 us; speedup vs baseline: 1.1619x; 1.1619x over previous
//
#include <hip/hip_runtime.h>
#include <math.h>

// ---------------- dims ----------------
#define SQ 197           // tokens
#define DD 768           // hidden
#define NHH 12
#define DHH 64
#define BB_ 64           // batch
#define MTOK (BB_*SQ)    // 12608
#define MPATCH (BB_*196) // 12544
#define NOUT 1000
#define LNN (SQ*DD)      // 151296 elems per sample
#define SQP 256          // padded seq for vT

typedef unsigned short u16;
typedef __attribute__((ext_vector_type(8))) short bf16x8;
typedef __attribute__((ext_vector_type(4))) float f32x4;

__device__ __forceinline__ u16 f2bf(float x) {      // RNE f32->bf16
    unsigned u = __float_as_uint(x);
    u = (u + 0x7FFF + ((u >> 16) & 1)) >> 16;
    return (u16)u;
}

// ---------------- pos emb (f64 for safety, tiny) ----------------
__global__ void pos_emb_kernel(float* __restrict__ pos) {
    int i = blockIdx.x * blockDim.x + threadIdx.x;
    if (i >= SQ * DD) return;
    int s = i / DD, d = i % DD;
    double e = (double)(d & ~1) / (double)DD;
    double ang = (double)s * pow(10000.0, -e);
    pos[i] = (d & 1) ? (float)cos(ang) : (float)sin(ang);
}

// ---------------- cls token row ----------------
__global__ void cls_kernel(const float* __restrict__ cls_tok,
                           const float* __restrict__ pos,
                           float* __restrict__ tokens) {
    int i = blockIdx.x * blockDim.x + threadIdx.x;
    if (i >= BB_ * DD) return;
    int b = i / DD, d = i % DD;
    tokens[(size_t)b * SQ * DD + d] = cls_tok[d] + pos[d];
}

// ---------------- f32 -> bf16 bulk convert (8 elems/thread) ----------------
__global__ __launch_bounds__(256) void conv_bf16_kernel(const float* __restrict__ in,
        u16* __restrict__ out, int n8) {
    int i = blockIdx.x * blockDim.x + threadIdx.x;
    if (i >= n8) return;
    float4 a = ((const float4*)in)[2*i];
    float4 b = ((const float4*)in)[2*i + 1];
    union { u16 u[8]; uint4 v; } r;
    r.u[0]=f2bf(a.x); r.u[1]=f2bf(a.y); r.u[2]=f2bf(a.z); r.u[3]=f2bf(a.w);
    r.u[4]=f2bf(b.x); r.u[5]=f2bf(b.y); r.u[6]=f2bf(b.z); r.u[7]=f2bf(b.w);
    ((uint4*)out)[i] = r.v;
}

// ---------------- 768x768 transpose + convert: out[n][k] = in[k][n] ----------------
__global__ __launch_bounds__(256) void transpose_bf16_kernel(const float* __restrict__ in,
        u16* __restrict__ out) {
    __shared__ float t[32][33];
    int bn = blockIdx.x * 32, bk = blockIdx.y * 32;
    int tx = threadIdx.x & 31;
#pragma unroll
    for (int r = 0; r < 4; ++r) {
        int kk = (threadIdx.x >> 5) * 4 + r;
        t[kk][tx] = in[(size_t)(bk + kk) * 768 + bn + tx];
    }
    __syncthreads();
#pragma unroll
    for (int r = 0; r < 4; ++r) {
        int nn = (threadIdx.x >> 5) * 4 + r;
        out[(size_t)(bn + nn) * 768 + bk + tx] = f2bf(t[tx][nn]);
    }
}

// ---------------- MFMA GEMM (embed): C[M,768] = A[M,768]bf16 * B, BT=[n][k] ----------------
__global__ __launch_bounds__(256) void gemm_mfma0(const u16* __restrict__ A,
        const u16* __restrict__ BT, const float* __restrict__ bias,
        const float* __restrict__ pos, float* __restrict__ outp, int M) {
    __shared__ u16 As[2][4096];   // [128 rows][32 k] bf16
    __shared__ u16 Bs[2][4096];
    const int tid = threadIdx.x;
    const int wv = tid >> 6, ln = tid & 63;
    const int m0 = blockIdx.x * 128, n0 = blockIdx.y * 128;
    const int wr = wv >> 1, wc = wv & 1;
    const int lrow = ln & 15, lk = ln >> 4;

    f32x4 acc[4][4];
#pragma unroll
    for (int i = 0; i < 4; ++i)
#pragma unroll
        for (int j = 0; j < 4; ++j) acc[i][j] = (f32x4){0.f, 0.f, 0.f, 0.f};

    auto stage = [&](const u16* __restrict__ src, int rowBase, int rowMax,
                     u16* lbase, int k0) {
#pragma unroll
        for (int rep = 0; rep < 2; ++rep) {
            int c = rep * 256 + wv * 64 + ln;
            int row = rowBase + (c >> 2);
            if (row > rowMax) row = rowMax;
            const void* g = (const char*)src + ((size_t)row * 768 + k0) * 2 + ((c & 3) << 4);
            void* l = (char*)lbase + rep * 4096 + wv * 1024;
            __builtin_amdgcn_global_load_lds(
                (const __attribute__((address_space(1))) unsigned int*)g,
                (__attribute__((address_space(3))) unsigned int*)l, 16, 0, 0);
        }
    };

    stage(A,  m0, M - 1,   &As[0][0], 0);
    stage(BT, n0, 767,     &Bs[0][0], 0);
    __syncthreads();

    int cur = 0;
    for (int t = 0; t < 24; ++t) {
        if (t < 23) {
            stage(A,  m0, M - 1, &As[cur ^ 1][0], (t + 1) * 32);
            stage(BT, n0, 767,   &Bs[cur ^ 1][0], (t + 1) * 32);
        }
        bf16x8 af[4], bfr[4];
#pragma unroll
        for (int i = 0; i < 4; ++i) {
            af[i]  = *(const bf16x8*)&As[cur][(wr * 64 + i * 16 + lrow) * 32 + lk * 8];
            bfr[i] = *(const bf16x8*)&Bs[cur][(wc * 64 + i * 16 + lrow) * 32 + lk * 8];
        }
#pragma unroll
        for (int i = 0; i < 4; ++i)
#pragma unroll
            for (int j = 0; j < 4; ++j)
                acc[i][j] = __builtin_amdgcn_mfma_f32_16x16x32_bf16(af[i], bfr[j], acc[i][j], 0, 0, 0);
        __syncthreads();
        cur ^= 1;
    }

#pragma unroll
    for (int i = 0; i < 4; ++i) {
        int gm = m0 + wr * 64 + i * 16 + (ln >> 4) * 4;
#pragma unroll
        for (int r = 0; r < 4; ++r) {
            int gmr = gm + r;
            if (gmr < M) {
#pragma unroll
                for (int j = 0; j < 4; ++j) {
                    int n = n0 + wc * 64 + j * 16 + (ln & 15);
                    float v = acc[i][j][r];
                    int bsmp = gmr / 196, p = gmr - bsmp * 196;
                    outp[(size_t)(gmr + bsmp + 1) * 768 + n] = v + bias[n] + pos[(size_t)(p + 1) * 768 + n];
                }
            }
        }
    }
}

// ---------------- LayerNorm1 over (S,D) per sample ----------------
__global__ __launch_bounds__(1024) void ln_stats(const float* __restrict__ x,
                                                 float* __restrict__ part) {
    int b = blockIdx.x, p = blockIdx.y;
    const float4* x4 = (const float4*)(x + (size_t)b*LNN + (size_t)p*(LNN/4));
    float s = 0.f, s2 = 0.f;
    for (int i = threadIdx.x; i < LNN/16; i += 1024) {
        float4 t = x4[i];
        s  += t.x + t.y + t.z + t.w;
        s2 += t.x*t.x + t.y*t.y + t.z*t.z + t.w*t.w;
    }
    for (int off = 32; off; off >>= 1) {
        s  += __shfl_down(s,  off);
        s2 += __shfl_down(s2, off);
    }
    __shared__ float r1[16], r2[16];
    int wid = threadIdx.x >> 6, lane = threadIdx.x & 63;
    if (lane == 0) { r1[wid] = s; r2[wid] = s2; }
    __syncthreads();
    if (threadIdx.x == 0) {
        float S1 = 0.f, S2 = 0.f;
        for (int i = 0; i < 16; ++i) { S1 += r1[i]; S2 += r2[i]; }
        part[b*8 + p*2 + 0] = S1;
        part[b*8 + p*2 + 1] = S2;
    }
}

__global__ __launch_bounds__(1024) void ln_apply_bf16(const float* __restrict__ x,
        const float* __restrict__ part, const float* __restrict__ g,
        const float* __restrict__ be, u16* __restrict__ yb) {
    int b = blockIdx.x, c = blockIdx.y;
    __shared__ float mu_s, rs_s;
    if (threadIdx.x == 0) {
        float S1 = part[b*8+0] + part[b*8+2] + part[b*8+4] + part[b*8+6];
        float S2 = part[b*8+1] + part[b*8+3] + part[b*8+5] + part[b*8+7];
        float mu = S1 * (1.f / (float)LNN);
        float var = S2 * (1.f / (float)LNN) - mu*mu;
        mu_s = mu; rs_s = rsqrtf(var + 1e-5f);
    }
    __syncthreads();
    float mu = mu_s, rstd = rs_s;
    size_t base = (size_t)b*LNN + (size_t)c*(LNN/16);
    const float4* x4 = (const float4*)(x + base);
    const float4* g4 = (const float4*)(g + (size_t)c*(LNN/16));
    const float4* b4 = (const float4*)(be + (size_t)c*(LNN/16));
    for (int i = threadIdx.x; i < LNN/64; i += 1024) {
        float4 xv = x4[i], gv = g4[i], bv = b4[i];
        union { u16 u[4]; uint2 v; } o;
        o.u[0]=f2bf((xv.x - mu)*rstd*gv.x + bv.x);
        o.u[1]=f2bf((xv.y - mu)*rstd*gv.y + bv.y);
        o.u[2]=f2bf((xv.z - mu)*rstd*gv.z + bv.z);
        o.u[3]=f2bf((xv.w - mu)*rstd*gv.w + bv.w);
        ((uint2*)(yb + base))[i] = o.v;
    }
}

// ---------------- QKV via MFMA: block = (sample b, head h), 4 waves ----------------
__global__ __launch_bounds__(256) void qkv_mfma(const u16* __restrict__ xb,
        const float* __restrict__ wq, const float* __restrict__ bq,
        const float* __restrict__ wk, const float* __restrict__ bk,
        const float* __restrict__ wv, const float* __restrict__ bv,
        u16* __restrict__ qb, u16* __restrict__ kb, u16* __restrict__ vT) {
    __shared__ u16 sh[32256];          // Xs [256][72] | Ws 3x[64][72]
    u16* Xs = sh;
    u16* Ws = sh + 18432;
    const int b = blockIdx.x, h = blockIdx.y;
    const int tid = threadIdx.x;
    const int w = tid >> 6, ln = tid & 63;
    const int lrow = ln & 15, lk = ln >> 4;

    {
        const u16* xrow = xb + (size_t)b * 197 * 768 + h * 64;
        for (int c = tid; c < 2048; c += 256) {
            int r = c >> 3, q8 = c & 7;
            int rr = r < 197 ? r : 196;
            *(uint4*)&Xs[r*72 + q8*8] = *(const uint4*)(xrow + (size_t)rr*768 + q8*8);
        }
    }
    {
        const float* s0 = wq + (size_t)h*4096;
        const float* s1 = wk + (size_t)h*4096;
        const float* s2 = wv + (size_t)h*4096;
#pragma unroll
        for (int m = 0; m < 3; ++m) {
            const float* s = (m == 0) ? s0 : (m == 1) ? s1 : s2;
            u16* wT = Ws + m * 4608;
            for (int qi = tid; qi < 1024; qi += 256) {
                int d = qi >> 4, e0 = (qi & 15) << 2;
                float4 t = *(const float4*)(s + d*64 + e0);
                wT[(e0+0)*72 + d] = f2bf(t.x);
                wT[(e0+1)*72 + d] = f2bf(t.y);
                wT[(e0+2)*72 + d] = f2bf(t.z);
                wT[(e0+3)*72 + d] = f2bf(t.w);
            }
        }
    }
    __syncthreads();

#pragma unroll
    for (int m = 0; m < 2; ++m) {
        const float* bias = ((m == 0) ? bq : bk) + h * 64;
        u16* dst = (m == 0) ? qb : kb;
        f32x4 acc[4][4];
#pragma unroll
        for (int i = 0; i < 4; ++i)
#pragma unroll
            for (int j = 0; j < 4; ++j) acc[i][j] = (f32x4){0.f,0.f,0.f,0.f};
#pragma unroll
        for (int s = 0; s < 2; ++s) {
            bf16x8 af[4], bfr[4];
#pragma unroll
            for (int i = 0; i < 4; ++i)
                af[i] = *(const bf16x8*)&Xs[(w*64 + i*16 + lrow)*72 + s*32 + lk*8];
#pragma unroll
            for (int j = 0; j < 4; ++j)
                bfr[j] = *(const bf16x8*)&Ws[m*4608 + (j*16 + lrow)*72 + s*32 + lk*8];
#pragma unroll
            for (int i = 0; i < 4; ++i)
#pragma unroll
                for (int j = 0; j < 4; ++j)
                    acc[i][j] = __builtin_amdgcn_mfma_f32_16x16x32_bf16(af[i], bfr[j], acc[i][j], 0, 0, 0);
        }
        float bj[4];
#pragma unroll
        for (int j = 0; j < 4; ++j) bj[j] = bias[j*16 + lrow];
#pragma unroll
        for (int i = 0; i < 4; ++i)
#pragma unroll
            for (int r = 0; r < 4; ++r) {
                int loc = w*64 + i*16 + lk*4 + r;
                if (loc < 197) {
                    size_t o = ((size_t)(b*197 + loc))*768 + h*64;
#pragma unroll
                    for (int j = 0; j < 4; ++j)
                        dst[o + j*16 + lrow] = f2bf(acc[i][j][r] + bj[j]);
                }
            }
    }

    {
        f32x4 acc[4][4];
#pragma unroll
        for (int i = 0; i < 4; ++i)
#pragma unroll
            for (int j = 0; j < 4; ++j) acc[i][j] = (f32x4){0.f,0.f,0.f,0.f};
#pragma unroll
        for (int s = 0; s < 2; ++s) {
            bf16x8 af[4], bfr[4];
#pragma unroll
            for (int i = 0; i < 4; ++i)
                af[i] = *(const bf16x8*)&Xs[(w*64 + i*16 + lrow)*72 + s*32 + lk*8];
#pragma unroll
            for (int j = 0; j < 4; ++j)
                bfr[j] = *(const bf16x8*)&Ws[2*4608 + (j*16 + lrow)*72 + s*32 + lk*8];
#pragma unroll
            for (int i = 0; i < 4; ++i)
#pragma unroll
                for (int j = 0; j < 4; ++j)
                    acc[i][j] = __builtin_amdgcn_mfma_f32_16x16x32_bf16(af[i], bfr[j], acc[i][j], 0, 0, 0);
        }
        float bj[4];
        const float* bias = bv + h * 64;
#pragma unroll
        for (int j = 0; j < 4; ++j) bj[j] = bias[j*16 + lrow];
        __syncthreads();
        u16* vs = Xs;                          // vstage [64 d][264 tok]
#pragma unroll
        for (int i = 0; i < 4; ++i)
#pragma unroll
            for (int j = 0; j < 4; ++j)
#pragma unroll
                for (int r = 0; r < 4; ++r)
                    vs[(j*16 + lrow)*264 + (w*64 + i*16 + lk*4 + r)] = f2bf(acc[i][j][r] + bj[j]);
        __syncthreads();
        const size_t vbase = (size_t)(b*NHH + h) * 64 * SQP;
        for (int t = tid; t < 4096; t += 256) {
            int d = t >> 6, tk0 = (t & 63) * 4;
            *(uint2*)&vT[vbase + (size_t)d*SQP + tk0] = *(const uint2*)&vs[d*264 + tk0];
        }
    }
}

// ---------------- attention: MFMA flash, block per (b,h,qblk of 64), 4 waves ----------------
// Residual add in-place into tokens + fused LN2 partial stats (per-block slot, no atomics).
__global__ __launch_bounds__(256) void attn_mfma(const u16* __restrict__ qb,
        const u16* __restrict__ kb, const u16* __restrict__ vT,
        float* __restrict__ tokens, float* __restrict__ part2) {
    __shared__ u16 sh[13824];                 // Qs[64][72] | Ks[64][72] | VTs[64][72]
    __shared__ float redp[8];
    u16* Qs  = sh;
    u16* Ks  = sh + 4608;
    u16* VTs = sh + 9216;

    const int bh = blockIdx.x;
    const int b = bh / NHH, h = bh % NHH;
    const int q0 = blockIdx.y * 64;
    const int tid = threadIdx.x;
    const int w = tid >> 6, l = tid & 63;
    const int g = l >> 4, lq = l & 15;

    {
        const u16* qrow = qb + (size_t)(b*197 + q0)*768 + h*64;
#pragma unroll
        for (int it = 0; it < 4; ++it) {
            int idx = tid + it*256;
            int r = idx >> 4, c = idx & 15;
            *(uint2*)&Qs[r*72 + c*4] = *(const uint2*)(qrow + (size_t)r*768 + c*4);
        }
    }

    f32x4 acco[4];
#pragma unroll
    for (int i = 0; i < 4; ++i) acco[i] = (f32x4){0.f,0.f,0.f,0.f};
    float S = 0.f;

    const int srcA = lq + ((l & 16) ? 32 : 0);

    for (int tt = 0; tt < 4; ++tt) {
        const int t0 = tt * 64;
        __syncthreads();
        {
            const u16* krow = kb + (size_t)(b*197 + t0)*768 + h*64;
            const u16* vrow = vT + (size_t)bh*64*SQP + t0;
#pragma unroll
            for (int it = 0; it < 4; ++it) {
                int idx = tid + it*256;
                int r = idx >> 4, c = idx & 15;
                *(uint2*)&Ks[r*72 + c*4]  = *(const uint2*)(krow + (size_t)r*768 + c*4);
                *(uint2*)&VTs[r*72 + c*4] = *(const uint2*)(vrow + (size_t)r*SQP + c*4);
            }
        }
        __syncthreads();

        f32x4 accp[4];
#pragma unroll
        for (int i = 0; i < 4; ++i) accp[i] = (f32x4){0.f,0.f,0.f,0.f};
#pragma unroll
        for (int s = 0; s < 2; ++s) {
            bf16x8 qf = *(const bf16x8*)&Qs[(w*16 + lq)*72 + s*32 + g*8];
#pragma unroll
            for (int tb = 0; tb < 4; ++tb) {
                bf16x8 kf = *(const bf16x8*)&Ks[(tb*16 + lq)*72 + s*32 + g*8];
                accp[tb] = __builtin_amdgcn_mfma_f32_16x16x32_bf16(kf, qf, accp[tb], 0, 0, 0);
            }
        }

        unsigned pk[4][2];
#pragma unroll
        for (int tb = 0; tb < 4; ++tb) {
            float p0, p1, p2, p3;
            {
                int tbase = t0 + tb*16 + g*4;
                p0 = (tbase + 0 < 197) ? __expf(accp[tb][0] * 0.125f) : 0.f;
                p1 = (tbase + 1 < 197) ? __expf(accp[tb][1] * 0.125f) : 0.f;
                p2 = (tbase + 2 < 197) ? __expf(accp[tb][2] * 0.125f) : 0.f;
                p3 = (tbase + 3 < 197) ? __expf(accp[tb][3] * 0.125f) : 0.f;
            }
            S += (p0 + p1) + (p2 + p3);
            asm("v_cvt_pk_bf16_f32 %0, %1, %2" : "=v"(pk[tb][0]) : "v"(p0), "v"(p1));
            asm("v_cvt_pk_bf16_f32 %0, %1, %2" : "=v"(pk[tb][1]) : "v"(p2), "v"(p3));
        }

#pragma unroll
        for (int s = 0; s < 2; ++s) {
            union { unsigned u[4]; bf16x8 v; } bp;
#pragma unroll
            for (int c = 0; c < 4; ++c) {
                int src = srcA + ((c >= 2) ? 16 : 0);
                unsigned v0 = (unsigned)__shfl((int)pk[2*s + 0][c & 1], src);
                unsigned v1 = (unsigned)__shfl((int)pk[2*s + 1][c & 1], src);
                bp.u[c] = (l & 32) ? v1 : v0;
            }
#pragma unroll
            for (int dblk = 0; dblk < 4; ++dblk) {
                bf16x8 vf = *(const bf16x8*)&VTs[(dblk*16 + lq)*72 + s*32 + g*8];
                acco[dblk] = __builtin_amdgcn_mfma_f32_16x16x32_bf16(vf, bp.v, acco[dblk], 0, 0, 0);
            }
        }
    }

    S += __shfl_xor(S, 16);
    S += __shfl_xor(S, 32);
    float invS = 1.f / S;

    __syncthreads();
    float* Osh = (float*)&sh[4608];           // 4 waves x [64][17] f32 = 17408 B
    float* os = Osh + w * 1088;
#pragma unroll
    for (int dblk = 0; dblk < 4; ++dblk)
#pragma unroll
        for (int r = 0; r < 4; ++r)
            os[(dblk*16 + g*4 + r)*17 + lq] = acco[dblk][r] * invS;
    __syncthreads();

    const int q_l = tid >> 2, dc = tid & 3;
    const int s_tok = q0 + q_l;
    float ps = 0.f, ps2 = 0.f;
    if (s_tok < 197) {
        const float* osr = Osh + (q_l >> 4)*1088;
        const int ql = q_l & 15;
        float* dst = tokens + (size_t)(b*197 + s_tok)*768 + h*64 + dc*16;
#pragma unroll
        for (int c4 = 0; c4 < 4; ++c4) {
            float4 t = *(float4*)&dst[c4*4];
            t.x += osr[(dc*16 + c4*4 + 0)*17 + ql];
            t.y += osr[(dc*16 + c4*4 + 1)*17 + ql];
            t.z += osr[(dc*16 + c4*4 + 2)*17 + ql];
            t.w += osr[(dc*16 + c4*4 + 3)*17 + ql];
            *(float4*)&dst[c4*4] = t;
            ps  += (t.x + t.y) + (t.z + t.w);
            ps2 += (t.x*t.x + t.y*t.y) + (t.z*t.z + t.w*t.w);
        }
    }
    // fused LN2 partial stats -> deterministic slot
#pragma unroll
    for (int off = 1; off < 64; off <<= 1) {
        ps  += __shfl_xor(ps,  off);
        ps2 += __shfl_xor(ps2, off);
    }
    if (l == 0) { redp[w*2] = ps; redp[w*2 + 1] = ps2; }
    __syncthreads();
    if (tid == 0) {
        float a = redp[0] + redp[2] + redp[4] + redp[6];
        float c = redp[1] + redp[3] + redp[5] + redp[7];
        part2[(bh*4 + blockIdx.y)*2]     = a;
        part2[(bh*4 + blockIdx.y)*2 + 1] = c;
    }
}

// ---------------- fused ln2(row0) + MLP(row0) + residual: cls rows only ----------------
__global__ __launch_bounds__(256) void mlp_cls(const float* __restrict__ tokens,
        const float* __restrict__ part2, const float* __restrict__ ln2_g,
        const float* __restrict__ ln2_b, const float* __restrict__ w_enc,
        const float* __restrict__ b_enc, float* __restrict__ mlp_out) {
    __shared__ float y0[768];
    const int b = blockIdx.x, tid = threadIdx.x;
    float s1 = 0.f, s2 = 0.f;
    for (int i = 0; i < 48; ++i) {
        s1 += part2[(b*48 + i)*2];
        s2 += part2[(b*48 + i)*2 + 1];
    }
    float mu = s1 * (1.f / (float)LNN);
    float var = s2 * (1.f / (float)LNN) - mu*mu;
    float rstd = rsqrtf(var + 1e-5f);
    const float* crow = tokens + (size_t)b * 197 * 768;   // cls row
    for (int d = tid; d < 768; d += 256)
        y0[d] = (crow[d] - mu) * rstd * ln2_g[d] + ln2_b[d];
    __syncthreads();
    const int n = blockIdx.y * 256 + tid;                 // grid.y = 3 -> n < 768
    float acc = b_enc[n];
#pragma unroll 8
    for (int k = 0; k < 768; ++k) acc += y0[k] * w_enc[(size_t)k*768 + n];
    mlp_out[(size_t)b*768 + n] = crow[n] + fmaxf(acc, 0.f);
}

// ---------------- head: logits (parallel) + softmax ----------------
__global__ __launch_bounds__(256) void logits_kernel(const float* __restrict__ xin,
        const float* __restrict__ w_head, const float* __restrict__ b_head,
        float* __restrict__ logits) {
    __shared__ float xr[768];
    const int b = blockIdx.x;
    const int o = blockIdx.y * 256 + threadIdx.x;
    for (int i = threadIdx.x; i < 768; i += 256) xr[i] = xin[(size_t)b*768 + i];
    __syncthreads();
    if (o < NOUT) {
        float acc = b_head[o];
#pragma unroll 8
        for (int d = 0; d < 768; ++d) acc += xr[d] * w_head[(size_t)d*NOUT + o];
        logits[(size_t)b*NOUT + o] = acc;
    }
}

__global__ __launch_bounds__(256) void softmax_kernel(const float* __restrict__ logits,
        float* __restrict__ outp) {
    __shared__ float red[8];
    const int b = blockIdx.x, tid = threadIdx.x;
    const float* lrow = logits + (size_t)b*NOUT;
    const int w = tid >> 6, l = tid & 63;
    float v[4];
    float mx = -1e30f;
#pragma unroll
    for (int i = 0; i < 4; ++i) {
        int t = tid + i*256;
        v[i] = (t < NOUT) ? lrow[t] : -1e30f;
        mx = fmaxf(mx, v[i]);
    }
    for (int off = 32; off; off >>= 1) mx = fmaxf(mx, __shfl_xor(mx, off));
    if (l == 0) red[w] = mx;
    __syncthreads();
    if (tid == 0) red[4] = fmaxf(fmaxf(red[0], red[1]), fmaxf(red[2], red[3]));
    __syncthreads();
    const float m = red[4];
    float s = 0.f;
#pragma unroll
    for (int i = 0; i < 4; ++i) { v[i] = __expf(v[i] - m); s += v[i]; }
    for (int off = 32; off; off >>= 1) s += __shfl_xor(s, off);
    if (l == 0) red[w] = s;
    __syncthreads();
    if (tid == 0) red[5] = red[0] + red[1] + red[2] + red[3];
    __syncthreads();
    const float inv = 1.f / red[5];
#pragma unroll
    for (int i = 0; i < 4; ++i) {
        int t = tid + i*256;
        if (t < NOUT) outp[(size_t)b*NOUT + t] = v[i] * inv;
    }
}

// ---------------- launch ----------------
extern "C" void kernel_launch(void* const* d_in, const int* in_sizes, int n_in,
                              void* d_out, int out_size, void* d_ws, size_t ws_size,
                              hipStream_t stream) {
    (void)in_sizes; (void)n_in; (void)out_size; (void)ws_size;
    const float* images = (const float*)d_in[0];
    const float* w_map  = (const float*)d_in[1];
    const float* b_map  = (const float*)d_in[2];
    const float* cls_tok= (const float*)d_in[3];
    const float* ln1_g  = (const float*)d_in[4];
    const float* ln1_b  = (const float*)d_in[5];
    const float* wq     = (const float*)d_in[6];
    const float* bq     = (const float*)d_in[7];
    const float* wk     = (const float*)d_in[8];
    const float* bk     = (const float*)d_in[9];
    const float* wv     = (const float*)d_in[10];
    const float* bv     = (const float*)d_in[11];
    const float* ln2_g  = (const float*)d_in[12];
    const float* ln2_b  = (const float*)d_in[13];
    const float* w_enc  = (const float*)d_in[14];
    const float* b_enc  = (const float*)d_in[15];
    const float* w_head = (const float*)d_in[16];
    const float* b_head = (const float*)d_in[17];
    float* out = (float*)d_out;
    float* ws = (float*)d_ws;

    float* pos    = ws;                     // 151296
    float* tokens = pos + 151296;           // 9682944 f32 (residual, updated in-place by attn)
    float* x      = tokens + 9682944;       // (u16*)x = ln1 bf16 out
    float* q      = x + 9682944;            // imb overlay, then qb
    float* kk     = q + 9682944;            // wt(w_map) overlay, then kb
    float* vv     = kk + 9682944;           // vT bf16 [768][64][256]
    float* part   = vv + 9682944;           // 512 (ln1 partial stats)
    float* part2  = part + 512;             // 6144 (ln2 per-(b,h,qblk) partials)
    float* mlp_o  = part2 + 6144;           // 49152 (final cls rows, f32)
    float* logit  = mlp_o + 49152;          // 64000

    u16* imb = (u16*)q;
    u16* wt  = (u16*)kk;
    u16* xb  = (u16*)x;
    u16* qbp = (u16*)q;
    u16* kbp = (u16*)kk;
    u16* vTp = (u16*)vv;

    pos_emb_kernel<<<(SQ*DD + 255)/256, 256, 0, stream>>>(pos);
    cls_kernel<<<(BB_*DD + 255)/256, 256, 0, stream>>>(cls_tok, pos, tokens);
    conv_bf16_kernel<<<(MPATCH*768/8 + 255)/256, 256, 0, stream>>>(images, imb, MPATCH*768/8);
    transpose_bf16_kernel<<<dim3(24, 24), 256, 0, stream>>>(w_map, wt);
    gemm_mfma0<<<dim3(98, 6), 256, 0, stream>>>(imb, wt, b_map, pos, tokens, MPATCH);
    ln_stats<<<dim3(64, 4), 1024, 0, stream>>>(tokens, part);
    ln_apply_bf16<<<dim3(64, 16), 1024, 0, stream>>>(tokens, part, ln1_g, ln1_b, xb);
    qkv_mfma<<<dim3(BB_, NHH), 256, 0, stream>>>(xb, wq, bq, wk, bk, wv, bv, qbp, kbp, vTp);
    attn_mfma<<<dim3(BB_*NHH, 4), 256, 0, stream>>>(qbp, kbp, vTp, tokens, part2);
    mlp_cls<<<dim3(BB_, 3), 256, 0, stream>>>(tokens, part2, ln2_g, ln2_b, w_enc, b_enc, mlp_o);
    logits_kernel<<<dim3(BB_, 4), 256, 0, stream>>>(mlp_o, w_head, b_head, logit);
    softmax_kernel<<<BB_, 256, 0, stream>>>(logit, out);
}

// Round 8
// 222.249 us; speedup vs baseline: 1.2240x; 1.0534x over previous
//
#include <hip/hip_runtime.h>
#include <math.h>

// ---------------- dims ----------------
#define SQ 197           // tokens
#define DD 768           // hidden
#define NHH 12
#define DHH 64
#define BB_ 64           // batch
#define MTOK (BB_*SQ)    // 12608
#define MPATCH (BB_*196) // 12544
#define NOUT 1000
#define LNN (SQ*DD)      // 151296 elems per sample
#define SQP 256          // padded seq for vT

typedef unsigned short u16;
typedef __attribute__((ext_vector_type(8))) short bf16x8;
typedef __attribute__((ext_vector_type(4))) float f32x4;

__device__ __forceinline__ u16 f2bf(float x) {      // RNE f32->bf16
    unsigned u = __float_as_uint(x);
    u = (u + 0x7FFF + ((u >> 16) & 1)) >> 16;
    return (u16)u;
}

// ---------------- pos emb (f64 for safety, tiny) ----------------
__global__ void pos_emb_kernel(float* __restrict__ pos) {
    int i = blockIdx.x * blockDim.x + threadIdx.x;
    if (i >= SQ * DD) return;
    int s = i / DD, d = i % DD;
    double e = (double)(d & ~1) / (double)DD;
    double ang = (double)s * pow(10000.0, -e);
    pos[i] = (d & 1) ? (float)cos(ang) : (float)sin(ang);
}

// ---------------- cls token row ----------------
__global__ void cls_kernel(const float* __restrict__ cls_tok,
                           const float* __restrict__ pos,
                           float* __restrict__ tokens) {
    int i = blockIdx.x * blockDim.x + threadIdx.x;
    if (i >= BB_ * DD) return;
    int b = i / DD, d = i % DD;
    tokens[(size_t)b * SQ * DD + d] = cls_tok[d] + pos[d];
}

// ---------------- f32 -> bf16 bulk convert (8 elems/thread) ----------------
__global__ __launch_bounds__(256) void conv_bf16_kernel(const float* __restrict__ in,
        u16* __restrict__ out, int n8) {
    int i = blockIdx.x * blockDim.x + threadIdx.x;
    if (i >= n8) return;
    float4 a = ((const float4*)in)[2*i];
    float4 b = ((const float4*)in)[2*i + 1];
    union { u16 u[8]; uint4 v; } r;
    r.u[0]=f2bf(a.x); r.u[1]=f2bf(a.y); r.u[2]=f2bf(a.z); r.u[3]=f2bf(a.w);
    r.u[4]=f2bf(b.x); r.u[5]=f2bf(b.y); r.u[6]=f2bf(b.z); r.u[7]=f2bf(b.w);
    ((uint4*)out)[i] = r.v;
}

// ---------------- 768x768 transpose + convert: out[n][k] = in[k][n] ----------------
__global__ __launch_bounds__(256) void transpose_bf16_kernel(const float* __restrict__ in,
        u16* __restrict__ out) {
    __shared__ float t[32][33];
    int bn = blockIdx.x * 32, bk = blockIdx.y * 32;
    int tx = threadIdx.x & 31;
#pragma unroll
    for (int r = 0; r < 4; ++r) {
        int kk = (threadIdx.x >> 5) * 4 + r;
        t[kk][tx] = in[(size_t)(bk + kk) * 768 + bn + tx];
    }
    __syncthreads();
#pragma unroll
    for (int r = 0; r < 4; ++r) {
        int nn = (threadIdx.x >> 5) * 4 + r;
        out[(size_t)(bn + nn) * 768 + bk + tx] = f2bf(t[tx][nn]);
    }
}

// ---------------- MFMA GEMM (embed): C[M,768] = A[M,768]bf16 * B, BT=[n][k] ----------------
__global__ __launch_bounds__(256) void gemm_mfma0(const u16* __restrict__ A,
        const u16* __restrict__ BT, const float* __restrict__ bias,
        const float* __restrict__ pos, float* __restrict__ outp, int M) {
    __shared__ u16 As[2][4096];   // [128 rows][32 k] bf16
    __shared__ u16 Bs[2][4096];
    const int tid = threadIdx.x;
    const int wv = tid >> 6, ln = tid & 63;
    const int m0 = blockIdx.x * 128, n0 = blockIdx.y * 128;
    const int wr = wv >> 1, wc = wv & 1;
    const int lrow = ln & 15, lk = ln >> 4;

    f32x4 acc[4][4];
#pragma unroll
    for (int i = 0; i < 4; ++i)
#pragma unroll
        for (int j = 0; j < 4; ++j) acc[i][j] = (f32x4){0.f, 0.f, 0.f, 0.f};

    auto stage = [&](const u16* __restrict__ src, int rowBase, int rowMax,
                     u16* lbase, int k0) {
#pragma unroll
        for (int rep = 0; rep < 2; ++rep) {
            int c = rep * 256 + wv * 64 + ln;
            int row = rowBase + (c >> 2);
            if (row > rowMax) row = rowMax;
            const void* g = (const char*)src + ((size_t)row * 768 + k0) * 2 + ((c & 3) << 4);
            void* l = (char*)lbase + rep * 4096 + wv * 1024;
            __builtin_amdgcn_global_load_lds(
                (const __attribute__((address_space(1))) unsigned int*)g,
                (__attribute__((address_space(3))) unsigned int*)l, 16, 0, 0);
        }
    };

    stage(A,  m0, M - 1,   &As[0][0], 0);
    stage(BT, n0, 767,     &Bs[0][0], 0);
    __syncthreads();

    int cur = 0;
    for (int t = 0; t < 24; ++t) {
        if (t < 23) {
            stage(A,  m0, M - 1, &As[cur ^ 1][0], (t + 1) * 32);
            stage(BT, n0, 767,   &Bs[cur ^ 1][0], (t + 1) * 32);
        }
        bf16x8 af[4], bfr[4];
#pragma unroll
        for (int i = 0; i < 4; ++i) {
            af[i]  = *(const bf16x8*)&As[cur][(wr * 64 + i * 16 + lrow) * 32 + lk * 8];
            bfr[i] = *(const bf16x8*)&Bs[cur][(wc * 64 + i * 16 + lrow) * 32 + lk * 8];
        }
#pragma unroll
        for (int i = 0; i < 4; ++i)
#pragma unroll
            for (int j = 0; j < 4; ++j)
                acc[i][j] = __builtin_amdgcn_mfma_f32_16x16x32_bf16(af[i], bfr[j], acc[i][j], 0, 0, 0);
        __syncthreads();
        cur ^= 1;
    }

#pragma unroll
    for (int i = 0; i < 4; ++i) {
        int gm = m0 + wr * 64 + i * 16 + (ln >> 4) * 4;
#pragma unroll
        for (int r = 0; r < 4; ++r) {
            int gmr = gm + r;
            if (gmr < M) {
#pragma unroll
                for (int j = 0; j < 4; ++j) {
                    int n = n0 + wc * 64 + j * 16 + (ln & 15);
                    float v = acc[i][j][r];
                    int bsmp = gmr / 196, p = gmr - bsmp * 196;
                    outp[(size_t)(gmr + bsmp + 1) * 768 + n] = v + bias[n] + pos[(size_t)(p + 1) * 768 + n];
                }
            }
        }
    }
}

// ---------------- LayerNorm1 stats over (S,D) per sample ----------------
__global__ __launch_bounds__(1024) void ln_stats(const float* __restrict__ x,
                                                 float* __restrict__ part) {
    int b = blockIdx.x, p = blockIdx.y;
    const float4* x4 = (const float4*)(x + (size_t)b*LNN + (size_t)p*(LNN/4));
    float s = 0.f, s2 = 0.f;
    for (int i = threadIdx.x; i < LNN/16; i += 1024) {
        float4 t = x4[i];
        s  += t.x + t.y + t.z + t.w;
        s2 += t.x*t.x + t.y*t.y + t.z*t.z + t.w*t.w;
    }
    for (int off = 32; off; off >>= 1) {
        s  += __shfl_down(s,  off);
        s2 += __shfl_down(s2, off);
    }
    __shared__ float r1[16], r2[16];
    int wid = threadIdx.x >> 6, lane = threadIdx.x & 63;
    if (lane == 0) { r1[wid] = s; r2[wid] = s2; }
    __syncthreads();
    if (threadIdx.x == 0) {
        float S1 = 0.f, S2 = 0.f;
        for (int i = 0; i < 16; ++i) { S1 += r1[i]; S2 += r2[i]; }
        part[b*8 + p*2 + 0] = S1;
        part[b*8 + p*2 + 1] = S2;
    }
}

// ---------------- QKV via MFMA with fused LN1-apply: block = (b, h), 4 waves ----------------
__global__ __launch_bounds__(256) void qkv_mfma(const float* __restrict__ tokens,
        const float* __restrict__ part,
        const float* __restrict__ ln1_g, const float* __restrict__ ln1_b,
        const float* __restrict__ wq, const float* __restrict__ bq,
        const float* __restrict__ wk, const float* __restrict__ bk,
        const float* __restrict__ wv, const float* __restrict__ bv,
        u16* __restrict__ qb, u16* __restrict__ kb, u16* __restrict__ vT) {
    __shared__ u16 sh[32256];          // Xs [256][72] | Ws 3x[64][72]
    u16* Xs = sh;
    u16* Ws = sh + 18432;
    const int b = blockIdx.x, h = blockIdx.y;
    const int tid = threadIdx.x;
    const int w = tid >> 6, ln = tid & 63;
    const int lrow = ln & 15, lk = ln >> 4;

    // LN1 stats for sample b
    const float S1 = part[b*8+0] + part[b*8+2] + part[b*8+4] + part[b*8+6];
    const float S2 = part[b*8+1] + part[b*8+3] + part[b*8+5] + part[b*8+7];
    const float mu = S1 * (1.f / (float)LNN);
    const float rstd = rsqrtf(S2 * (1.f / (float)LNN) - mu*mu + 1e-5f);

    // stage X with LN applied on the fly (rows clamped to 196)
    {
        const float* trow = tokens + (size_t)b * 197 * 768 + h * 64;
        for (int c = tid; c < 2048; c += 256) {
            int r = c >> 3, q8 = (c & 7) * 8;
            int rr = r < 197 ? r : 196;
            const float* tp = trow  + (size_t)rr*768 + q8;
            const float* gp = ln1_g + (size_t)rr*768 + h*64 + q8;
            const float* bp = ln1_b + (size_t)rr*768 + h*64 + q8;
            float4 t0 = *(const float4*)tp,      t1 = *(const float4*)(tp+4);
            float4 g0 = *(const float4*)gp,      g1 = *(const float4*)(gp+4);
            float4 b0 = *(const float4*)bp,      b1 = *(const float4*)(bp+4);
            union { u16 u[8]; uint4 v; } o;
            o.u[0] = f2bf((t0.x - mu)*rstd*g0.x + b0.x);
            o.u[1] = f2bf((t0.y - mu)*rstd*g0.y + b0.y);
            o.u[2] = f2bf((t0.z - mu)*rstd*g0.z + b0.z);
            o.u[3] = f2bf((t0.w - mu)*rstd*g0.w + b0.w);
            o.u[4] = f2bf((t1.x - mu)*rstd*g1.x + b1.x);
            o.u[5] = f2bf((t1.y - mu)*rstd*g1.y + b1.y);
            o.u[6] = f2bf((t1.z - mu)*rstd*g1.z + b1.z);
            o.u[7] = f2bf((t1.w - mu)*rstd*g1.w + b1.w);
            *(uint4*)&Xs[r*72 + q8] = o.v;
        }
    }
    {
        const float* s0 = wq + (size_t)h*4096;
        const float* s1 = wk + (size_t)h*4096;
        const float* s2 = wv + (size_t)h*4096;
#pragma unroll
        for (int m = 0; m < 3; ++m) {
            const float* s = (m == 0) ? s0 : (m == 1) ? s1 : s2;
            u16* wT = Ws + m * 4608;
            for (int qi = tid; qi < 1024; qi += 256) {
                int d = qi >> 4, e0 = (qi & 15) << 2;
                float4 t = *(const float4*)(s + d*64 + e0);
                wT[(e0+0)*72 + d] = f2bf(t.x);
                wT[(e0+1)*72 + d] = f2bf(t.y);
                wT[(e0+2)*72 + d] = f2bf(t.z);
                wT[(e0+3)*72 + d] = f2bf(t.w);
            }
        }
    }
    __syncthreads();

#pragma unroll
    for (int m = 0; m < 2; ++m) {
        const float* bias = ((m == 0) ? bq : bk) + h * 64;
        u16* dst = (m == 0) ? qb : kb;
        f32x4 acc[4][4];
#pragma unroll
        for (int i = 0; i < 4; ++i)
#pragma unroll
            for (int j = 0; j < 4; ++j) acc[i][j] = (f32x4){0.f,0.f,0.f,0.f};
#pragma unroll
        for (int s = 0; s < 2; ++s) {
            bf16x8 af[4], bfr[4];
#pragma unroll
            for (int i = 0; i < 4; ++i)
                af[i] = *(const bf16x8*)&Xs[(w*64 + i*16 + lrow)*72 + s*32 + lk*8];
#pragma unroll
            for (int j = 0; j < 4; ++j)
                bfr[j] = *(const bf16x8*)&Ws[m*4608 + (j*16 + lrow)*72 + s*32 + lk*8];
#pragma unroll
            for (int i = 0; i < 4; ++i)
#pragma unroll
                for (int j = 0; j < 4; ++j)
                    acc[i][j] = __builtin_amdgcn_mfma_f32_16x16x32_bf16(af[i], bfr[j], acc[i][j], 0, 0, 0);
        }
        float bj[4];
#pragma unroll
        for (int j = 0; j < 4; ++j) bj[j] = bias[j*16 + lrow];
#pragma unroll
        for (int i = 0; i < 4; ++i)
#pragma unroll
            for (int r = 0; r < 4; ++r) {
                int loc = w*64 + i*16 + lk*4 + r;
                if (loc < 197) {
                    size_t o = ((size_t)(b*197 + loc))*768 + h*64;
#pragma unroll
                    for (int j = 0; j < 4; ++j)
                        dst[o + j*16 + lrow] = f2bf(acc[i][j][r] + bj[j]);
                }
            }
    }

    {
        f32x4 acc[4][4];
#pragma unroll
        for (int i = 0; i < 4; ++i)
#pragma unroll
            for (int j = 0; j < 4; ++j) acc[i][j] = (f32x4){0.f,0.f,0.f,0.f};
#pragma unroll
        for (int s = 0; s < 2; ++s) {
            bf16x8 af[4], bfr[4];
#pragma unroll
            for (int i = 0; i < 4; ++i)
                af[i] = *(const bf16x8*)&Xs[(w*64 + i*16 + lrow)*72 + s*32 + lk*8];
#pragma unroll
            for (int j = 0; j < 4; ++j)
                bfr[j] = *(const bf16x8*)&Ws[2*4608 + (j*16 + lrow)*72 + s*32 + lk*8];
#pragma unroll
            for (int i = 0; i < 4; ++i)
#pragma unroll
                for (int j = 0; j < 4; ++j)
                    acc[i][j] = __builtin_amdgcn_mfma_f32_16x16x32_bf16(af[i], bfr[j], acc[i][j], 0, 0, 0);
        }
        float bj[4];
        const float* bias = bv + h * 64;
#pragma unroll
        for (int j = 0; j < 4; ++j) bj[j] = bias[j*16 + lrow];
        __syncthreads();
        u16* vs = Xs;                          // vstage [64 d][264 tok]
#pragma unroll
        for (int i = 0; i < 4; ++i)
#pragma unroll
            for (int j = 0; j < 4; ++j)
#pragma unroll
                for (int r = 0; r < 4; ++r)
                    vs[(j*16 + lrow)*264 + (w*64 + i*16 + lk*4 + r)] = f2bf(acc[i][j][r] + bj[j]);
        __syncthreads();
        const size_t vbase = (size_t)(b*NHH + h) * 64 * SQP;
        for (int t = tid; t < 4096; t += 256) {
            int d = t >> 6, tk0 = (t & 63) * 4;
            *(uint2*)&vT[vbase + (size_t)d*SQP + tk0] = *(const uint2*)&vs[d*264 + tk0];
        }
    }
}

// ---------------- attention: MFMA flash, block per (b,h,qhalf of 128), 4 waves ----------------
// Per staged K/V tile, two 64-row q-subtiles (s2) are computed -> K/V traffic halved.
// Residual add in-place + fused LN2 partial stats (deterministic slot, no atomics).
__global__ __launch_bounds__(256) void attn_mfma(const u16* __restrict__ qb,
        const u16* __restrict__ kb, const u16* __restrict__ vT,
        float* __restrict__ tokens, float* __restrict__ part2) {
    __shared__ u16 sh[18432];                 // Qs[128][72] | Ks[64][72] | VTs[64][72]
    __shared__ float redp[8];
    u16* Qs  = sh;                            // 9216 u16
    u16* Ks  = sh + 9216;
    u16* VTs = sh + 13824;

    const int bh = blockIdx.x;
    const int b = bh / NHH, h = bh % NHH;
    const int q0 = blockIdx.y * 128;
    const int tid = threadIdx.x;
    const int w = tid >> 6, l = tid & 63;
    const int g = l >> 4, lq = l & 15;

    // stage Q: 128 rows (global row clamped to 196)
    {
        const u16* qbase = qb + (size_t)(b*197)*768 + h*64;
#pragma unroll
        for (int it = 0; it < 8; ++it) {
            int idx = tid + it*256;
            int r = idx >> 4, c = idx & 15;
            int gr = q0 + r; if (gr > 196) gr = 196;
            *(uint2*)&Qs[r*72 + c*4] = *(const uint2*)(qbase + (size_t)gr*768 + c*4);
        }
    }

    f32x4 acco[2][4];
#pragma unroll
    for (int s2 = 0; s2 < 2; ++s2)
#pragma unroll
        for (int i = 0; i < 4; ++i) acco[s2][i] = (f32x4){0.f,0.f,0.f,0.f};
    float S[2] = {0.f, 0.f};

    const int srcA = lq + ((l & 16) ? 32 : 0);

    for (int tt = 0; tt < 4; ++tt) {
        const int t0 = tt * 64;
        __syncthreads();
        {
            const u16* krow = kb + (size_t)(b*197)*768 + h*64;
            const u16* vrow = vT + (size_t)bh*64*SQP + t0;
#pragma unroll
            for (int it = 0; it < 4; ++it) {
                int idx = tid + it*256;
                int r = idx >> 4, c = idx & 15;
                int gt = t0 + r; if (gt > 196) gt = 196;
                *(uint2*)&Ks[r*72 + c*4]  = *(const uint2*)(krow + (size_t)gt*768 + c*4);
                *(uint2*)&VTs[r*72 + c*4] = *(const uint2*)(vrow + (size_t)r*SQP + c*4);
            }
        }
        __syncthreads();

#pragma unroll
        for (int s2 = 0; s2 < 2; ++s2) {
            f32x4 accp[4];
#pragma unroll
            for (int i = 0; i < 4; ++i) accp[i] = (f32x4){0.f,0.f,0.f,0.f};
#pragma unroll
            for (int s = 0; s < 2; ++s) {
                bf16x8 qf = *(const bf16x8*)&Qs[(s2*64 + w*16 + lq)*72 + s*32 + g*8];
#pragma unroll
                for (int tb = 0; tb < 4; ++tb) {
                    bf16x8 kf = *(const bf16x8*)&Ks[(tb*16 + lq)*72 + s*32 + g*8];
                    accp[tb] = __builtin_amdgcn_mfma_f32_16x16x32_bf16(kf, qf, accp[tb], 0, 0, 0);
                }
            }

            unsigned pk[4][2];
#pragma unroll
            for (int tb = 0; tb < 4; ++tb) {
                int tbase = t0 + tb*16 + g*4;
                float p0 = (tbase + 0 < 197) ? __expf(accp[tb][0] * 0.125f) : 0.f;
                float p1 = (tbase + 1 < 197) ? __expf(accp[tb][1] * 0.125f) : 0.f;
                float p2 = (tbase + 2 < 197) ? __expf(accp[tb][2] * 0.125f) : 0.f;
                float p3 = (tbase + 3 < 197) ? __expf(accp[tb][3] * 0.125f) : 0.f;
                S[s2] += (p0 + p1) + (p2 + p3);
                asm("v_cvt_pk_bf16_f32 %0, %1, %2" : "=v"(pk[tb][0]) : "v"(p0), "v"(p1));
                asm("v_cvt_pk_bf16_f32 %0, %1, %2" : "=v"(pk[tb][1]) : "v"(p2), "v"(p3));
            }

#pragma unroll
            for (int s = 0; s < 2; ++s) {
                union { unsigned u[4]; bf16x8 v; } bp;
#pragma unroll
                for (int c = 0; c < 4; ++c) {
                    int src = srcA + ((c >= 2) ? 16 : 0);
                    unsigned v0 = (unsigned)__shfl((int)pk[2*s + 0][c & 1], src);
                    unsigned v1 = (unsigned)__shfl((int)pk[2*s + 1][c & 1], src);
                    bp.u[c] = (l & 32) ? v1 : v0;
                }
#pragma unroll
                for (int dblk = 0; dblk < 4; ++dblk) {
                    bf16x8 vf = *(const bf16x8*)&VTs[(dblk*16 + lq)*72 + s*32 + g*8];
                    acco[s2][dblk] = __builtin_amdgcn_mfma_f32_16x16x32_bf16(vf, bp.v, acco[s2][dblk], 0, 0, 0);
                }
            }
        }
    }

    float invS[2];
#pragma unroll
    for (int s2 = 0; s2 < 2; ++s2) {
        S[s2] += __shfl_xor(S[s2], 16);
        S[s2] += __shfl_xor(S[s2], 32);
        invS[s2] = 1.f / S[s2];
    }

    // epilogue (twice): transpose through LDS (overlays dead Qs), residual add + LN2 partials
    float* Osh = (float*)sh;                  // 4 waves x [64][17] f32 = 17408 B
    float ps = 0.f, ps2v = 0.f;
    const int q_l = tid >> 2, dc = tid & 3;
#pragma unroll
    for (int s2 = 0; s2 < 2; ++s2) {
        __syncthreads();
        float* os = Osh + w * 1088;
#pragma unroll
        for (int dblk = 0; dblk < 4; ++dblk)
#pragma unroll
            for (int r = 0; r < 4; ++r)
                os[(dblk*16 + g*4 + r)*17 + lq] = acco[s2][dblk][r] * invS[s2];
        __syncthreads();

        const int s_tok = q0 + s2*64 + q_l;
        if (s_tok < 197) {
            const float* osr = Osh + (q_l >> 4)*1088;
            const int ql = q_l & 15;
            float* dst = tokens + (size_t)(b*197 + s_tok)*768 + h*64 + dc*16;
#pragma unroll
            for (int c4 = 0; c4 < 4; ++c4) {
                float4 t = *(float4*)&dst[c4*4];
                t.x += osr[(dc*16 + c4*4 + 0)*17 + ql];
                t.y += osr[(dc*16 + c4*4 + 1)*17 + ql];
                t.z += osr[(dc*16 + c4*4 + 2)*17 + ql];
                t.w += osr[(dc*16 + c4*4 + 3)*17 + ql];
                *(float4*)&dst[c4*4] = t;
                ps   += (t.x + t.y) + (t.z + t.w);
                ps2v += (t.x*t.x + t.y*t.y) + (t.z*t.z + t.w*t.w);
            }
        }
    }

#pragma unroll
    for (int off = 1; off < 64; off <<= 1) {
        ps   += __shfl_xor(ps,   off);
        ps2v += __shfl_xor(ps2v, off);
    }
    if (l == 0) { redp[w*2] = ps; redp[w*2 + 1] = ps2v; }
    __syncthreads();
    if (tid == 0) {
        float a = redp[0] + redp[2] + redp[4] + redp[6];
        float c = redp[1] + redp[3] + redp[5] + redp[7];
        int slot = bh*2 + blockIdx.y;
        part2[slot*2]     = a;
        part2[slot*2 + 1] = c;
    }
}

// ---------------- fused ln2(row0) + MLP(row0) + residual: cls rows only ----------------
__global__ __launch_bounds__(256) void mlp_cls(const float* __restrict__ tokens,
        const float* __restrict__ part2, const float* __restrict__ ln2_g,
        const float* __restrict__ ln2_b, const float* __restrict__ w_enc,
        const float* __restrict__ b_enc, float* __restrict__ mlp_out) {
    __shared__ float y0[768];
    const int b = blockIdx.x, tid = threadIdx.x;
    float s1 = 0.f, s2 = 0.f;
    for (int i = 0; i < 24; ++i) {
        s1 += part2[(b*24 + i)*2];
        s2 += part2[(b*24 + i)*2 + 1];
    }
    float mu = s1 * (1.f / (float)LNN);
    float var = s2 * (1.f / (float)LNN) - mu*mu;
    float rstd = rsqrtf(var + 1e-5f);
    const float* crow = tokens + (size_t)b * 197 * 768;   // cls row
    for (int d = tid; d < 768; d += 256)
        y0[d] = (crow[d] - mu) * rstd * ln2_g[d] + ln2_b[d];
    __syncthreads();
    const int n = blockIdx.y * 256 + tid;                 // grid.y = 3 -> n < 768
    float acc = b_enc[n];
#pragma unroll 8
    for (int k = 0; k < 768; ++k) acc += y0[k] * w_enc[(size_t)k*768 + n];
    mlp_out[(size_t)b*768 + n] = crow[n] + fmaxf(acc, 0.f);
}

// ---------------- head: logits (parallel) + softmax ----------------
__global__ __launch_bounds__(256) void logits_kernel(const float* __restrict__ xin,
        const float* __restrict__ w_head, const float* __restrict__ b_head,
        float* __restrict__ logits) {
    __shared__ float xr[768];
    const int b = blockIdx.x;
    const int o = blockIdx.y * 256 + threadIdx.x;
    for (int i = threadIdx.x; i < 768; i += 256) xr[i] = xin[(size_t)b*768 + i];
    __syncthreads();
    if (o < NOUT) {
        float acc = b_head[o];
#pragma unroll 8
        for (int d = 0; d < 768; ++d) acc += xr[d] * w_head[(size_t)d*NOUT + o];
        logits[(size_t)b*NOUT + o] = acc;
    }
}

__global__ __launch_bounds__(256) void softmax_kernel(const float* __restrict__ logits,
        float* __restrict__ outp) {
    __shared__ float red[8];
    const int b = blockIdx.x, tid = threadIdx.x;
    const float* lrow = logits + (size_t)b*NOUT;
    const int w = tid >> 6, l = tid & 63;
    float v[4];
    float mx = -1e30f;
#pragma unroll
    for (int i = 0; i < 4; ++i) {
        int t = tid + i*256;
        v[i] = (t < NOUT) ? lrow[t] : -1e30f;
        mx = fmaxf(mx, v[i]);
    }
    for (int off = 32; off; off >>= 1) mx = fmaxf(mx, __shfl_xor(mx, off));
    if (l == 0) red[w] = mx;
    __syncthreads();
    if (tid == 0) red[4] = fmaxf(fmaxf(red[0], red[1]), fmaxf(red[2], red[3]));
    __syncthreads();
    const float m = red[4];
    float s = 0.f;
#pragma unroll
    for (int i = 0; i < 4; ++i) { v[i] = __expf(v[i] - m); s += v[i]; }
    for (int off = 32; off; off >>= 1) s += __shfl_xor(s, off);
    if (l == 0) red[w] = s;
    __syncthreads();
    if (tid == 0) red[5] = red[0] + red[1] + red[2] + red[3];
    __syncthreads();
    const float inv = 1.f / red[5];
#pragma unroll
    for (int i = 0; i < 4; ++i) {
        int t = tid + i*256;
        if (t < NOUT) outp[(size_t)b*NOUT + t] = v[i] * inv;
    }
}

// ---------------- launch ----------------
extern "C" void kernel_launch(void* const* d_in, const int* in_sizes, int n_in,
                              void* d_out, int out_size, void* d_ws, size_t ws_size,
                              hipStream_t stream) {
    (void)in_sizes; (void)n_in; (void)out_size; (void)ws_size;
    const float* images = (const float*)d_in[0];
    const float* w_map  = (const float*)d_in[1];
    const float* b_map  = (const float*)d_in[2];
    const float* cls_tok= (const float*)d_in[3];
    const float* ln1_g  = (const float*)d_in[4];
    const float* ln1_b  = (const float*)d_in[5];
    const float* wq     = (const float*)d_in[6];
    const float* bq     = (const float*)d_in[7];
    const float* wk     = (const float*)d_in[8];
    const float* bk     = (const float*)d_in[9];
    const float* wv     = (const float*)d_in[10];
    const float* bv     = (const float*)d_in[11];
    const float* ln2_g  = (const float*)d_in[12];
    const float* ln2_b  = (const float*)d_in[13];
    const float* w_enc  = (const float*)d_in[14];
    const float* b_enc  = (const float*)d_in[15];
    const float* w_head = (const float*)d_in[16];
    const float* b_head = (const float*)d_in[17];
    float* out = (float*)d_out;
    float* ws = (float*)d_ws;

    float* pos    = ws;                     // 151296
    float* tokens = pos + 151296;           // 9682944 f32 (residual, updated in-place by attn)
    float* x      = tokens + 9682944;       // unused this round (kept for layout stability)
    float* q      = x + 9682944;            // imb overlay, then qb
    float* kk     = q + 9682944;            // wt(w_map) overlay, then kb
    float* vv     = kk + 9682944;           // vT bf16 [768][64][256]
    float* part   = vv + 9682944;           // 512 (ln1 partial stats)
    float* part2  = part + 512;             // 3072 (ln2 per-(b,h,qhalf) partials)
    float* mlp_o  = part2 + 3072;           // 49152 (final cls rows, f32)
    float* logit  = mlp_o + 49152;          // 64000

    u16* imb = (u16*)q;
    u16* wt  = (u16*)kk;
    u16* qbp = (u16*)q;
    u16* kbp = (u16*)kk;
    u16* vTp = (u16*)vv;

    pos_emb_kernel<<<(SQ*DD + 255)/256, 256, 0, stream>>>(pos);
    cls_kernel<<<(BB_*DD + 255)/256, 256, 0, stream>>>(cls_tok, pos, tokens);
    conv_bf16_kernel<<<(MPATCH*768/8 + 255)/256, 256, 0, stream>>>(images, imb, MPATCH*768/8);
    transpose_bf16_kernel<<<dim3(24, 24), 256, 0, stream>>>(w_map, wt);
    gemm_mfma0<<<dim3(98, 6), 256, 0, stream>>>(imb, wt, b_map, pos, tokens, MPATCH);
    ln_stats<<<dim3(64, 4), 1024, 0, stream>>>(tokens, part);
    qkv_mfma<<<dim3(BB_, NHH), 256, 0, stream>>>(tokens, part, ln1_g, ln1_b,
                                                 wq, bq, wk, bk, wv, bv, qbp, kbp, vTp);
    attn_mfma<<<dim3(BB_*NHH, 2), 256, 0, stream>>>(qbp, kbp, vTp, tokens, part2);
    mlp_cls<<<dim3(BB_, 3), 256, 0, stream>>>(tokens, part2, ln2_g, ln2_b, w_enc, b_enc, mlp_o);
    logits_kernel<<<dim3(BB_, 4), 256, 0, stream>>>(mlp_o, w_head, b_head, logit);
    softmax_kernel<<<BB_, 256, 0, stream>>>(logit, out);
}

// Round 9
// 216.355 us; speedup vs baseline: 1.2573x; 1.0272x over previous
//
#include <hip/hip_runtime.h>
#include <math.h>

// ---------------- dims ----------------
#define SQ 197           // tokens
#define DD 768           // hidden
#define NHH 12
#define DHH 64
#define BB_ 64           // batch
#define MTOK (BB_*SQ)    // 12608
#define MPATCH (BB_*196) // 12544
#define NOUT 1000
#define LNN (SQ*DD)      // 151296 elems per sample
#define SQP 256          // padded seq for vT

typedef unsigned short u16;
typedef __attribute__((ext_vector_type(8))) short bf16x8;
typedef __attribute__((ext_vector_type(4))) float f32x4;

__device__ __forceinline__ u16 f2bf(float x) {      // RNE f32->bf16
    unsigned u = __float_as_uint(x);
    u = (u + 0x7FFF + ((u >> 16) & 1)) >> 16;
    return (u16)u;
}

// ---------------- pos emb (f64 for safety, tiny) ----------------
__global__ void pos_emb_kernel(float* __restrict__ pos) {
    int i = blockIdx.x * blockDim.x + threadIdx.x;
    if (i >= SQ * DD) return;
    int s = i / DD, d = i % DD;
    double e = (double)(d & ~1) / (double)DD;
    double ang = (double)s * pow(10000.0, -e);
    pos[i] = (d & 1) ? (float)cos(ang) : (float)sin(ang);
}

// ---------------- cls token row ----------------
__global__ void cls_kernel(const float* __restrict__ cls_tok,
                           const float* __restrict__ pos,
                           float* __restrict__ tokens) {
    int i = blockIdx.x * blockDim.x + threadIdx.x;
    if (i >= BB_ * DD) return;
    int b = i / DD, d = i % DD;
    tokens[(size_t)b * SQ * DD + d] = cls_tok[d] + pos[d];
}

// ---------------- f32 -> bf16 bulk convert (8 elems/thread) ----------------
__global__ __launch_bounds__(256) void conv_bf16_kernel(const float* __restrict__ in,
        u16* __restrict__ out, int n8) {
    int i = blockIdx.x * blockDim.x + threadIdx.x;
    if (i >= n8) return;
    float4 a = ((const float4*)in)[2*i];
    float4 b = ((const float4*)in)[2*i + 1];
    union { u16 u[8]; uint4 v; } r;
    r.u[0]=f2bf(a.x); r.u[1]=f2bf(a.y); r.u[2]=f2bf(a.z); r.u[3]=f2bf(a.w);
    r.u[4]=f2bf(b.x); r.u[5]=f2bf(b.y); r.u[6]=f2bf(b.z); r.u[7]=f2bf(b.w);
    ((uint4*)out)[i] = r.v;
}

// ---------------- 768x768 transpose + convert: out[n][k] = in[k][n] ----------------
__global__ __launch_bounds__(256) void transpose_bf16_kernel(const float* __restrict__ in,
        u16* __restrict__ out) {
    __shared__ float t[32][33];
    int bn = blockIdx.x * 32, bk = blockIdx.y * 32;
    int tx = threadIdx.x & 31;
#pragma unroll
    for (int r = 0; r < 4; ++r) {
        int kk = (threadIdx.x >> 5) * 4 + r;
        t[kk][tx] = in[(size_t)(bk + kk) * 768 + bn + tx];
    }
    __syncthreads();
#pragma unroll
    for (int r = 0; r < 4; ++r) {
        int nn = (threadIdx.x >> 5) * 4 + r;
        out[(size_t)(bn + nn) * 768 + bk + tx] = f2bf(t[tx][nn]);
    }
}

// ---------------- wqkv pre-transpose: wTg[m][h][e][d] bf16 ----------------
__global__ __launch_bounds__(256) void wqkv_prep(const float* __restrict__ wq,
        const float* __restrict__ wk, const float* __restrict__ wv,
        u16* __restrict__ wTg) {
    __shared__ float t[64][65];
    const int h = blockIdx.x, m = blockIdx.y;
    const float* src = ((m == 0) ? wq : (m == 1) ? wk : wv) + (size_t)h*4096;
    const int tid = threadIdx.x;
#pragma unroll
    for (int i = 0; i < 4; ++i) {
        int d = (tid >> 4) + i*16, e4 = (tid & 15) * 4;
        float4 v = *(const float4*)(src + d*64 + e4);
        t[d][e4+0] = v.x; t[d][e4+1] = v.y; t[d][e4+2] = v.z; t[d][e4+3] = v.w;
    }
    __syncthreads();
    u16* dst = wTg + ((size_t)(m*NHH + h)) * 4096;
#pragma unroll
    for (int i = 0; i < 4; ++i) {
        int e = (tid >> 4) + i*16, d4 = (tid & 15) * 4;
        union { u16 u[4]; uint2 v2; } o;
        o.u[0] = f2bf(t[d4+0][e]); o.u[1] = f2bf(t[d4+1][e]);
        o.u[2] = f2bf(t[d4+2][e]); o.u[3] = f2bf(t[d4+3][e]);
        *(uint2*)(dst + e*64 + d4) = o.v2;
    }
}

// ---------------- MFMA GEMM (embed): C[M,768] = A[M,768]bf16 * B, BT=[n][k] ----------------
__global__ __launch_bounds__(256) void gemm_mfma0(const u16* __restrict__ A,
        const u16* __restrict__ BT, const float* __restrict__ bias,
        const float* __restrict__ pos, float* __restrict__ outp, int M) {
    __shared__ u16 As[2][4096];   // [128 rows][32 k] bf16
    __shared__ u16 Bs[2][4096];
    const int tid = threadIdx.x;
    const int wv = tid >> 6, ln = tid & 63;
    const int m0 = blockIdx.x * 128, n0 = blockIdx.y * 128;
    const int wr = wv >> 1, wc = wv & 1;
    const int lrow = ln & 15, lk = ln >> 4;

    f32x4 acc[4][4];
#pragma unroll
    for (int i = 0; i < 4; ++i)
#pragma unroll
        for (int j = 0; j < 4; ++j) acc[i][j] = (f32x4){0.f, 0.f, 0.f, 0.f};

    auto stage = [&](const u16* __restrict__ src, int rowBase, int rowMax,
                     u16* lbase, int k0) {
#pragma unroll
        for (int rep = 0; rep < 2; ++rep) {
            int c = rep * 256 + wv * 64 + ln;
            int row = rowBase + (c >> 2);
            if (row > rowMax) row = rowMax;
            const void* g = (const char*)src + ((size_t)row * 768 + k0) * 2 + ((c & 3) << 4);
            void* l = (char*)lbase + rep * 4096 + wv * 1024;
            __builtin_amdgcn_global_load_lds(
                (const __attribute__((address_space(1))) unsigned int*)g,
                (__attribute__((address_space(3))) unsigned int*)l, 16, 0, 0);
        }
    };

    stage(A,  m0, M - 1,   &As[0][0], 0);
    stage(BT, n0, 767,     &Bs[0][0], 0);
    __syncthreads();

    int cur = 0;
    for (int t = 0; t < 24; ++t) {
        if (t < 23) {
            stage(A,  m0, M - 1, &As[cur ^ 1][0], (t + 1) * 32);
            stage(BT, n0, 767,   &Bs[cur ^ 1][0], (t + 1) * 32);
        }
        bf16x8 af[4], bfr[4];
#pragma unroll
        for (int i = 0; i < 4; ++i) {
            af[i]  = *(const bf16x8*)&As[cur][(wr * 64 + i * 16 + lrow) * 32 + lk * 8];
            bfr[i] = *(const bf16x8*)&Bs[cur][(wc * 64 + i * 16 + lrow) * 32 + lk * 8];
        }
#pragma unroll
        for (int i = 0; i < 4; ++i)
#pragma unroll
            for (int j = 0; j < 4; ++j)
                acc[i][j] = __builtin_amdgcn_mfma_f32_16x16x32_bf16(af[i], bfr[j], acc[i][j], 0, 0, 0);
        __syncthreads();
        cur ^= 1;
    }

#pragma unroll
    for (int i = 0; i < 4; ++i) {
        int gm = m0 + wr * 64 + i * 16 + (ln >> 4) * 4;
#pragma unroll
        for (int r = 0; r < 4; ++r) {
            int gmr = gm + r;
            if (gmr < M) {
#pragma unroll
                for (int j = 0; j < 4; ++j) {
                    int n = n0 + wc * 64 + j * 16 + (ln & 15);
                    float v = acc[i][j][r];
                    int bsmp = gmr / 196, p = gmr - bsmp * 196;
                    outp[(size_t)(gmr + bsmp + 1) * 768 + n] = v + bias[n] + pos[(size_t)(p + 1) * 768 + n];
                }
            }
        }
    }
}

// ---------------- LayerNorm1 stats over (S,D) per sample ----------------
__global__ __launch_bounds__(1024) void ln_stats(const float* __restrict__ x,
                                                 float* __restrict__ part) {
    int b = blockIdx.x, p = blockIdx.y;
    const float4* x4 = (const float4*)(x + (size_t)b*LNN + (size_t)p*(LNN/4));
    float s = 0.f, s2 = 0.f;
    for (int i = threadIdx.x; i < LNN/16; i += 1024) {
        float4 t = x4[i];
        s  += t.x + t.y + t.z + t.w;
        s2 += t.x*t.x + t.y*t.y + t.z*t.z + t.w*t.w;
    }
    for (int off = 32; off; off >>= 1) {
        s  += __shfl_down(s,  off);
        s2 += __shfl_down(s2, off);
    }
    __shared__ float r1[16], r2[16];
    int wid = threadIdx.x >> 6, lane = threadIdx.x & 63;
    if (lane == 0) { r1[wid] = s; r2[wid] = s2; }
    __syncthreads();
    if (threadIdx.x == 0) {
        float S1 = 0.f, S2 = 0.f;
        for (int i = 0; i < 16; ++i) { S1 += r1[i]; S2 += r2[i]; }
        part[b*8 + p*2 + 0] = S1;
        part[b*8 + p*2 + 1] = S2;
    }
}

// ---------------- QKV via MFMA: block = (64-token chunk, head), 4 waves ----------------
// Chunks span sample boundaries: 197 chunks x 64 = 12608 tokens exactly (no padding).
// LN1 applied per-row during X staging; weights from pre-transposed bf16 global.
__global__ __launch_bounds__(256) void qkv_mfma(const float* __restrict__ tokens,
        const float* __restrict__ part,
        const float* __restrict__ ln1_g, const float* __restrict__ ln1_b,
        const u16* __restrict__ wTg,
        const float* __restrict__ bq, const float* __restrict__ bk,
        const float* __restrict__ bv,
        u16* __restrict__ qb, u16* __restrict__ kb, u16* __restrict__ vT) {
    __shared__ u16 Xs[64*72];          // 9216 u16; reused as vstage
    __shared__ u16 Ws[3*64*72];        // 13824 u16
    const int c0 = blockIdx.x * 64, h = blockIdx.y;
    const int tid = threadIdx.x;
    const int w = tid >> 6, ln = tid & 63;
    const int lrow = ln & 15, lk = ln >> 4;

    // stage X (LN1 applied on the fly), rows = tokens c0..c0+63 (global index)
    for (int c2 = tid; c2 < 512; c2 += 256) {
        int r = c2 >> 3, q8 = (c2 & 7) * 8;
        int t = c0 + r;
        int bb = t / 197, s = t - bb * 197;
        float S1 = part[bb*8+0] + part[bb*8+2] + part[bb*8+4] + part[bb*8+6];
        float S2 = part[bb*8+1] + part[bb*8+3] + part[bb*8+5] + part[bb*8+7];
        float mu = S1 * (1.f / (float)LNN);
        float rstd = rsqrtf(S2 * (1.f / (float)LNN) - mu*mu + 1e-5f);
        const float* tp = tokens + (size_t)t*768 + h*64 + q8;
        const float* gp = ln1_g + (size_t)s*768 + h*64 + q8;
        const float* bp = ln1_b + (size_t)s*768 + h*64 + q8;
        float4 t0 = *(const float4*)tp, t1 = *(const float4*)(tp+4);
        float4 g0 = *(const float4*)gp, g1 = *(const float4*)(gp+4);
        float4 b0 = *(const float4*)bp, b1 = *(const float4*)(bp+4);
        union { u16 u[8]; uint4 v; } o;
        o.u[0] = f2bf((t0.x - mu)*rstd*g0.x + b0.x);
        o.u[1] = f2bf((t0.y - mu)*rstd*g0.y + b0.y);
        o.u[2] = f2bf((t0.z - mu)*rstd*g0.z + b0.z);
        o.u[3] = f2bf((t0.w - mu)*rstd*g0.w + b0.w);
        o.u[4] = f2bf((t1.x - mu)*rstd*g1.x + b1.x);
        o.u[5] = f2bf((t1.y - mu)*rstd*g1.y + b1.y);
        o.u[6] = f2bf((t1.z - mu)*rstd*g1.z + b1.z);
        o.u[7] = f2bf((t1.w - mu)*rstd*g1.w + b1.w);
        *(uint4*)&Xs[r*72 + q8] = o.v;
    }
    // stage W: coalesced copy of pre-transposed bf16 (no conflicts, no VALU)
    for (int idx = tid; idx < 1536; idx += 256) {
        int m = idx >> 9, rem = idx & 511;
        int e = rem >> 3, c8 = (rem & 7) * 8;
        *(uint4*)&Ws[m*4608 + e*72 + c8] =
            *(const uint4*)(wTg + ((size_t)(m*NHH + h))*4096 + e*64 + c8);
    }
    __syncthreads();

    // one merged MFMA loop: A-frags shared across q,k,v
    bf16x8 af[2];
    af[0] = *(const bf16x8*)&Xs[(w*16 + lrow)*72 + lk*8];
    af[1] = *(const bf16x8*)&Xs[(w*16 + lrow)*72 + 32 + lk*8];
    f32x4 acc[3][4];
#pragma unroll
    for (int m = 0; m < 3; ++m)
#pragma unroll
        for (int j = 0; j < 4; ++j) acc[m][j] = (f32x4){0.f,0.f,0.f,0.f};
#pragma unroll
    for (int m = 0; m < 3; ++m)
#pragma unroll
        for (int s = 0; s < 2; ++s)
#pragma unroll
            for (int j = 0; j < 4; ++j) {
                bf16x8 bfr = *(const bf16x8*)&Ws[m*4608 + (j*16 + lrow)*72 + s*32 + lk*8];
                acc[m][j] = __builtin_amdgcn_mfma_f32_16x16x32_bf16(af[s], bfr, acc[m][j], 0, 0, 0);
            }

    // write q, k (token-major, same layout as before)
#pragma unroll
    for (int m = 0; m < 2; ++m) {
        const float* bias = ((m == 0) ? bq : bk) + h*64;
        u16* dst = (m == 0) ? qb : kb;
        float bj[4];
#pragma unroll
        for (int j = 0; j < 4; ++j) bj[j] = bias[j*16 + lrow];
#pragma unroll
        for (int r = 0; r < 4; ++r) {
            int t = c0 + w*16 + lk*4 + r;
            size_t o = (size_t)t*768 + h*64;
#pragma unroll
            for (int j = 0; j < 4; ++j)
                dst[o + j*16 + lrow] = f2bf(acc[m][j][r] + bj[j]);
        }
    }

    // v: transpose via LDS (reuse Xs), then per-element writeback to vT[bh][d][s]
    {
        float bj[4];
#pragma unroll
        for (int j = 0; j < 4; ++j) bj[j] = bv[h*64 + j*16 + lrow];
        __syncthreads();                       // all waves done reading Xs
        u16* vs = Xs;                          // [64 e][72 tok]
#pragma unroll
        for (int j = 0; j < 4; ++j)
#pragma unroll
            for (int r = 0; r < 4; ++r)
                vs[(j*16 + lrow)*72 + (w*16 + lk*4 + r)] = f2bf(acc[2][j][r] + bj[j]);
        __syncthreads();
        for (int idx = tid; idx < 4096; idx += 256) {
            int d = idx >> 6, tl = idx & 63;
            int t = c0 + tl;
            int bb = t / 197, s = t - bb * 197;
            vT[((size_t)(bb*NHH + h)*64 + d)*SQP + s] = vs[d*72 + tl];
        }
    }
}

// ---------------- attention: MFMA flash, block per (b,h,qhalf of 128), 4 waves ----------------
__global__ __launch_bounds__(256) void attn_mfma(const u16* __restrict__ qb,
        const u16* __restrict__ kb, const u16* __restrict__ vT,
        float* __restrict__ tokens, float* __restrict__ part2) {
    __shared__ u16 sh[18432];                 // Qs[128][72] | Ks[64][72] | VTs[64][72]
    __shared__ float redp[8];
    u16* Qs  = sh;                            // 9216 u16
    u16* Ks  = sh + 9216;
    u16* VTs = sh + 13824;

    const int bh = blockIdx.x;
    const int b = bh / NHH, h = bh % NHH;
    const int q0 = blockIdx.y * 128;
    const int tid = threadIdx.x;
    const int w = tid >> 6, l = tid & 63;
    const int g = l >> 4, lq = l & 15;

    {
        const u16* qbase = qb + (size_t)(b*197)*768 + h*64;
#pragma unroll
        for (int it = 0; it < 8; ++it) {
            int idx = tid + it*256;
            int r = idx >> 4, c = idx & 15;
            int gr = q0 + r; if (gr > 196) gr = 196;
            *(uint2*)&Qs[r*72 + c*4] = *(const uint2*)(qbase + (size_t)gr*768 + c*4);
        }
    }

    f32x4 acco[2][4];
#pragma unroll
    for (int s2 = 0; s2 < 2; ++s2)
#pragma unroll
        for (int i = 0; i < 4; ++i) acco[s2][i] = (f32x4){0.f,0.f,0.f,0.f};
    float S[2] = {0.f, 0.f};

    const int srcA = lq + ((l & 16) ? 32 : 0);

    for (int tt = 0; tt < 4; ++tt) {
        const int t0 = tt * 64;
        __syncthreads();
        {
            const u16* krow = kb + (size_t)(b*197)*768 + h*64;
            const u16* vrow = vT + (size_t)bh*64*SQP + t0;
#pragma unroll
            for (int it = 0; it < 4; ++it) {
                int idx = tid + it*256;
                int r = idx >> 4, c = idx & 15;
                int gt = t0 + r; if (gt > 196) gt = 196;
                *(uint2*)&Ks[r*72 + c*4]  = *(const uint2*)(krow + (size_t)gt*768 + c*4);
                *(uint2*)&VTs[r*72 + c*4] = *(const uint2*)(vrow + (size_t)r*SQP + c*4);
            }
        }
        __syncthreads();

#pragma unroll
        for (int s2 = 0; s2 < 2; ++s2) {
            f32x4 accp[4];
#pragma unroll
            for (int i = 0; i < 4; ++i) accp[i] = (f32x4){0.f,0.f,0.f,0.f};
#pragma unroll
            for (int s = 0; s < 2; ++s) {
                bf16x8 qf = *(const bf16x8*)&Qs[(s2*64 + w*16 + lq)*72 + s*32 + g*8];
#pragma unroll
                for (int tb = 0; tb < 4; ++tb) {
                    bf16x8 kf = *(const bf16x8*)&Ks[(tb*16 + lq)*72 + s*32 + g*8];
                    accp[tb] = __builtin_amdgcn_mfma_f32_16x16x32_bf16(kf, qf, accp[tb], 0, 0, 0);
                }
            }

            unsigned pk[4][2];
#pragma unroll
            for (int tb = 0; tb < 4; ++tb) {
                int tbase = t0 + tb*16 + g*4;
                float p0 = (tbase + 0 < 197) ? __expf(accp[tb][0] * 0.125f) : 0.f;
                float p1 = (tbase + 1 < 197) ? __expf(accp[tb][1] * 0.125f) : 0.f;
                float p2 = (tbase + 2 < 197) ? __expf(accp[tb][2] * 0.125f) : 0.f;
                float p3 = (tbase + 3 < 197) ? __expf(accp[tb][3] * 0.125f) : 0.f;
                S[s2] += (p0 + p1) + (p2 + p3);
                asm("v_cvt_pk_bf16_f32 %0, %1, %2" : "=v"(pk[tb][0]) : "v"(p0), "v"(p1));
                asm("v_cvt_pk_bf16_f32 %0, %1, %2" : "=v"(pk[tb][1]) : "v"(p2), "v"(p3));
            }

#pragma unroll
            for (int s = 0; s < 2; ++s) {
                union { unsigned u[4]; bf16x8 v; } bp;
#pragma unroll
                for (int c = 0; c < 4; ++c) {
                    int src = srcA + ((c >= 2) ? 16 : 0);
                    unsigned v0 = (unsigned)__shfl((int)pk[2*s + 0][c & 1], src);
                    unsigned v1 = (unsigned)__shfl((int)pk[2*s + 1][c & 1], src);
                    bp.u[c] = (l & 32) ? v1 : v0;
                }
#pragma unroll
                for (int dblk = 0; dblk < 4; ++dblk) {
                    bf16x8 vf = *(const bf16x8*)&VTs[(dblk*16 + lq)*72 + s*32 + g*8];
                    acco[s2][dblk] = __builtin_amdgcn_mfma_f32_16x16x32_bf16(vf, bp.v, acco[s2][dblk], 0, 0, 0);
                }
            }
        }
    }

    float invS[2];
#pragma unroll
    for (int s2 = 0; s2 < 2; ++s2) {
        S[s2] += __shfl_xor(S[s2], 16);
        S[s2] += __shfl_xor(S[s2], 32);
        invS[s2] = 1.f / S[s2];
    }

    float* Osh = (float*)sh;                  // 4 waves x [64][17] f32 = 17408 B
    float ps = 0.f, ps2v = 0.f;
    const int q_l = tid >> 2, dc = tid & 3;
#pragma unroll
    for (int s2 = 0; s2 < 2; ++s2) {
        __syncthreads();
        float* os = Osh + w * 1088;
#pragma unroll
        for (int dblk = 0; dblk < 4; ++dblk)
#pragma unroll
            for (int r = 0; r < 4; ++r)
                os[(dblk*16 + g*4 + r)*17 + lq] = acco[s2][dblk][r] * invS[s2];
        __syncthreads();

        const int s_tok = q0 + s2*64 + q_l;
        if (s_tok < 197) {
            const float* osr = Osh + (q_l >> 4)*1088;
            const int ql = q_l & 15;
            float* dst = tokens + (size_t)(b*197 + s_tok)*768 + h*64 + dc*16;
#pragma unroll
            for (int c4 = 0; c4 < 4; ++c4) {
                float4 t = *(float4*)&dst[c4*4];
                t.x += osr[(dc*16 + c4*4 + 0)*17 + ql];
                t.y += osr[(dc*16 + c4*4 + 1)*17 + ql];
                t.z += osr[(dc*16 + c4*4 + 2)*17 + ql];
                t.w += osr[(dc*16 + c4*4 + 3)*17 + ql];
                *(float4*)&dst[c4*4] = t;
                ps   += (t.x + t.y) + (t.z + t.w);
                ps2v += (t.x*t.x + t.y*t.y) + (t.z*t.z + t.w*t.w);
            }
        }
    }

#pragma unroll
    for (int off = 1; off < 64; off <<= 1) {
        ps   += __shfl_xor(ps,   off);
        ps2v += __shfl_xor(ps2v, off);
    }
    if (l == 0) { redp[w*2] = ps; redp[w*2 + 1] = ps2v; }
    __syncthreads();
    if (tid == 0) {
        float a = redp[0] + redp[2] + redp[4] + redp[6];
        float c = redp[1] + redp[3] + redp[5] + redp[7];
        int slot = bh*2 + blockIdx.y;
        part2[slot*2]     = a;
        part2[slot*2 + 1] = c;
    }
}

// ---------------- fused ln2(row0) + MLP(row0) + residual: cls rows only ----------------
__global__ __launch_bounds__(256) void mlp_cls(const float* __restrict__ tokens,
        const float* __restrict__ part2, const float* __restrict__ ln2_g,
        const float* __restrict__ ln2_b, const float* __restrict__ w_enc,
        const float* __restrict__ b_enc, float* __restrict__ mlp_out) {
    __shared__ float y0[768];
    const int b = blockIdx.x, tid = threadIdx.x;
    float s1 = 0.f, s2 = 0.f;
    for (int i = 0; i < 24; ++i) {
        s1 += part2[(b*24 + i)*2];
        s2 += part2[(b*24 + i)*2 + 1];
    }
    float mu = s1 * (1.f / (float)LNN);
    float var = s2 * (1.f / (float)LNN) - mu*mu;
    float rstd = rsqrtf(var + 1e-5f);
    const float* crow = tokens + (size_t)b * 197 * 768;   // cls row
    for (int d = tid; d < 768; d += 256)
        y0[d] = (crow[d] - mu) * rstd * ln2_g[d] + ln2_b[d];
    __syncthreads();
    const int n = blockIdx.y * 256 + tid;                 // grid.y = 3 -> n < 768
    float acc = b_enc[n];
#pragma unroll 8
    for (int k = 0; k < 768; ++k) acc += y0[k] * w_enc[(size_t)k*768 + n];
    mlp_out[(size_t)b*768 + n] = crow[n] + fmaxf(acc, 0.f);
}

// ---------------- head: logits (parallel) + softmax ----------------
__global__ __launch_bounds__(256) void logits_kernel(const float* __restrict__ xin,
        const float* __restrict__ w_head, const float* __restrict__ b_head,
        float* __restrict__ logits) {
    __shared__ float xr[768];
    const int b = blockIdx.x;
    const int o = blockIdx.y * 256 + threadIdx.x;
    for (int i = threadIdx.x; i < 768; i += 256) xr[i] = xin[(size_t)b*768 + i];
    __syncthreads();
    if (o < NOUT) {
        float acc = b_head[o];
#pragma unroll 8
        for (int d = 0; d < 768; ++d) acc += xr[d] * w_head[(size_t)d*NOUT + o];
        logits[(size_t)b*NOUT + o] = acc;
    }
}

__global__ __launch_bounds__(256) void softmax_kernel(const float* __restrict__ logits,
        float* __restrict__ outp) {
    __shared__ float red[8];
    const int b = blockIdx.x, tid = threadIdx.x;
    const float* lrow = logits + (size_t)b*NOUT;
    const int w = tid >> 6, l = tid & 63;
    float v[4];
    float mx = -1e30f;
#pragma unroll
    for (int i = 0; i < 4; ++i) {
        int t = tid + i*256;
        v[i] = (t < NOUT) ? lrow[t] : -1e30f;
        mx = fmaxf(mx, v[i]);
    }
    for (int off = 32; off; off >>= 1) mx = fmaxf(mx, __shfl_xor(mx, off));
    if (l == 0) red[w] = mx;
    __syncthreads();
    if (tid == 0) red[4] = fmaxf(fmaxf(red[0], red[1]), fmaxf(red[2], red[3]));
    __syncthreads();
    const float m = red[4];
    float s = 0.f;
#pragma unroll
    for (int i = 0; i < 4; ++i) { v[i] = __expf(v[i] - m); s += v[i]; }
    for (int off = 32; off; off >>= 1) s += __shfl_xor(s, off);
    if (l == 0) red[w] = s;
    __syncthreads();
    if (tid == 0) red[5] = red[0] + red[1] + red[2] + red[3];
    __syncthreads();
    const float inv = 1.f / red[5];
#pragma unroll
    for (int i = 0; i < 4; ++i) {
        int t = tid + i*256;
        if (t < NOUT) outp[(size_t)b*NOUT + t] = v[i] * inv;
    }
}

// ---------------- launch ----------------
extern "C" void kernel_launch(void* const* d_in, const int* in_sizes, int n_in,
                              void* d_out, int out_size, void* d_ws, size_t ws_size,
                              hipStream_t stream) {
    (void)in_sizes; (void)n_in; (void)out_size; (void)ws_size;
    const float* images = (const float*)d_in[0];
    const float* w_map  = (const float*)d_in[1];
    const float* b_map  = (const float*)d_in[2];
    const float* cls_tok= (const float*)d_in[3];
    const float* ln1_g  = (const float*)d_in[4];
    const float* ln1_b  = (const float*)d_in[5];
    const float* wq     = (const float*)d_in[6];
    const float* bq     = (const float*)d_in[7];
    const float* wk     = (const float*)d_in[8];
    const float* bk     = (const float*)d_in[9];
    const float* wv     = (const float*)d_in[10];
    const float* bv     = (const float*)d_in[11];
    const float* ln2_g  = (const float*)d_in[12];
    const float* ln2_b  = (const float*)d_in[13];
    const float* w_enc  = (const float*)d_in[14];
    const float* b_enc  = (const float*)d_in[15];
    const float* w_head = (const float*)d_in[16];
    const float* b_head = (const float*)d_in[17];
    float* out = (float*)d_out;
    float* ws = (float*)d_ws;

    float* pos    = ws;                     // 151296
    float* tokens = pos + 151296;           // 9682944 f32 (residual, updated in-place by attn)
    float* x      = tokens + 9682944;       // spare (layout stability)
    float* q      = x + 9682944;            // imb overlay, then qb
    float* kk     = q + 9682944;            // wt(w_map) overlay, then kb
    float* vv     = kk + 9682944;           // vT bf16 [768][64][256]
    float* part   = vv + 9682944;           // 512 (ln1 partial stats)
    float* part2  = part + 512;             // 3072 (ln2 per-(b,h,qhalf) partials)
    float* mlp_o  = part2 + 3072;           // 49152 (final cls rows, f32)
    float* logit  = mlp_o + 49152;          // 64000
    float* wqkvT  = logit + 64000;          // 73728 f32-slots = 147456 u16 bf16

    u16* imb = (u16*)q;
    u16* wt  = (u16*)kk;
    u16* qbp = (u16*)q;
    u16* kbp = (u16*)kk;
    u16* vTp = (u16*)vv;
    u16* wTg = (u16*)wqkvT;

    pos_emb_kernel<<<(SQ*DD + 255)/256, 256, 0, stream>>>(pos);
    cls_kernel<<<(BB_*DD + 255)/256, 256, 0, stream>>>(cls_tok, pos, tokens);
    conv_bf16_kernel<<<(MPATCH*768/8 + 255)/256, 256, 0, stream>>>(images, imb, MPATCH*768/8);
    transpose_bf16_kernel<<<dim3(24, 24), 256, 0, stream>>>(w_map, wt);
    wqkv_prep<<<dim3(NHH, 3), 256, 0, stream>>>(wq, wk, wv, wTg);
    gemm_mfma0<<<dim3(98, 6), 256, 0, stream>>>(imb, wt, b_map, pos, tokens, MPATCH);
    ln_stats<<<dim3(64, 4), 1024, 0, stream>>>(tokens, part);
    qkv_mfma<<<dim3(197, NHH), 256, 0, stream>>>(tokens, part, ln1_g, ln1_b, wTg,
                                                 bq, bk, bv, qbp, kbp, vTp);
    attn_mfma<<<dim3(BB_*NHH, 2), 256, 0, stream>>>(qbp, kbp, vTp, tokens, part2);
    mlp_cls<<<dim3(BB_, 3), 256, 0, stream>>>(tokens, part2, ln2_g, ln2_b, w_enc, b_enc, mlp_o);
    logits_kernel<<<dim3(BB_, 4), 256, 0, stream>>>(mlp_o, w_head, b_head, logit);
    softmax_kernel<<<BB_, 256, 0, stream>>>(logit, out);
}

// Round 10
// 209.111 us; speedup vs baseline: 1.3009x; 1.0346x over previous
//
#include <hip/hip_runtime.h>
#include <math.h>

// ---------------- dims ----------------
#define SQ 197           // tokens
#define DD 768           // hidden
#define NHH 12
#define DHH 64
#define BB_ 64           // batch
#define MTOK (BB_*SQ)    // 12608
#define MPATCH (BB_*196) // 12544
#define NOUT 1000
#define LNN (SQ*DD)      // 151296 elems per sample
#define SQP 256          // padded seq for vT

typedef unsigned short u16;
typedef __attribute__((ext_vector_type(8))) short bf16x8;
typedef __attribute__((ext_vector_type(4))) float f32x4;

__device__ __forceinline__ u16 f2bf(float x) {      // RNE f32->bf16
    unsigned u = __float_as_uint(x);
    u = (u + 0x7FFF + ((u >> 16) & 1)) >> 16;
    return (u16)u;
}

// ---------------- pos emb (f64 for safety, tiny) ----------------
__global__ void pos_emb_kernel(float* __restrict__ pos) {
    int i = blockIdx.x * blockDim.x + threadIdx.x;
    if (i >= SQ * DD) return;
    int s = i / DD, d = i % DD;
    double e = (double)(d & ~1) / (double)DD;
    double ang = (double)s * pow(10000.0, -e);
    pos[i] = (d & 1) ? (float)cos(ang) : (float)sin(ang);
}

// ---------------- cls token row + LN1 partials ----------------
__global__ __launch_bounds__(256) void cls_kernel(const float* __restrict__ cls_tok,
                           const float* __restrict__ pos,
                           float* __restrict__ tokens, float* __restrict__ cpart) {
    __shared__ float red[8];
    const int i = blockIdx.x * 256 + threadIdx.x;   // 192 blocks, 3 per sample
    const int b = i / DD, d = i % DD;
    float v = cls_tok[d] + pos[d];
    tokens[(size_t)b * SQ * DD + d] = v;
    float ps = v, ps2 = v * v;
    const int w = threadIdx.x >> 6, l = threadIdx.x & 63;
#pragma unroll
    for (int off = 1; off < 64; off <<= 1) {
        ps  += __shfl_xor(ps,  off);
        ps2 += __shfl_xor(ps2, off);
    }
    if (l == 0) { red[w*2] = ps; red[w*2+1] = ps2; }
    __syncthreads();
    if (threadIdx.x == 0) {
        cpart[blockIdx.x*2]     = red[0] + red[2] + red[4] + red[6];
        cpart[blockIdx.x*2 + 1] = red[1] + red[3] + red[5] + red[7];
    }
}

// ---------------- f32 -> bf16 bulk convert (8 elems/thread) ----------------
__global__ __launch_bounds__(256) void conv_bf16_kernel(const float* __restrict__ in,
        u16* __restrict__ out, int n8) {
    int i = blockIdx.x * blockDim.x + threadIdx.x;
    if (i >= n8) return;
    float4 a = ((const float4*)in)[2*i];
    float4 b = ((const float4*)in)[2*i + 1];
    union { u16 u[8]; uint4 v; } r;
    r.u[0]=f2bf(a.x); r.u[1]=f2bf(a.y); r.u[2]=f2bf(a.z); r.u[3]=f2bf(a.w);
    r.u[4]=f2bf(b.x); r.u[5]=f2bf(b.y); r.u[6]=f2bf(b.z); r.u[7]=f2bf(b.w);
    ((uint4*)out)[i] = r.v;
}

// ---------------- 768x768 transpose + convert: out[n][k] = in[k][n] ----------------
__global__ __launch_bounds__(256) void transpose_bf16_kernel(const float* __restrict__ in,
        u16* __restrict__ out) {
    __shared__ float t[32][33];
    int bn = blockIdx.x * 32, bk = blockIdx.y * 32;
    int tx = threadIdx.x & 31;
#pragma unroll
    for (int r = 0; r < 4; ++r) {
        int kk = (threadIdx.x >> 5) * 4 + r;
        t[kk][tx] = in[(size_t)(bk + kk) * 768 + bn + tx];
    }
    __syncthreads();
#pragma unroll
    for (int r = 0; r < 4; ++r) {
        int nn = (threadIdx.x >> 5) * 4 + r;
        out[(size_t)(bn + nn) * 768 + bk + tx] = f2bf(t[tx][nn]);
    }
}

// ---------------- wqkv pre-transpose: wTg[m][h][e][d] bf16 ----------------
__global__ __launch_bounds__(256) void wqkv_prep(const float* __restrict__ wq,
        const float* __restrict__ wk, const float* __restrict__ wv,
        u16* __restrict__ wTg) {
    __shared__ float t[64][65];
    const int h = blockIdx.x, m = blockIdx.y;
    const float* src = ((m == 0) ? wq : (m == 1) ? wk : wv) + (size_t)h*4096;
    const int tid = threadIdx.x;
#pragma unroll
    for (int i = 0; i < 4; ++i) {
        int d = (tid >> 4) + i*16, e4 = (tid & 15) * 4;
        float4 v = *(const float4*)(src + d*64 + e4);
        t[d][e4+0] = v.x; t[d][e4+1] = v.y; t[d][e4+2] = v.z; t[d][e4+3] = v.w;
    }
    __syncthreads();
    u16* dst = wTg + ((size_t)(m*NHH + h)) * 4096;
#pragma unroll
    for (int i = 0; i < 4; ++i) {
        int e = (tid >> 4) + i*16, d4 = (tid & 15) * 4;
        union { u16 u[4]; uint2 v2; } o;
        o.u[0] = f2bf(t[d4+0][e]); o.u[1] = f2bf(t[d4+1][e]);
        o.u[2] = f2bf(t[d4+2][e]); o.u[3] = f2bf(t[d4+3][e]);
        *(uint2*)(dst + e*64 + d4) = o.v2;
    }
}

// ---------------- MFMA GEMM (embed) + fused LN1 partials ----------------
__global__ __launch_bounds__(256) void gemm_mfma0(const u16* __restrict__ A,
        const u16* __restrict__ BT, const float* __restrict__ bias,
        const float* __restrict__ pos, float* __restrict__ outp, int M,
        float* __restrict__ gpart) {
    __shared__ u16 As[2][4096];   // [128 rows][32 k] bf16
    __shared__ u16 Bs[2][4096];
    __shared__ float redg[16];
    const int tid = threadIdx.x;
    const int wv = tid >> 6, ln = tid & 63;
    const int m0 = blockIdx.x * 128, n0 = blockIdx.y * 128;
    const int wr = wv >> 1, wc = wv & 1;
    const int lrow = ln & 15, lk = ln >> 4;
    const int s0 = m0 / 196;

    f32x4 acc[4][4];
#pragma unroll
    for (int i = 0; i < 4; ++i)
#pragma unroll
        for (int j = 0; j < 4; ++j) acc[i][j] = (f32x4){0.f, 0.f, 0.f, 0.f};

    auto stage = [&](const u16* __restrict__ src, int rowBase, int rowMax,
                     u16* lbase, int k0) {
#pragma unroll
        for (int rep = 0; rep < 2; ++rep) {
            int c = rep * 256 + wv * 64 + ln;
            int row = rowBase + (c >> 2);
            if (row > rowMax) row = rowMax;
            const void* g = (const char*)src + ((size_t)row * 768 + k0) * 2 + ((c & 3) << 4);
            void* l = (char*)lbase + rep * 4096 + wv * 1024;
            __builtin_amdgcn_global_load_lds(
                (const __attribute__((address_space(1))) unsigned int*)g,
                (__attribute__((address_space(3))) unsigned int*)l, 16, 0, 0);
        }
    };

    stage(A,  m0, M - 1,   &As[0][0], 0);
    stage(BT, n0, 767,     &Bs[0][0], 0);
    __syncthreads();

    int cur = 0;
    for (int t = 0; t < 24; ++t) {
        if (t < 23) {
            stage(A,  m0, M - 1, &As[cur ^ 1][0], (t + 1) * 32);
            stage(BT, n0, 767,   &Bs[cur ^ 1][0], (t + 1) * 32);
        }
        bf16x8 af[4], bfr[4];
#pragma unroll
        for (int i = 0; i < 4; ++i) {
            af[i]  = *(const bf16x8*)&As[cur][(wr * 64 + i * 16 + lrow) * 32 + lk * 8];
            bfr[i] = *(const bf16x8*)&Bs[cur][(wc * 64 + i * 16 + lrow) * 32 + lk * 8];
        }
#pragma unroll
        for (int i = 0; i < 4; ++i)
#pragma unroll
            for (int j = 0; j < 4; ++j)
                acc[i][j] = __builtin_amdgcn_mfma_f32_16x16x32_bf16(af[i], bfr[j], acc[i][j], 0, 0, 0);
        __syncthreads();
        cur ^= 1;
    }

    float psA = 0.f, ps2A = 0.f, psB = 0.f, ps2B = 0.f;
#pragma unroll
    for (int i = 0; i < 4; ++i) {
        int gm = m0 + wr * 64 + i * 16 + (ln >> 4) * 4;
#pragma unroll
        for (int r = 0; r < 4; ++r) {
            int gmr = gm + r;
            if (gmr < M) {
                int bsmp = gmr / 196, p = gmr - bsmp * 196;
#pragma unroll
                for (int j = 0; j < 4; ++j) {
                    int n = n0 + wc * 64 + j * 16 + (ln & 15);
                    float v = acc[i][j][r] + bias[n] + pos[(size_t)(p + 1) * 768 + n];
                    outp[(size_t)(gmr + bsmp + 1) * 768 + n] = v;
                    if (bsmp == s0) { psA += v; ps2A += v*v; }
                    else            { psB += v; ps2B += v*v; }
                }
            }
        }
    }
    // block-reduce LN1 partials -> deterministic slot (2 samples max per block)
#pragma unroll
    for (int off = 1; off < 64; off <<= 1) {
        psA  += __shfl_xor(psA,  off);  ps2A += __shfl_xor(ps2A, off);
        psB  += __shfl_xor(psB,  off);  ps2B += __shfl_xor(ps2B, off);
    }
    __syncthreads();
    if (ln == 0) {
        redg[wv*4+0] = psA; redg[wv*4+1] = ps2A;
        redg[wv*4+2] = psB; redg[wv*4+3] = ps2B;
    }
    __syncthreads();
    if (tid == 0) {
        float a = redg[0]+redg[4]+redg[8]+redg[12];
        float b = redg[1]+redg[5]+redg[9]+redg[13];
        float c = redg[2]+redg[6]+redg[10]+redg[14];
        float d = redg[3]+redg[7]+redg[11]+redg[15];
        float* gp = gpart + (size_t)(blockIdx.x*6 + blockIdx.y)*4;
        gp[0] = a; gp[1] = b; gp[2] = c; gp[3] = d;
    }
}

// ---------------- LN1 partial reducer: 64 blocks (1/sample), 64 threads ----------------
__global__ __launch_bounds__(64) void reduce_ln1(const float* __restrict__ gpart,
        const float* __restrict__ cpart, float* __restrict__ part) {
    const int b = blockIdx.x, t = threadIdx.x;
    float s1 = 0.f, s2 = 0.f;
    for (int grp = t; grp < 98*6; grp += 64) {
        int bx = grp / 6;
        int sA = (bx * 128) / 196;
        const float* gp = gpart + (size_t)grp*4;
        if (sA == b)     { s1 += gp[0]; s2 += gp[1]; }
        if (sA + 1 == b) { s1 += gp[2]; s2 += gp[3]; }
    }
#pragma unroll
    for (int off = 1; off < 64; off <<= 1) {
        s1 += __shfl_xor(s1, off);
        s2 += __shfl_xor(s2, off);
    }
    if (t == 0) {
#pragma unroll
        for (int i = 0; i < 3; ++i) {
            s1 += cpart[(b*3 + i)*2];
            s2 += cpart[(b*3 + i)*2 + 1];
        }
        part[b*8 + 0] = s1;
        part[b*8 + 1] = s2;
#pragma unroll
        for (int i = 2; i < 8; ++i) part[b*8 + i] = 0.f;
    }
}

// ---------------- QKV via MFMA: block = (64-token chunk, head), 4 waves ----------------
__global__ __launch_bounds__(256) void qkv_mfma(const float* __restrict__ tokens,
        const float* __restrict__ part,
        const float* __restrict__ ln1_g, const float* __restrict__ ln1_b,
        const u16* __restrict__ wTg,
        const float* __restrict__ bq, const float* __restrict__ bk,
        const float* __restrict__ bv,
        u16* __restrict__ qb, u16* __restrict__ kb, u16* __restrict__ vT) {
    __shared__ u16 Xs[64*72];          // 9216 u16; reused as vstage
    __shared__ u16 Ws[3*64*72];        // 13824 u16
    const int c0 = blockIdx.x * 64, h = blockIdx.y;
    const int tid = threadIdx.x;
    const int w = tid >> 6, ln = tid & 63;
    const int lrow = ln & 15, lk = ln >> 4;

    for (int c2 = tid; c2 < 512; c2 += 256) {
        int r = c2 >> 3, q8 = (c2 & 7) * 8;
        int t = c0 + r;
        int bb = t / 197, s = t - bb * 197;
        float S1 = part[bb*8+0] + part[bb*8+2] + part[bb*8+4] + part[bb*8+6];
        float S2 = part[bb*8+1] + part[bb*8+3] + part[bb*8+5] + part[bb*8+7];
        float mu = S1 * (1.f / (float)LNN);
        float rstd = rsqrtf(S2 * (1.f / (float)LNN) - mu*mu + 1e-5f);
        const float* tp = tokens + (size_t)t*768 + h*64 + q8;
        const float* gp = ln1_g + (size_t)s*768 + h*64 + q8;
        const float* bp = ln1_b + (size_t)s*768 + h*64 + q8;
        float4 t0 = *(const float4*)tp, t1 = *(const float4*)(tp+4);
        float4 g0 = *(const float4*)gp, g1 = *(const float4*)(gp+4);
        float4 b0 = *(const float4*)bp, b1 = *(const float4*)(bp+4);
        union { u16 u[8]; uint4 v; } o;
        o.u[0] = f2bf((t0.x - mu)*rstd*g0.x + b0.x);
        o.u[1] = f2bf((t0.y - mu)*rstd*g0.y + b0.y);
        o.u[2] = f2bf((t0.z - mu)*rstd*g0.z + b0.z);
        o.u[3] = f2bf((t0.w - mu)*rstd*g0.w + b0.w);
        o.u[4] = f2bf((t1.x - mu)*rstd*g1.x + b1.x);
        o.u[5] = f2bf((t1.y - mu)*rstd*g1.y + b1.y);
        o.u[6] = f2bf((t1.z - mu)*rstd*g1.z + b1.z);
        o.u[7] = f2bf((t1.w - mu)*rstd*g1.w + b1.w);
        *(uint4*)&Xs[r*72 + q8] = o.v;
    }
    for (int idx = tid; idx < 1536; idx += 256) {
        int m = idx >> 9, rem = idx & 511;
        int e = rem >> 3, c8 = (rem & 7) * 8;
        *(uint4*)&Ws[m*4608 + e*72 + c8] =
            *(const uint4*)(wTg + ((size_t)(m*NHH + h))*4096 + e*64 + c8);
    }
    __syncthreads();

    bf16x8 af[2];
    af[0] = *(const bf16x8*)&Xs[(w*16 + lrow)*72 + lk*8];
    af[1] = *(const bf16x8*)&Xs[(w*16 + lrow)*72 + 32 + lk*8];
    f32x4 acc[3][4];
#pragma unroll
    for (int m = 0; m < 3; ++m)
#pragma unroll
        for (int j = 0; j < 4; ++j) acc[m][j] = (f32x4){0.f,0.f,0.f,0.f};
#pragma unroll
    for (int m = 0; m < 3; ++m)
#pragma unroll
        for (int s = 0; s < 2; ++s)
#pragma unroll
            for (int j = 0; j < 4; ++j) {
                bf16x8 bfr = *(const bf16x8*)&Ws[m*4608 + (j*16 + lrow)*72 + s*32 + lk*8];
                acc[m][j] = __builtin_amdgcn_mfma_f32_16x16x32_bf16(af[s], bfr, acc[m][j], 0, 0, 0);
            }

#pragma unroll
    for (int m = 0; m < 2; ++m) {
        const float* bias = ((m == 0) ? bq : bk) + h*64;
        u16* dst = (m == 0) ? qb : kb;
        float bj[4];
#pragma unroll
        for (int j = 0; j < 4; ++j) bj[j] = bias[j*16 + lrow];
#pragma unroll
        for (int r = 0; r < 4; ++r) {
            int t = c0 + w*16 + lk*4 + r;
            size_t o = (size_t)t*768 + h*64;
#pragma unroll
            for (int j = 0; j < 4; ++j)
                dst[o + j*16 + lrow] = f2bf(acc[m][j][r] + bj[j]);
        }
    }

    {
        float bj[4];
#pragma unroll
        for (int j = 0; j < 4; ++j) bj[j] = bv[h*64 + j*16 + lrow];
        __syncthreads();
        u16* vs = Xs;                          // [64 e][72 tok]
#pragma unroll
        for (int j = 0; j < 4; ++j)
#pragma unroll
            for (int r = 0; r < 4; ++r)
                vs[(j*16 + lrow)*72 + (w*16 + lk*4 + r)] = f2bf(acc[2][j][r] + bj[j]);
        __syncthreads();
        for (int idx = tid; idx < 4096; idx += 256) {
            int d = idx >> 6, tl = idx & 63;
            int t = c0 + tl;
            int bb = t / 197, s = t - bb * 197;
            vT[((size_t)(bb*NHH + h)*64 + d)*SQP + s] = vs[d*72 + tl];
        }
    }
}

// ---------------- attention: MFMA flash, register-prefetched K/V staging ----------------
__global__ __launch_bounds__(256) void attn_mfma(const u16* __restrict__ qb,
        const u16* __restrict__ kb, const u16* __restrict__ vT,
        float* __restrict__ tokens, float* __restrict__ part2) {
    __shared__ u16 sh[18432];                 // Qs[128][72] | Ks[64][72] | VTs[64][72]
    __shared__ float redp[8];
    u16* Qs  = sh;                            // 9216 u16
    u16* Ks  = sh + 9216;
    u16* VTs = sh + 13824;

    const int bh = blockIdx.x;
    const int b = bh / NHH, h = bh % NHH;
    const int q0 = blockIdx.y * 128;
    const int tid = threadIdx.x;
    const int w = tid >> 6, l = tid & 63;
    const int g = l >> 4, lq = l & 15;

    {
        const u16* qbase = qb + (size_t)(b*197)*768 + h*64;
#pragma unroll
        for (int it = 0; it < 8; ++it) {
            int idx = tid + it*256;
            int r = idx >> 4, c = idx & 15;
            int gr = q0 + r; if (gr > 196) gr = 196;
            *(uint2*)&Qs[r*72 + c*4] = *(const uint2*)(qbase + (size_t)gr*768 + c*4);
        }
    }

    f32x4 acco[2][4];
#pragma unroll
    for (int s2 = 0; s2 < 2; ++s2)
#pragma unroll
        for (int i = 0; i < 4; ++i) acco[s2][i] = (f32x4){0.f,0.f,0.f,0.f};
    float S[2] = {0.f, 0.f};

    const int srcA = lq + ((l & 16) ? 32 : 0);
    const u16* krow = kb + (size_t)(b*197)*768 + h*64;
    const u16* vbase = vT + (size_t)bh*64*SQP;

    // register prefetch of K/V tile (T14 async-STAGE split)
    uint2 kreg[4], vreg[4];
    auto issue = [&](int tt) {
        const int t0 = tt * 64;
#pragma unroll
        for (int it = 0; it < 4; ++it) {
            int idx = tid + it*256;
            int r = idx >> 4, c = idx & 15;
            int gt = t0 + r; if (gt > 196) gt = 196;
            kreg[it] = *(const uint2*)(krow + (size_t)gt*768 + c*4);
            vreg[it] = *(const uint2*)(vbase + (size_t)(t0 + r)*0 + (size_t)r*SQP + t0 + c*4 - t0);
        }
    };
    // (note: V row layout is vT[bh][d][s]; tile tt uses cols t0..t0+63 of rows d=r)
    auto issueKV = [&](int tt) {
        const int t0 = tt * 64;
#pragma unroll
        for (int it = 0; it < 4; ++it) {
            int idx = tid + it*256;
            int r = idx >> 4, c = idx & 15;
            int gt = t0 + r; if (gt > 196) gt = 196;
            kreg[it] = *(const uint2*)(krow + (size_t)gt*768 + c*4);
            vreg[it] = *(const uint2*)(vbase + (size_t)r*SQP + t0 + c*4);
        }
    };
    (void)issue;
    issueKV(0);

    for (int tt = 0; tt < 4; ++tt) {
        __syncthreads();                      // Ks/VTs free (prev compute done)
#pragma unroll
        for (int it = 0; it < 4; ++it) {
            int idx = tid + it*256;
            int r = idx >> 4, c = idx & 15;
            *(uint2*)&Ks[r*72 + c*4]  = kreg[it];
            *(uint2*)&VTs[r*72 + c*4] = vreg[it];
        }
        if (tt < 3) issueKV(tt + 1);          // loads fly during compute below
        __syncthreads();

        const int t0 = tt * 64;
#pragma unroll
        for (int s2 = 0; s2 < 2; ++s2) {
            f32x4 accp[4];
#pragma unroll
            for (int i = 0; i < 4; ++i) accp[i] = (f32x4){0.f,0.f,0.f,0.f};
#pragma unroll
            for (int s = 0; s < 2; ++s) {
                bf16x8 qf = *(const bf16x8*)&Qs[(s2*64 + w*16 + lq)*72 + s*32 + g*8];
#pragma unroll
                for (int tb = 0; tb < 4; ++tb) {
                    bf16x8 kf = *(const bf16x8*)&Ks[(tb*16 + lq)*72 + s*32 + g*8];
                    accp[tb] = __builtin_amdgcn_mfma_f32_16x16x32_bf16(kf, qf, accp[tb], 0, 0, 0);
                }
            }

            unsigned pk[4][2];
#pragma unroll
            for (int tb = 0; tb < 4; ++tb) {
                int tbase = t0 + tb*16 + g*4;
                float p0 = (tbase + 0 < 197) ? __expf(accp[tb][0] * 0.125f) : 0.f;
                float p1 = (tbase + 1 < 197) ? __expf(accp[tb][1] * 0.125f) : 0.f;
                float p2 = (tbase + 2 < 197) ? __expf(accp[tb][2] * 0.125f) : 0.f;
                float p3 = (tbase + 3 < 197) ? __expf(accp[tb][3] * 0.125f) : 0.f;
                S[s2] += (p0 + p1) + (p2 + p3);
                asm("v_cvt_pk_bf16_f32 %0, %1, %2" : "=v"(pk[tb][0]) : "v"(p0), "v"(p1));
                asm("v_cvt_pk_bf16_f32 %0, %1, %2" : "=v"(pk[tb][1]) : "v"(p2), "v"(p3));
            }

#pragma unroll
            for (int s = 0; s < 2; ++s) {
                union { unsigned u[4]; bf16x8 v; } bp;
#pragma unroll
                for (int c = 0; c < 4; ++c) {
                    int src = srcA + ((c >= 2) ? 16 : 0);
                    unsigned v0 = (unsigned)__shfl((int)pk[2*s + 0][c & 1], src);
                    unsigned v1 = (unsigned)__shfl((int)pk[2*s + 1][c & 1], src);
                    bp.u[c] = (l & 32) ? v1 : v0;
                }
#pragma unroll
                for (int dblk = 0; dblk < 4; ++dblk) {
                    bf16x8 vf = *(const bf16x8*)&VTs[(dblk*16 + lq)*72 + s*32 + g*8];
                    acco[s2][dblk] = __builtin_amdgcn_mfma_f32_16x16x32_bf16(vf, bp.v, acco[s2][dblk], 0, 0, 0);
                }
            }
        }
    }

    float invS[2];
#pragma unroll
    for (int s2 = 0; s2 < 2; ++s2) {
        S[s2] += __shfl_xor(S[s2], 16);
        S[s2] += __shfl_xor(S[s2], 32);
        invS[s2] = 1.f / S[s2];
    }

    float* Osh = (float*)sh;                  // 4 waves x [64][17] f32 = 17408 B
    float ps = 0.f, ps2v = 0.f;
    const int q_l = tid >> 2, dc = tid & 3;
#pragma unroll
    for (int s2 = 0; s2 < 2; ++s2) {
        __syncthreads();
        float* os = Osh + w * 1088;
#pragma unroll
        for (int dblk = 0; dblk < 4; ++dblk)
#pragma unroll
            for (int r = 0; r < 4; ++r)
                os[(dblk*16 + g*4 + r)*17 + lq] = acco[s2][dblk][r] * invS[s2];
        __syncthreads();

        const int s_tok = q0 + s2*64 + q_l;
        if (s_tok < 197) {
            const float* osr = Osh + (q_l >> 4)*1088;
            const int ql = q_l & 15;
            float* dst = tokens + (size_t)(b*197 + s_tok)*768 + h*64 + dc*16;
#pragma unroll
            for (int c4 = 0; c4 < 4; ++c4) {
                float4 t = *(float4*)&dst[c4*4];
                t.x += osr[(dc*16 + c4*4 + 0)*17 + ql];
                t.y += osr[(dc*16 + c4*4 + 1)*17 + ql];
                t.z += osr[(dc*16 + c4*4 + 2)*17 + ql];
                t.w += osr[(dc*16 + c4*4 + 3)*17 + ql];
                *(float4*)&dst[c4*4] = t;
                ps   += (t.x + t.y) + (t.z + t.w);
                ps2v += (t.x*t.x + t.y*t.y) + (t.z*t.z + t.w*t.w);
            }
        }
    }

#pragma unroll
    for (int off = 1; off < 64; off <<= 1) {
        ps   += __shfl_xor(ps,   off);
        ps2v += __shfl_xor(ps2v, off);
    }
    if (l == 0) { redp[w*2] = ps; redp[w*2 + 1] = ps2v; }
    __syncthreads();
    if (tid == 0) {
        float a = redp[0] + redp[2] + redp[4] + redp[6];
        float c = redp[1] + redp[3] + redp[5] + redp[7];
        int slot = bh*2 + blockIdx.y;
        part2[slot*2]     = a;
        part2[slot*2 + 1] = c;
    }
}

// ---------------- fused ln2(row0) + MLP(row0) + residual: cls rows only ----------------
__global__ __launch_bounds__(256) void mlp_cls(const float* __restrict__ tokens,
        const float* __restrict__ part2, const float* __restrict__ ln2_g,
        const float* __restrict__ ln2_b, const float* __restrict__ w_enc,
        const float* __restrict__ b_enc, float* __restrict__ mlp_out) {
    __shared__ float y0[768];
    const int b = blockIdx.x, tid = threadIdx.x;
    float s1 = 0.f, s2 = 0.f;
    for (int i = 0; i < 24; ++i) {
        s1 += part2[(b*24 + i)*2];
        s2 += part2[(b*24 + i)*2 + 1];
    }
    float mu = s1 * (1.f / (float)LNN);
    float var = s2 * (1.f / (float)LNN) - mu*mu;
    float rstd = rsqrtf(var + 1e-5f);
    const float* crow = tokens + (size_t)b * 197 * 768;   // cls row
    for (int d = tid; d < 768; d += 256)
        y0[d] = (crow[d] - mu) * rstd * ln2_g[d] + ln2_b[d];
    __syncthreads();
    const int n = blockIdx.y * 256 + tid;                 // grid.y = 3 -> n < 768
    float acc = b_enc[n];
#pragma unroll 8
    for (int k = 0; k < 768; ++k) acc += y0[k] * w_enc[(size_t)k*768 + n];
    mlp_out[(size_t)b*768 + n] = crow[n] + fmaxf(acc, 0.f);
}

// ---------------- head: logits (parallel) + softmax ----------------
__global__ __launch_bounds__(256) void logits_kernel(const float* __restrict__ xin,
        const float* __restrict__ w_head, const float* __restrict__ b_head,
        float* __restrict__ logits) {
    __shared__ float xr[768];
    const int b = blockIdx.x;
    const int o = blockIdx.y * 256 + threadIdx.x;
    for (int i = threadIdx.x; i < 768; i += 256) xr[i] = xin[(size_t)b*768 + i];
    __syncthreads();
    if (o < NOUT) {
        float acc = b_head[o];
#pragma unroll 8
        for (int d = 0; d < 768; ++d) acc += xr[d] * w_head[(size_t)d*NOUT + o];
        logits[(size_t)b*NOUT + o] = acc;
    }
}

__global__ __launch_bounds__(256) void softmax_kernel(const float* __restrict__ logits,
        float* __restrict__ outp) {
    __shared__ float red[8];
    const int b = blockIdx.x, tid = threadIdx.x;
    const float* lrow = logits + (size_t)b*NOUT;
    const int w = tid >> 6, l = tid & 63;
    float v[4];
    float mx = -1e30f;
#pragma unroll
    for (int i = 0; i < 4; ++i) {
        int t = tid + i*256;
        v[i] = (t < NOUT) ? lrow[t] : -1e30f;
        mx = fmaxf(mx, v[i]);
    }
    for (int off = 32; off; off >>= 1) mx = fmaxf(mx, __shfl_xor(mx, off));
    if (l == 0) red[w] = mx;
    __syncthreads();
    if (tid == 0) red[4] = fmaxf(fmaxf(red[0], red[1]), fmaxf(red[2], red[3]));
    __syncthreads();
    const float m = red[4];
    float s = 0.f;
#pragma unroll
    for (int i = 0; i < 4; ++i) { v[i] = __expf(v[i] - m); s += v[i]; }
    for (int off = 32; off; off >>= 1) s += __shfl_xor(s, off);
    if (l == 0) red[w] = s;
    __syncthreads();
    if (tid == 0) red[5] = red[0] + red[1] + red[2] + red[3];
    __syncthreads();
    const float inv = 1.f / red[5];
#pragma unroll
    for (int i = 0; i < 4; ++i) {
        int t = tid + i*256;
        if (t < NOUT) outp[(size_t)b*NOUT + t] = v[i] * inv;
    }
}

// ---------------- launch ----------------
extern "C" void kernel_launch(void* const* d_in, const int* in_sizes, int n_in,
                              void* d_out, int out_size, void* d_ws, size_t ws_size,
                              hipStream_t stream) {
    (void)in_sizes; (void)n_in; (void)out_size; (void)ws_size;
    const float* images = (const float*)d_in[0];
    const float* w_map  = (const float*)d_in[1];
    const float* b_map  = (const float*)d_in[2];
    const float* cls_tok= (const float*)d_in[3];
    const float* ln1_g  = (const float*)d_in[4];
    const float* ln1_b  = (const float*)d_in[5];
    const float* wq     = (const float*)d_in[6];
    const float* bq     = (const float*)d_in[7];
    const float* wk     = (const float*)d_in[8];
    const float* bk     = (const float*)d_in[9];
    const float* wv     = (const float*)d_in[10];
    const float* bv     = (const float*)d_in[11];
    const float* ln2_g  = (const float*)d_in[12];
    const float* ln2_b  = (const float*)d_in[13];
    const float* w_enc  = (const float*)d_in[14];
    const float* b_enc  = (const float*)d_in[15];
    const float* w_head = (const float*)d_in[16];
    const float* b_head = (const float*)d_in[17];
    float* out = (float*)d_out;
    float* ws = (float*)d_ws;

    float* pos    = ws;                     // 151296
    float* tokens = pos + 151296;           // 9682944 f32 (residual, updated in-place by attn)
    float* x      = tokens + 9682944;       // spare (layout stability)
    float* q      = x + 9682944;            // imb overlay, then qb
    float* kk     = q + 9682944;            // wt(w_map) overlay, then kb
    float* vv     = kk + 9682944;           // vT bf16 [768][64][256]
    float* part   = vv + 9682944;           // 512 (ln1 stats, reduced)
    float* part2  = part + 512;             // 3072 (ln2 per-(b,h,qhalf) partials)
    float* mlp_o  = part2 + 3072;           // 49152 (final cls rows, f32)
    float* logit  = mlp_o + 49152;          // 64000
    float* wqkvT  = logit + 64000;          // 73728 f32-slots = 147456 u16 bf16
    float* gpart  = wqkvT + 73728;          // 2352 (gemm0 LN1 partials)
    float* cpart  = gpart + 2352;           // 384 (cls LN1 partials)

    u16* imb = (u16*)q;
    u16* wt  = (u16*)kk;
    u16* qbp = (u16*)q;
    u16* kbp = (u16*)kk;
    u16* vTp = (u16*)vv;
    u16* wTg = (u16*)wqkvT;

    pos_emb_kernel<<<(SQ*DD + 255)/256, 256, 0, stream>>>(pos);
    cls_kernel<<<BB_*DD/256, 256, 0, stream>>>(cls_tok, pos, tokens, cpart);
    conv_bf16_kernel<<<(MPATCH*768/8 + 255)/256, 256, 0, stream>>>(images, imb, MPATCH*768/8);
    transpose_bf16_kernel<<<dim3(24, 24), 256, 0, stream>>>(w_map, wt);
    wqkv_prep<<<dim3(NHH, 3), 256, 0, stream>>>(wq, wk, wv, wTg);
    gemm_mfma0<<<dim3(98, 6), 256, 0, stream>>>(imb, wt, b_map, pos, tokens, MPATCH, gpart);
    reduce_ln1<<<BB_, 64, 0, stream>>>(gpart, cpart, part);
    qkv_mfma<<<dim3(197, NHH), 256, 0, stream>>>(tokens, part, ln1_g, ln1_b, wTg,
                                                 bq, bk, bv, qbp, kbp, vTp);
    attn_mfma<<<dim3(BB_*NHH, 2), 256, 0, stream>>>(qbp, kbp, vTp, tokens, part2);
    mlp_cls<<<dim3(BB_, 3), 256, 0, stream>>>(tokens, part2, ln2_g, ln2_b, w_enc, b_enc, mlp_o);
    logits_kernel<<<dim3(BB_, 4), 256, 0, stream>>>(mlp_o, w_head, b_head, logit);
    softmax_kernel<<<BB_, 256, 0, stream>>>(logit, out);
}

// Round 11
// 205.274 us; speedup vs baseline: 1.3252x; 1.0187x over previous
//
#include <hip/hip_runtime.h>
#include <math.h>

// ---------------- dims ----------------
#define SQ 197           // tokens
#define DD 768           // hidden
#define NHH 12
#define DHH 64
#define BB_ 64           // batch
#define MTOK (BB_*SQ)    // 12608
#define MPATCH (BB_*196) // 12544
#define NOUT 1000
#define LNN (SQ*DD)      // 151296 elems per sample
#define SQP 256          // padded seq for vT

typedef unsigned short u16;
typedef __attribute__((ext_vector_type(8))) short bf16x8;
typedef __attribute__((ext_vector_type(4))) float f32x4;

__device__ __forceinline__ u16 f2bf(float x) {      // RNE f32->bf16
    unsigned u = __float_as_uint(x);
    u = (u + 0x7FFF + ((u >> 16) & 1)) >> 16;
    return (u16)u;
}

// ---------------- pos emb (f64 for safety, tiny) ----------------
__global__ void pos_emb_kernel(float* __restrict__ pos) {
    int i = blockIdx.x * blockDim.x + threadIdx.x;
    if (i >= SQ * DD) return;
    int s = i / DD, d = i % DD;
    double e = (double)(d & ~1) / (double)DD;
    double ang = (double)s * pow(10000.0, -e);
    pos[i] = (d & 1) ? (float)cos(ang) : (float)sin(ang);
}

// ---------------- cls token row + LN1 partials ----------------
__global__ __launch_bounds__(256) void cls_kernel(const float* __restrict__ cls_tok,
                           const float* __restrict__ pos,
                           float* __restrict__ tokens, float* __restrict__ cpart) {
    __shared__ float red[8];
    const int i = blockIdx.x * 256 + threadIdx.x;   // 192 blocks, 3 per sample
    const int b = i / DD, d = i % DD;
    float v = cls_tok[d] + pos[d];
    tokens[(size_t)b * SQ * DD + d] = v;
    float ps = v, ps2 = v * v;
    const int w = threadIdx.x >> 6, l = threadIdx.x & 63;
#pragma unroll
    for (int off = 1; off < 64; off <<= 1) {
        ps  += __shfl_xor(ps,  off);
        ps2 += __shfl_xor(ps2, off);
    }
    if (l == 0) { red[w*2] = ps; red[w*2+1] = ps2; }
    __syncthreads();
    if (threadIdx.x == 0) {
        cpart[blockIdx.x*2]     = red[0] + red[2] + red[4] + red[6];
        cpart[blockIdx.x*2 + 1] = red[1] + red[3] + red[5] + red[7];
    }
}

// ---------------- f32 -> bf16 bulk convert (8 elems/thread) ----------------
__global__ __launch_bounds__(256) void conv_bf16_kernel(const float* __restrict__ in,
        u16* __restrict__ out, int n8) {
    int i = blockIdx.x * blockDim.x + threadIdx.x;
    if (i >= n8) return;
    float4 a = ((const float4*)in)[2*i];
    float4 b = ((const float4*)in)[2*i + 1];
    union { u16 u[8]; uint4 v; } r;
    r.u[0]=f2bf(a.x); r.u[1]=f2bf(a.y); r.u[2]=f2bf(a.z); r.u[3]=f2bf(a.w);
    r.u[4]=f2bf(b.x); r.u[5]=f2bf(b.y); r.u[6]=f2bf(b.z); r.u[7]=f2bf(b.w);
    ((uint4*)out)[i] = r.v;
}

// ---------------- 768x768 transpose + convert: out[n][k] = in[k][n] ----------------
__global__ __launch_bounds__(256) void transpose_bf16_kernel(const float* __restrict__ in,
        u16* __restrict__ out) {
    __shared__ float t[32][33];
    int bn = blockIdx.x * 32, bk = blockIdx.y * 32;
    int tx = threadIdx.x & 31;
#pragma unroll
    for (int r = 0; r < 4; ++r) {
        int kk = (threadIdx.x >> 5) * 4 + r;
        t[kk][tx] = in[(size_t)(bk + kk) * 768 + bn + tx];
    }
    __syncthreads();
#pragma unroll
    for (int r = 0; r < 4; ++r) {
        int nn = (threadIdx.x >> 5) * 4 + r;
        out[(size_t)(bn + nn) * 768 + bk + tx] = f2bf(t[tx][nn]);
    }
}

// ---------------- wqkv pre-transpose: wTg[m][h][e][d] bf16 ----------------
__global__ __launch_bounds__(256) void wqkv_prep(const float* __restrict__ wq,
        const float* __restrict__ wk, const float* __restrict__ wv,
        u16* __restrict__ wTg) {
    __shared__ float t[64][65];
    const int h = blockIdx.x, m = blockIdx.y;
    const float* src = ((m == 0) ? wq : (m == 1) ? wk : wv) + (size_t)h*4096;
    const int tid = threadIdx.x;
#pragma unroll
    for (int i = 0; i < 4; ++i) {
        int d = (tid >> 4) + i*16, e4 = (tid & 15) * 4;
        float4 v = *(const float4*)(src + d*64 + e4);
        t[d][e4+0] = v.x; t[d][e4+1] = v.y; t[d][e4+2] = v.z; t[d][e4+3] = v.w;
    }
    __syncthreads();
    u16* dst = wTg + ((size_t)(m*NHH + h)) * 4096;
#pragma unroll
    for (int i = 0; i < 4; ++i) {
        int e = (tid >> 4) + i*16, d4 = (tid & 15) * 4;
        union { u16 u[4]; uint2 v2; } o;
        o.u[0] = f2bf(t[d4+0][e]); o.u[1] = f2bf(t[d4+1][e]);
        o.u[2] = f2bf(t[d4+2][e]); o.u[3] = f2bf(t[d4+3][e]);
        *(uint2*)(dst + e*64 + d4) = o.v2;
    }
}

// ---------------- MFMA GEMM (embed) + fused LN1 partials ----------------
__global__ __launch_bounds__(256) void gemm_mfma0(const u16* __restrict__ A,
        const u16* __restrict__ BT, const float* __restrict__ bias,
        const float* __restrict__ pos, float* __restrict__ outp, int M,
        float* __restrict__ gpart) {
    __shared__ u16 As[2][4096];   // [128 rows][32 k] bf16
    __shared__ u16 Bs[2][4096];
    __shared__ float redg[16];
    const int tid = threadIdx.x;
    const int wv = tid >> 6, ln = tid & 63;
    const int m0 = blockIdx.x * 128, n0 = blockIdx.y * 128;
    const int wr = wv >> 1, wc = wv & 1;
    const int lrow = ln & 15, lk = ln >> 4;
    const int s0 = m0 / 196;

    f32x4 acc[4][4];
#pragma unroll
    for (int i = 0; i < 4; ++i)
#pragma unroll
        for (int j = 0; j < 4; ++j) acc[i][j] = (f32x4){0.f, 0.f, 0.f, 0.f};

    auto stage = [&](const u16* __restrict__ src, int rowBase, int rowMax,
                     u16* lbase, int k0) {
#pragma unroll
        for (int rep = 0; rep < 2; ++rep) {
            int c = rep * 256 + wv * 64 + ln;
            int row = rowBase + (c >> 2);
            if (row > rowMax) row = rowMax;
            const void* g = (const char*)src + ((size_t)row * 768 + k0) * 2 + ((c & 3) << 4);
            void* l = (char*)lbase + rep * 4096 + wv * 1024;
            __builtin_amdgcn_global_load_lds(
                (const __attribute__((address_space(1))) unsigned int*)g,
                (__attribute__((address_space(3))) unsigned int*)l, 16, 0, 0);
        }
    };

    stage(A,  m0, M - 1,   &As[0][0], 0);
    stage(BT, n0, 767,     &Bs[0][0], 0);
    __syncthreads();

    int cur = 0;
    for (int t = 0; t < 24; ++t) {
        if (t < 23) {
            stage(A,  m0, M - 1, &As[cur ^ 1][0], (t + 1) * 32);
            stage(BT, n0, 767,   &Bs[cur ^ 1][0], (t + 1) * 32);
        }
        bf16x8 af[4], bfr[4];
#pragma unroll
        for (int i = 0; i < 4; ++i) {
            af[i]  = *(const bf16x8*)&As[cur][(wr * 64 + i * 16 + lrow) * 32 + lk * 8];
            bfr[i] = *(const bf16x8*)&Bs[cur][(wc * 64 + i * 16 + lrow) * 32 + lk * 8];
        }
#pragma unroll
        for (int i = 0; i < 4; ++i)
#pragma unroll
            for (int j = 0; j < 4; ++j)
                acc[i][j] = __builtin_amdgcn_mfma_f32_16x16x32_bf16(af[i], bfr[j], acc[i][j], 0, 0, 0);
        __syncthreads();
        cur ^= 1;
    }

    float psA = 0.f, ps2A = 0.f, psB = 0.f, ps2B = 0.f;
#pragma unroll
    for (int i = 0; i < 4; ++i) {
        int gm = m0 + wr * 64 + i * 16 + (ln >> 4) * 4;
#pragma unroll
        for (int r = 0; r < 4; ++r) {
            int gmr = gm + r;
            if (gmr < M) {
                int bsmp = gmr / 196, p = gmr - bsmp * 196;
#pragma unroll
                for (int j = 0; j < 4; ++j) {
                    int n = n0 + wc * 64 + j * 16 + (ln & 15);
                    float v = acc[i][j][r] + bias[n] + pos[(size_t)(p + 1) * 768 + n];
                    outp[(size_t)(gmr + bsmp + 1) * 768 + n] = v;
                    if (bsmp == s0) { psA += v; ps2A += v*v; }
                    else            { psB += v; ps2B += v*v; }
                }
            }
        }
    }
#pragma unroll
    for (int off = 1; off < 64; off <<= 1) {
        psA  += __shfl_xor(psA,  off);  ps2A += __shfl_xor(ps2A, off);
        psB  += __shfl_xor(psB,  off);  ps2B += __shfl_xor(ps2B, off);
    }
    __syncthreads();
    if (ln == 0) {
        redg[wv*4+0] = psA; redg[wv*4+1] = ps2A;
        redg[wv*4+2] = psB; redg[wv*4+3] = ps2B;
    }
    __syncthreads();
    if (tid == 0) {
        float a = redg[0]+redg[4]+redg[8]+redg[12];
        float b = redg[1]+redg[5]+redg[9]+redg[13];
        float c = redg[2]+redg[6]+redg[10]+redg[14];
        float d = redg[3]+redg[7]+redg[11]+redg[15];
        float* gp = gpart + (size_t)(blockIdx.x*6 + blockIdx.y)*4;
        gp[0] = a; gp[1] = b; gp[2] = c; gp[3] = d;
    }
}

// ---------------- LN1 partial reducer: 64 blocks (1/sample), 64 threads ----------------
__global__ __launch_bounds__(64) void reduce_ln1(const float* __restrict__ gpart,
        const float* __restrict__ cpart, float* __restrict__ part) {
    const int b = blockIdx.x, t = threadIdx.x;
    float s1 = 0.f, s2 = 0.f;
    for (int grp = t; grp < 98*6; grp += 64) {
        int bx = grp / 6;
        int sA = (bx * 128) / 196;
        const float* gp = gpart + (size_t)grp*4;
        if (sA == b)     { s1 += gp[0]; s2 += gp[1]; }
        if (sA + 1 == b) { s1 += gp[2]; s2 += gp[3]; }
    }
#pragma unroll
    for (int off = 1; off < 64; off <<= 1) {
        s1 += __shfl_xor(s1, off);
        s2 += __shfl_xor(s2, off);
    }
    if (t == 0) {
#pragma unroll
        for (int i = 0; i < 3; ++i) {
            s1 += cpart[(b*3 + i)*2];
            s2 += cpart[(b*3 + i)*2 + 1];
        }
        part[b*8 + 0] = s1;
        part[b*8 + 1] = s2;
#pragma unroll
        for (int i = 2; i < 8; ++i) part[b*8 + i] = 0.f;
    }
}

// ---------------- QKV via MFMA: block = (64-token chunk, head), 4 waves ----------------
__global__ __launch_bounds__(256) void qkv_mfma(const float* __restrict__ tokens,
        const float* __restrict__ part,
        const float* __restrict__ ln1_g, const float* __restrict__ ln1_b,
        const u16* __restrict__ wTg,
        const float* __restrict__ bq, const float* __restrict__ bk,
        const float* __restrict__ bv,
        u16* __restrict__ qb, u16* __restrict__ kb, u16* __restrict__ vT) {
    __shared__ u16 Xs[64*72];          // 9216 u16; reused as vstage
    __shared__ u16 Ws[3*64*72];        // 13824 u16
    const int c0 = blockIdx.x * 64, h = blockIdx.y;
    const int tid = threadIdx.x;
    const int w = tid >> 6, ln = tid & 63;
    const int lrow = ln & 15, lk = ln >> 4;

    for (int c2 = tid; c2 < 512; c2 += 256) {
        int r = c2 >> 3, q8 = (c2 & 7) * 8;
        int t = c0 + r;
        int bb = t / 197, s = t - bb * 197;
        float S1 = part[bb*8+0] + part[bb*8+2] + part[bb*8+4] + part[bb*8+6];
        float S2 = part[bb*8+1] + part[bb*8+3] + part[bb*8+5] + part[bb*8+7];
        float mu = S1 * (1.f / (float)LNN);
        float rstd = rsqrtf(S2 * (1.f / (float)LNN) - mu*mu + 1e-5f);
        const float* tp = tokens + (size_t)t*768 + h*64 + q8;
        const float* gp = ln1_g + (size_t)s*768 + h*64 + q8;
        const float* bp = ln1_b + (size_t)s*768 + h*64 + q8;
        float4 t0 = *(const float4*)tp, t1 = *(const float4*)(tp+4);
        float4 g0 = *(const float4*)gp, g1 = *(const float4*)(gp+4);
        float4 b0 = *(const float4*)bp, b1 = *(const float4*)(bp+4);
        union { u16 u[8]; uint4 v; } o;
        o.u[0] = f2bf((t0.x - mu)*rstd*g0.x + b0.x);
        o.u[1] = f2bf((t0.y - mu)*rstd*g0.y + b0.y);
        o.u[2] = f2bf((t0.z - mu)*rstd*g0.z + b0.z);
        o.u[3] = f2bf((t0.w - mu)*rstd*g0.w + b0.w);
        o.u[4] = f2bf((t1.x - mu)*rstd*g1.x + b1.x);
        o.u[5] = f2bf((t1.y - mu)*rstd*g1.y + b1.y);
        o.u[6] = f2bf((t1.z - mu)*rstd*g1.z + b1.z);
        o.u[7] = f2bf((t1.w - mu)*rstd*g1.w + b1.w);
        *(uint4*)&Xs[r*72 + q8] = o.v;
    }
    for (int idx = tid; idx < 1536; idx += 256) {
        int m = idx >> 9, rem = idx & 511;
        int e = rem >> 3, c8 = (rem & 7) * 8;
        *(uint4*)&Ws[m*4608 + e*72 + c8] =
            *(const uint4*)(wTg + ((size_t)(m*NHH + h))*4096 + e*64 + c8);
    }
    __syncthreads();

    bf16x8 af[2];
    af[0] = *(const bf16x8*)&Xs[(w*16 + lrow)*72 + lk*8];
    af[1] = *(const bf16x8*)&Xs[(w*16 + lrow)*72 + 32 + lk*8];
    f32x4 acc[3][4];
#pragma unroll
    for (int m = 0; m < 3; ++m)
#pragma unroll
        for (int j = 0; j < 4; ++j) acc[m][j] = (f32x4){0.f,0.f,0.f,0.f};
#pragma unroll
    for (int m = 0; m < 3; ++m)
#pragma unroll
        for (int s = 0; s < 2; ++s)
#pragma unroll
            for (int j = 0; j < 4; ++j) {
                bf16x8 bfr = *(const bf16x8*)&Ws[m*4608 + (j*16 + lrow)*72 + s*32 + lk*8];
                acc[m][j] = __builtin_amdgcn_mfma_f32_16x16x32_bf16(af[s], bfr, acc[m][j], 0, 0, 0);
            }

#pragma unroll
    for (int m = 0; m < 2; ++m) {
        const float* bias = ((m == 0) ? bq : bk) + h*64;
        u16* dst = (m == 0) ? qb : kb;
        float bj[4];
#pragma unroll
        for (int j = 0; j < 4; ++j) bj[j] = bias[j*16 + lrow];
#pragma unroll
        for (int r = 0; r < 4; ++r) {
            int t = c0 + w*16 + lk*4 + r;
            size_t o = (size_t)t*768 + h*64;
#pragma unroll
            for (int j = 0; j < 4; ++j)
                dst[o + j*16 + lrow] = f2bf(acc[m][j][r] + bj[j]);
        }
    }

    {
        float bj[4];
#pragma unroll
        for (int j = 0; j < 4; ++j) bj[j] = bv[h*64 + j*16 + lrow];
        __syncthreads();
        u16* vs = Xs;                          // [64 e][72 tok]
#pragma unroll
        for (int j = 0; j < 4; ++j)
#pragma unroll
            for (int r = 0; r < 4; ++r)
                vs[(j*16 + lrow)*72 + (w*16 + lk*4 + r)] = f2bf(acc[2][j][r] + bj[j]);
        __syncthreads();
        for (int idx = tid; idx < 4096; idx += 256) {
            int d = idx >> 6, tl = idx & 63;
            int t = c0 + tl;
            int bb = t / 197, s = t - bb * 197;
            vT[((size_t)(bb*NHH + h)*64 + d)*SQP + s] = vs[d*72 + tl];
        }
    }
}

// ---------------- attention: Q-in-regs, small LDS, no tokens write ----------------
// Emits only (a) per-(b,h,qhalf) LN2 partial stats and (b) the updated cls rows.
__global__ __launch_bounds__(256) void attn_mfma(const u16* __restrict__ qb,
        const u16* __restrict__ kb, const u16* __restrict__ vT,
        const float* __restrict__ tokens, float* __restrict__ cls_out,
        float* __restrict__ part2) {
    __shared__ u16 sh[9216];                  // Q-stage[128][72] -> Ks[64][72]|VTs[64][72] -> Osh
    __shared__ float redp[8];

    const int bh = blockIdx.x;
    const int b = bh / NHH, h = bh % NHH;
    const int q0 = blockIdx.y * 128;
    const int tid = threadIdx.x;
    const int w = tid >> 6, l = tid & 63;
    const int g = l >> 4, lq = l & 15;

    // stage Q tile coalesced into sh, then lift fragments to registers
    {
        const u16* qbase = qb + (size_t)(b*197)*768 + h*64;
#pragma unroll
        for (int it = 0; it < 8; ++it) {
            int idx = tid + it*256;
            int r = idx >> 4, c = idx & 15;
            int gr = q0 + r; if (gr > 196) gr = 196;
            *(uint2*)&sh[r*72 + c*4] = *(const uint2*)(qbase + (size_t)gr*768 + c*4);
        }
    }
    __syncthreads();
    bf16x8 qfr[2][2];
#pragma unroll
    for (int s2 = 0; s2 < 2; ++s2)
#pragma unroll
        for (int s = 0; s < 2; ++s)
            qfr[s2][s] = *(const bf16x8*)&sh[(s2*64 + w*16 + lq)*72 + s*32 + g*8];

    u16* Ks  = sh;                            // reuse staging area
    u16* VTs = sh + 4608;

    f32x4 acco[2][4];
#pragma unroll
    for (int s2 = 0; s2 < 2; ++s2)
#pragma unroll
        for (int i = 0; i < 4; ++i) acco[s2][i] = (f32x4){0.f,0.f,0.f,0.f};
    float S[2] = {0.f, 0.f};

    const int srcA = lq + ((l & 16) ? 32 : 0);
    const u16* krow = kb + (size_t)(b*197)*768 + h*64;
    const u16* vbase = vT + (size_t)bh*64*SQP;

    uint2 kreg[4], vreg[4];
    auto issueKV = [&](int tt) {
        const int t0 = tt * 64;
#pragma unroll
        for (int it = 0; it < 4; ++it) {
            int idx = tid + it*256;
            int r = idx >> 4, c = idx & 15;
            int gt = t0 + r; if (gt > 196) gt = 196;
            kreg[it] = *(const uint2*)(krow + (size_t)gt*768 + c*4);
            vreg[it] = *(const uint2*)(vbase + (size_t)r*SQP + t0 + c*4);
        }
    };
    issueKV(0);

    for (int tt = 0; tt < 4; ++tt) {
        __syncthreads();                      // sh free (Q frags lifted / prev compute done)
#pragma unroll
        for (int it = 0; it < 4; ++it) {
            int idx = tid + it*256;
            int r = idx >> 4, c = idx & 15;
            *(uint2*)&Ks[r*72 + c*4]  = kreg[it];
            *(uint2*)&VTs[r*72 + c*4] = vreg[it];
        }
        if (tt < 3) issueKV(tt + 1);          // loads fly during compute below
        __syncthreads();

        const int t0 = tt * 64;
#pragma unroll
        for (int s2 = 0; s2 < 2; ++s2) {
            f32x4 accp[4];
#pragma unroll
            for (int i = 0; i < 4; ++i) accp[i] = (f32x4){0.f,0.f,0.f,0.f};
#pragma unroll
            for (int s = 0; s < 2; ++s) {
#pragma unroll
                for (int tb = 0; tb < 4; ++tb) {
                    bf16x8 kf = *(const bf16x8*)&Ks[(tb*16 + lq)*72 + s*32 + g*8];
                    accp[tb] = __builtin_amdgcn_mfma_f32_16x16x32_bf16(kf, qfr[s2][s], accp[tb], 0, 0, 0);
                }
            }

            unsigned pk[4][2];
#pragma unroll
            for (int tb = 0; tb < 4; ++tb) {
                int tbase = t0 + tb*16 + g*4;
                float p0 = (tbase + 0 < 197) ? __expf(accp[tb][0] * 0.125f) : 0.f;
                float p1 = (tbase + 1 < 197) ? __expf(accp[tb][1] * 0.125f) : 0.f;
                float p2 = (tbase + 2 < 197) ? __expf(accp[tb][2] * 0.125f) : 0.f;
                float p3 = (tbase + 3 < 197) ? __expf(accp[tb][3] * 0.125f) : 0.f;
                S[s2] += (p0 + p1) + (p2 + p3);
                asm("v_cvt_pk_bf16_f32 %0, %1, %2" : "=v"(pk[tb][0]) : "v"(p0), "v"(p1));
                asm("v_cvt_pk_bf16_f32 %0, %1, %2" : "=v"(pk[tb][1]) : "v"(p2), "v"(p3));
            }

#pragma unroll
            for (int s = 0; s < 2; ++s) {
                union { unsigned u[4]; bf16x8 v; } bp;
#pragma unroll
                for (int c = 0; c < 4; ++c) {
                    int src = srcA + ((c >= 2) ? 16 : 0);
                    unsigned v0 = (unsigned)__shfl((int)pk[2*s + 0][c & 1], src);
                    unsigned v1 = (unsigned)__shfl((int)pk[2*s + 1][c & 1], src);
                    bp.u[c] = (l & 32) ? v1 : v0;
                }
#pragma unroll
                for (int dblk = 0; dblk < 4; ++dblk) {
                    bf16x8 vf = *(const bf16x8*)&VTs[(dblk*16 + lq)*72 + s*32 + g*8];
                    acco[s2][dblk] = __builtin_amdgcn_mfma_f32_16x16x32_bf16(vf, bp.v, acco[s2][dblk], 0, 0, 0);
                }
            }
        }
    }

    float invS[2];
#pragma unroll
    for (int s2 = 0; s2 < 2; ++s2) {
        S[s2] += __shfl_xor(S[s2], 16);
        S[s2] += __shfl_xor(S[s2], 32);
        invS[s2] = 1.f / S[s2];
    }

    // epilogue: transpose O^T through LDS (stride 18 = conflict-light), stats + cls only
    float* Osh = (float*)sh;                  // 4 waves x [64][18] f32 = 18432 B
    float ps = 0.f, ps2v = 0.f;
    const int q_l = tid >> 2, dc = tid & 3;
#pragma unroll
    for (int s2 = 0; s2 < 2; ++s2) {
        __syncthreads();
        float* os = Osh + w * 1152;
#pragma unroll
        for (int dblk = 0; dblk < 4; ++dblk)
#pragma unroll
            for (int r = 0; r < 4; ++r)
                os[(dblk*16 + g*4 + r)*18 + lq] = acco[s2][dblk][r] * invS[s2];
        __syncthreads();

        const int s_tok = q0 + s2*64 + q_l;
        if (s_tok < 197) {
            const float* osr = Osh + (q_l >> 4)*1152;
            const int ql = q_l & 15;
            const float* trow = tokens + (size_t)(b*197 + s_tok)*768 + h*64 + dc*16;
            float* crow = cls_out + (size_t)b*768 + h*64 + dc*16;
#pragma unroll
            for (int c4 = 0; c4 < 4; ++c4) {
                float4 t = *(const float4*)(trow + c4*4);
                t.x += osr[(dc*16 + c4*4 + 0)*18 + ql];
                t.y += osr[(dc*16 + c4*4 + 1)*18 + ql];
                t.z += osr[(dc*16 + c4*4 + 2)*18 + ql];
                t.w += osr[(dc*16 + c4*4 + 3)*18 + ql];
                ps   += (t.x + t.y) + (t.z + t.w);
                ps2v += (t.x*t.x + t.y*t.y) + (t.z*t.z + t.w*t.w);
                if (s_tok == 0) *(float4*)(crow + c4*4) = t;   // only cls rows persist
            }
        }
    }

#pragma unroll
    for (int off = 1; off < 64; off <<= 1) {
        ps   += __shfl_xor(ps,   off);
        ps2v += __shfl_xor(ps2v, off);
    }
    if (l == 0) { redp[w*2] = ps; redp[w*2 + 1] = ps2v; }
    __syncthreads();
    if (tid == 0) {
        float a = redp[0] + redp[2] + redp[4] + redp[6];
        float c = redp[1] + redp[3] + redp[5] + redp[7];
        int slot = bh*2 + blockIdx.y;
        part2[slot*2]     = a;
        part2[slot*2 + 1] = c;
    }
}

// ---------------- fused ln2(row0) + MLP(row0) + residual: cls rows only ----------------
__global__ __launch_bounds__(256) void mlp_cls(const float* __restrict__ cls_out,
        const float* __restrict__ part2, const float* __restrict__ ln2_g,
        const float* __restrict__ ln2_b, const float* __restrict__ w_enc,
        const float* __restrict__ b_enc, float* __restrict__ mlp_out) {
    __shared__ float y0[768];
    const int b = blockIdx.x, tid = threadIdx.x;
    float s1 = 0.f, s2 = 0.f;
    for (int i = 0; i < 24; ++i) {
        s1 += part2[(b*24 + i)*2];
        s2 += part2[(b*24 + i)*2 + 1];
    }
    float mu = s1 * (1.f / (float)LNN);
    float var = s2 * (1.f / (float)LNN) - mu*mu;
    float rstd = rsqrtf(var + 1e-5f);
    const float* crow = cls_out + (size_t)b * 768;
    for (int d = tid; d < 768; d += 256)
        y0[d] = (crow[d] - mu) * rstd * ln2_g[d] + ln2_b[d];
    __syncthreads();
    const int n = blockIdx.y * 256 + tid;                 // grid.y = 3 -> n < 768
    float acc = b_enc[n];
#pragma unroll 8
    for (int k = 0; k < 768; ++k) acc += y0[k] * w_enc[(size_t)k*768 + n];
    mlp_out[(size_t)b*768 + n] = crow[n] + fmaxf(acc, 0.f);
}

// ---------------- head: logits (parallel) + softmax ----------------
__global__ __launch_bounds__(256) void logits_kernel(const float* __restrict__ xin,
        const float* __restrict__ w_head, const float* __restrict__ b_head,
        float* __restrict__ logits) {
    __shared__ float xr[768];
    const int b = blockIdx.x;
    const int o = blockIdx.y * 256 + threadIdx.x;
    for (int i = threadIdx.x; i < 768; i += 256) xr[i] = xin[(size_t)b*768 + i];
    __syncthreads();
    if (o < NOUT) {
        float acc = b_head[o];
#pragma unroll 8
        for (int d = 0; d < 768; ++d) acc += xr[d] * w_head[(size_t)d*NOUT + o];
        logits[(size_t)b*NOUT + o] = acc;
    }
}

__global__ __launch_bounds__(256) void softmax_kernel(const float* __restrict__ logits,
        float* __restrict__ outp) {
    __shared__ float red[8];
    const int b = blockIdx.x, tid = threadIdx.x;
    const float* lrow = logits + (size_t)b*NOUT;
    const int w = tid >> 6, l = tid & 63;
    float v[4];
    float mx = -1e30f;
#pragma unroll
    for (int i = 0; i < 4; ++i) {
        int t = tid + i*256;
        v[i] = (t < NOUT) ? lrow[t] : -1e30f;
        mx = fmaxf(mx, v[i]);
    }
    for (int off = 32; off; off >>= 1) mx = fmaxf(mx, __shfl_xor(mx, off));
    if (l == 0) red[w] = mx;
    __syncthreads();
    if (tid == 0) red[4] = fmaxf(fmaxf(red[0], red[1]), fmaxf(red[2], red[3]));
    __syncthreads();
    const float m = red[4];
    float s = 0.f;
#pragma unroll
    for (int i = 0; i < 4; ++i) { v[i] = __expf(v[i] - m); s += v[i]; }
    for (int off = 32; off; off >>= 1) s += __shfl_xor(s, off);
    if (l == 0) red[w] = s;
    __syncthreads();
    if (tid == 0) red[5] = red[0] + red[1] + red[2] + red[3];
    __syncthreads();
    const float inv = 1.f / red[5];
#pragma unroll
    for (int i = 0; i < 4; ++i) {
        int t = tid + i*256;
        if (t < NOUT) outp[(size_t)b*NOUT + t] = v[i] * inv;
    }
}

// ---------------- launch ----------------
extern "C" void kernel_launch(void* const* d_in, const int* in_sizes, int n_in,
                              void* d_out, int out_size, void* d_ws, size_t ws_size,
                              hipStream_t stream) {
    (void)in_sizes; (void)n_in; (void)out_size; (void)ws_size;
    const float* images = (const float*)d_in[0];
    const float* w_map  = (const float*)d_in[1];
    const float* b_map  = (const float*)d_in[2];
    const float* cls_tok= (const float*)d_in[3];
    const float* ln1_g  = (const float*)d_in[4];
    const float* ln1_b  = (const float*)d_in[5];
    const float* wq     = (const float*)d_in[6];
    const float* bq     = (const float*)d_in[7];
    const float* wk     = (const float*)d_in[8];
    const float* bk     = (const float*)d_in[9];
    const float* wv     = (const float*)d_in[10];
    const float* bv     = (const float*)d_in[11];
    const float* ln2_g  = (const float*)d_in[12];
    const float* ln2_b  = (const float*)d_in[13];
    const float* w_enc  = (const float*)d_in[14];
    const float* b_enc  = (const float*)d_in[15];
    const float* w_head = (const float*)d_in[16];
    const float* b_head = (const float*)d_in[17];
    float* out = (float*)d_out;
    float* ws = (float*)d_ws;

    float* pos    = ws;                     // 151296
    float* tokens = pos + 151296;           // 9682944 f32 (pre-attn residual, read-only in attn)
    float* x      = tokens + 9682944;       // spare (layout stability)
    float* q      = x + 9682944;            // imb overlay, then qb
    float* kk     = q + 9682944;            // wt(w_map) overlay, then kb
    float* vv     = kk + 9682944;           // vT bf16 [768][64][256]
    float* part   = vv + 9682944;           // 512 (ln1 stats, reduced)
    float* part2  = part + 512;             // 3072 (ln2 per-(b,h,qhalf) partials)
    float* mlp_o  = part2 + 3072;           // 49152 (final cls rows, f32)
    float* logit  = mlp_o + 49152;          // 64000
    float* wqkvT  = logit + 64000;          // 73728 f32-slots = 147456 u16 bf16
    float* gpart  = wqkvT + 73728;          // 2352 (gemm0 LN1 partials)
    float* cpart  = gpart + 2352;           // 384 (cls LN1 partials)
    float* cls_o  = cpart + 384;            // 49152 (post-attn cls rows, f32)

    u16* imb = (u16*)q;
    u16* wt  = (u16*)kk;
    u16* qbp = (u16*)q;
    u16* kbp = (u16*)kk;
    u16* vTp = (u16*)vv;
    u16* wTg = (u16*)wqkvT;

    pos_emb_kernel<<<(SQ*DD + 255)/256, 256, 0, stream>>>(pos);
    cls_kernel<<<BB_*DD/256, 256, 0, stream>>>(cls_tok, pos, tokens, cpart);
    conv_bf16_kernel<<<(MPATCH*768/8 + 255)/256, 256, 0, stream>>>(images, imb, MPATCH*768/8);
    transpose_bf16_kernel<<<dim3(24, 24), 256, 0, stream>>>(w_map, wt);
    wqkv_prep<<<dim3(NHH, 3), 256, 0, stream>>>(wq, wk, wv, wTg);
    gemm_mfma0<<<dim3(98, 6), 256, 0, stream>>>(imb, wt, b_map, pos, tokens, MPATCH, gpart);
    reduce_ln1<<<BB_, 64, 0, stream>>>(gpart, cpart, part);
    qkv_mfma<<<dim3(197, NHH), 256, 0, stream>>>(tokens, part, ln1_g, ln1_b, wTg,
                                                 bq, bk, bv, qbp, kbp, vTp);
    attn_mfma<<<dim3(BB_*NHH, 2), 256, 0, stream>>>(qbp, kbp, vTp, tokens, cls_o, part2);
    mlp_cls<<<dim3(BB_, 3), 256, 0, stream>>>(cls_o, part2, ln2_g, ln2_b, w_enc, b_enc, mlp_o);
    logits_kernel<<<dim3(BB_, 4), 256, 0, stream>>>(mlp_o, w_head, b_head, logit);
    softmax_kernel<<<BB_, 256, 0, stream>>>(logit, out);
}

// Round 12
// 196.215 us; speedup vs baseline: 1.3864x; 1.0462x over previous
//
#include <hip/hip_runtime.h>
#include <math.h>

// ---------------- dims ----------------
#define SQ 197           // tokens
#define DD 768           // hidden
#define NHH 12
#define DHH 64
#define BB_ 64           // batch
#define MTOK (BB_*SQ)    // 12608
#define MPATCH (BB_*196) // 12544
#define NOUT 1000
#define LNN (SQ*DD)      // 151296 elems per sample
#define SQP 256          // padded seq for vT

typedef unsigned short u16;
typedef __attribute__((ext_vector_type(8))) short bf16x8;
typedef __attribute__((ext_vector_type(4))) float f32x4;

__device__ __forceinline__ u16 f2bf(float x) {      // RNE f32->bf16
    unsigned u = __float_as_uint(x);
    u = (u + 0x7FFF + ((u >> 16) & 1)) >> 16;
    return (u16)u;
}

// ---------------- pos emb (f64 for safety, tiny) ----------------
__global__ void pos_emb_kernel(float* __restrict__ pos) {
    int i = blockIdx.x * blockDim.x + threadIdx.x;
    if (i >= SQ * DD) return;
    int s = i / DD, d = i % DD;
    double e = (double)(d & ~1) / (double)DD;
    double ang = (double)s * pow(10000.0, -e);
    pos[i] = (d & 1) ? (float)cos(ang) : (float)sin(ang);
}

// ---------------- cls token row + LN1 partials ----------------
__global__ __launch_bounds__(256) void cls_kernel(const float* __restrict__ cls_tok,
                           const float* __restrict__ pos,
                           float* __restrict__ tokens, float* __restrict__ cpart) {
    __shared__ float red[8];
    const int i = blockIdx.x * 256 + threadIdx.x;   // 192 blocks, 3 per sample
    const int b = i / DD, d = i % DD;
    float v = cls_tok[d] + pos[d];
    tokens[(size_t)b * SQ * DD + d] = v;
    float ps = v, ps2 = v * v;
    const int w = threadIdx.x >> 6, l = threadIdx.x & 63;
#pragma unroll
    for (int off = 1; off < 64; off <<= 1) {
        ps  += __shfl_xor(ps,  off);
        ps2 += __shfl_xor(ps2, off);
    }
    if (l == 0) { red[w*2] = ps; red[w*2+1] = ps2; }
    __syncthreads();
    if (threadIdx.x == 0) {
        cpart[blockIdx.x*2]     = red[0] + red[2] + red[4] + red[6];
        cpart[blockIdx.x*2 + 1] = red[1] + red[3] + red[5] + red[7];
    }
}

// ---------------- f32 -> bf16 bulk convert (8 elems/thread) ----------------
__global__ __launch_bounds__(256) void conv_bf16_kernel(const float* __restrict__ in,
        u16* __restrict__ out, int n8) {
    int i = blockIdx.x * blockDim.x + threadIdx.x;
    if (i >= n8) return;
    float4 a = ((const float4*)in)[2*i];
    float4 b = ((const float4*)in)[2*i + 1];
    union { u16 u[8]; uint4 v; } r;
    r.u[0]=f2bf(a.x); r.u[1]=f2bf(a.y); r.u[2]=f2bf(a.z); r.u[3]=f2bf(a.w);
    r.u[4]=f2bf(b.x); r.u[5]=f2bf(b.y); r.u[6]=f2bf(b.z); r.u[7]=f2bf(b.w);
    ((uint4*)out)[i] = r.v;
}

// ---------------- 768x768 transpose + convert: out[n][k] = in[k][n] ----------------
__global__ __launch_bounds__(256) void transpose_bf16_kernel(const float* __restrict__ in,
        u16* __restrict__ out) {
    __shared__ float t[32][33];
    int bn = blockIdx.x * 32, bk = blockIdx.y * 32;
    int tx = threadIdx.x & 31;
#pragma unroll
    for (int r = 0; r < 4; ++r) {
        int kk = (threadIdx.x >> 5) * 4 + r;
        t[kk][tx] = in[(size_t)(bk + kk) * 768 + bn + tx];
    }
    __syncthreads();
#pragma unroll
    for (int r = 0; r < 4; ++r) {
        int nn = (threadIdx.x >> 5) * 4 + r;
        out[(size_t)(bn + nn) * 768 + bk + tx] = f2bf(t[tx][nn]);
    }
}

// ---------------- wqkv pre-transpose: wTg[m][h][e][d] bf16 ----------------
__global__ __launch_bounds__(256) void wqkv_prep(const float* __restrict__ wq,
        const float* __restrict__ wk, const float* __restrict__ wv,
        u16* __restrict__ wTg) {
    __shared__ float t[64][65];
    const int h = blockIdx.x, m = blockIdx.y;
    const float* src = ((m == 0) ? wq : (m == 1) ? wk : wv) + (size_t)h*4096;
    const int tid = threadIdx.x;
#pragma unroll
    for (int i = 0; i < 4; ++i) {
        int d = (tid >> 4) + i*16, e4 = (tid & 15) * 4;
        float4 v = *(const float4*)(src + d*64 + e4);
        t[d][e4+0] = v.x; t[d][e4+1] = v.y; t[d][e4+2] = v.z; t[d][e4+3] = v.w;
    }
    __syncthreads();
    u16* dst = wTg + ((size_t)(m*NHH + h)) * 4096;
#pragma unroll
    for (int i = 0; i < 4; ++i) {
        int e = (tid >> 4) + i*16, d4 = (tid & 15) * 4;
        union { u16 u[4]; uint2 v2; } o;
        o.u[0] = f2bf(t[d4+0][e]); o.u[1] = f2bf(t[d4+1][e]);
        o.u[2] = f2bf(t[d4+2][e]); o.u[3] = f2bf(t[d4+3][e]);
        *(uint2*)(dst + e*64 + d4) = o.v2;
    }
}

// ---------------- MFMA GEMM (embed) + fused LN1 partials ----------------
__global__ __launch_bounds__(256) void gemm_mfma0(const u16* __restrict__ A,
        const u16* __restrict__ BT, const float* __restrict__ bias,
        const float* __restrict__ pos, float* __restrict__ outp, int M,
        float* __restrict__ gpart) {
    __shared__ u16 As[2][4096];   // [128 rows][32 k] bf16
    __shared__ u16 Bs[2][4096];
    __shared__ float redg[16];
    const int tid = threadIdx.x;
    const int wv = tid >> 6, ln = tid & 63;
    const int m0 = blockIdx.x * 128, n0 = blockIdx.y * 128;
    const int wr = wv >> 1, wc = wv & 1;
    const int lrow = ln & 15, lk = ln >> 4;
    const int s0 = m0 / 196;

    f32x4 acc[4][4];
#pragma unroll
    for (int i = 0; i < 4; ++i)
#pragma unroll
        for (int j = 0; j < 4; ++j) acc[i][j] = (f32x4){0.f, 0.f, 0.f, 0.f};

    auto stage = [&](const u16* __restrict__ src, int rowBase, int rowMax,
                     u16* lbase, int k0) {
#pragma unroll
        for (int rep = 0; rep < 2; ++rep) {
            int c = rep * 256 + wv * 64 + ln;
            int row = rowBase + (c >> 2);
            if (row > rowMax) row = rowMax;
            const void* g = (const char*)src + ((size_t)row * 768 + k0) * 2 + ((c & 3) << 4);
            void* l = (char*)lbase + rep * 4096 + wv * 1024;
            __builtin_amdgcn_global_load_lds(
                (const __attribute__((address_space(1))) unsigned int*)g,
                (__attribute__((address_space(3))) unsigned int*)l, 16, 0, 0);
        }
    };

    stage(A,  m0, M - 1,   &As[0][0], 0);
    stage(BT, n0, 767,     &Bs[0][0], 0);
    __syncthreads();

    int cur = 0;
    for (int t = 0; t < 24; ++t) {
        if (t < 23) {
            stage(A,  m0, M - 1, &As[cur ^ 1][0], (t + 1) * 32);
            stage(BT, n0, 767,   &Bs[cur ^ 1][0], (t + 1) * 32);
        }
        bf16x8 af[4], bfr[4];
#pragma unroll
        for (int i = 0; i < 4; ++i) {
            af[i]  = *(const bf16x8*)&As[cur][(wr * 64 + i * 16 + lrow) * 32 + lk * 8];
            bfr[i] = *(const bf16x8*)&Bs[cur][(wc * 64 + i * 16 + lrow) * 32 + lk * 8];
        }
#pragma unroll
        for (int i = 0; i < 4; ++i)
#pragma unroll
            for (int j = 0; j < 4; ++j)
                acc[i][j] = __builtin_amdgcn_mfma_f32_16x16x32_bf16(af[i], bfr[j], acc[i][j], 0, 0, 0);
        __syncthreads();
        cur ^= 1;
    }

    float psA = 0.f, ps2A = 0.f, psB = 0.f, ps2B = 0.f;
#pragma unroll
    for (int i = 0; i < 4; ++i) {
        int gm = m0 + wr * 64 + i * 16 + (ln >> 4) * 4;
#pragma unroll
        for (int r = 0; r < 4; ++r) {
            int gmr = gm + r;
            if (gmr < M) {
                int bsmp = gmr / 196, p = gmr - bsmp * 196;
#pragma unroll
                for (int j = 0; j < 4; ++j) {
                    int n = n0 + wc * 64 + j * 16 + (ln & 15);
                    float v = acc[i][j][r] + bias[n] + pos[(size_t)(p + 1) * 768 + n];
                    outp[(size_t)(gmr + bsmp + 1) * 768 + n] = v;
                    if (bsmp == s0) { psA += v; ps2A += v*v; }
                    else            { psB += v; ps2B += v*v; }
                }
            }
        }
    }
#pragma unroll
    for (int off = 1; off < 64; off <<= 1) {
        psA  += __shfl_xor(psA,  off);  ps2A += __shfl_xor(ps2A, off);
        psB  += __shfl_xor(psB,  off);  ps2B += __shfl_xor(ps2B, off);
    }
    __syncthreads();
    if (ln == 0) {
        redg[wv*4+0] = psA; redg[wv*4+1] = ps2A;
        redg[wv*4+2] = psB; redg[wv*4+3] = ps2B;
    }
    __syncthreads();
    if (tid == 0) {
        float a = redg[0]+redg[4]+redg[8]+redg[12];
        float b = redg[1]+redg[5]+redg[9]+redg[13];
        float c = redg[2]+redg[6]+redg[10]+redg[14];
        float d = redg[3]+redg[7]+redg[11]+redg[15];
        float* gp = gpart + (size_t)(blockIdx.x*6 + blockIdx.y)*4;
        gp[0] = a; gp[1] = b; gp[2] = c; gp[3] = d;
    }
}

// ---------------- LN1 partial reducer: 64 blocks (1/sample), 64 threads ----------------
__global__ __launch_bounds__(64) void reduce_ln1(const float* __restrict__ gpart,
        const float* __restrict__ cpart, float* __restrict__ part) {
    const int b = blockIdx.x, t = threadIdx.x;
    float s1 = 0.f, s2 = 0.f;
    for (int grp = t; grp < 98*6; grp += 64) {
        int bx = grp / 6;
        int sA = (bx * 128) / 196;
        const float* gp = gpart + (size_t)grp*4;
        if (sA == b)     { s1 += gp[0]; s2 += gp[1]; }
        if (sA + 1 == b) { s1 += gp[2]; s2 += gp[3]; }
    }
#pragma unroll
    for (int off = 1; off < 64; off <<= 1) {
        s1 += __shfl_xor(s1, off);
        s2 += __shfl_xor(s2, off);
    }
    if (t == 0) {
#pragma unroll
        for (int i = 0; i < 3; ++i) {
            s1 += cpart[(b*3 + i)*2];
            s2 += cpart[(b*3 + i)*2 + 1];
        }
        part[b*8 + 0] = s1;
        part[b*8 + 1] = s2;
#pragma unroll
        for (int i = 2; i < 8; ++i) part[b*8 + i] = 0.f;
    }
}

// ---------------- QKV via MFMA: block = (64-token chunk, head), 4 waves ----------------
__global__ __launch_bounds__(256) void qkv_mfma(const float* __restrict__ tokens,
        const float* __restrict__ part,
        const float* __restrict__ ln1_g, const float* __restrict__ ln1_b,
        const u16* __restrict__ wTg,
        const float* __restrict__ bq, const float* __restrict__ bk,
        const float* __restrict__ bv,
        u16* __restrict__ qb, u16* __restrict__ kb, u16* __restrict__ vT) {
    __shared__ u16 Xs[64*72];          // 9216 u16; reused as vstage
    __shared__ u16 Ws[3*64*72];        // 13824 u16
    const int c0 = blockIdx.x * 64, h = blockIdx.y;
    const int tid = threadIdx.x;
    const int w = tid >> 6, ln = tid & 63;
    const int lrow = ln & 15, lk = ln >> 4;

    for (int c2 = tid; c2 < 512; c2 += 256) {
        int r = c2 >> 3, q8 = (c2 & 7) * 8;
        int t = c0 + r;
        int bb = t / 197, s = t - bb * 197;
        float S1 = part[bb*8+0] + part[bb*8+2] + part[bb*8+4] + part[bb*8+6];
        float S2 = part[bb*8+1] + part[bb*8+3] + part[bb*8+5] + part[bb*8+7];
        float mu = S1 * (1.f / (float)LNN);
        float rstd = rsqrtf(S2 * (1.f / (float)LNN) - mu*mu + 1e-5f);
        const float* tp = tokens + (size_t)t*768 + h*64 + q8;
        const float* gp = ln1_g + (size_t)s*768 + h*64 + q8;
        const float* bp = ln1_b + (size_t)s*768 + h*64 + q8;
        float4 t0 = *(const float4*)tp, t1 = *(const float4*)(tp+4);
        float4 g0 = *(const float4*)gp, g1 = *(const float4*)(gp+4);
        float4 b0 = *(const float4*)bp, b1 = *(const float4*)(bp+4);
        union { u16 u[8]; uint4 v; } o;
        o.u[0] = f2bf((t0.x - mu)*rstd*g0.x + b0.x);
        o.u[1] = f2bf((t0.y - mu)*rstd*g0.y + b0.y);
        o.u[2] = f2bf((t0.z - mu)*rstd*g0.z + b0.z);
        o.u[3] = f2bf((t0.w - mu)*rstd*g0.w + b0.w);
        o.u[4] = f2bf((t1.x - mu)*rstd*g1.x + b1.x);
        o.u[5] = f2bf((t1.y - mu)*rstd*g1.y + b1.y);
        o.u[6] = f2bf((t1.z - mu)*rstd*g1.z + b1.z);
        o.u[7] = f2bf((t1.w - mu)*rstd*g1.w + b1.w);
        *(uint4*)&Xs[r*72 + q8] = o.v;
    }
    for (int idx = tid; idx < 1536; idx += 256) {
        int m = idx >> 9, rem = idx & 511;
        int e = rem >> 3, c8 = (rem & 7) * 8;
        *(uint4*)&Ws[m*4608 + e*72 + c8] =
            *(const uint4*)(wTg + ((size_t)(m*NHH + h))*4096 + e*64 + c8);
    }
    __syncthreads();

    bf16x8 af[2];
    af[0] = *(const bf16x8*)&Xs[(w*16 + lrow)*72 + lk*8];
    af[1] = *(const bf16x8*)&Xs[(w*16 + lrow)*72 + 32 + lk*8];
    f32x4 acc[3][4];
#pragma unroll
    for (int m = 0; m < 3; ++m)
#pragma unroll
        for (int j = 0; j < 4; ++j) acc[m][j] = (f32x4){0.f,0.f,0.f,0.f};
#pragma unroll
    for (int m = 0; m < 3; ++m)
#pragma unroll
        for (int s = 0; s < 2; ++s)
#pragma unroll
            for (int j = 0; j < 4; ++j) {
                bf16x8 bfr = *(const bf16x8*)&Ws[m*4608 + (j*16 + lrow)*72 + s*32 + lk*8];
                acc[m][j] = __builtin_amdgcn_mfma_f32_16x16x32_bf16(af[s], bfr, acc[m][j], 0, 0, 0);
            }

#pragma unroll
    for (int m = 0; m < 2; ++m) {
        const float* bias = ((m == 0) ? bq : bk) + h*64;
        u16* dst = (m == 0) ? qb : kb;
        float bj[4];
#pragma unroll
        for (int j = 0; j < 4; ++j) bj[j] = bias[j*16 + lrow];
#pragma unroll
        for (int r = 0; r < 4; ++r) {
            int t = c0 + w*16 + lk*4 + r;
            size_t o = (size_t)t*768 + h*64;
#pragma unroll
            for (int j = 0; j < 4; ++j)
                dst[o + j*16 + lrow] = f2bf(acc[m][j][r] + bj[j]);
        }
    }

    {
        float bj[4];
#pragma unroll
        for (int j = 0; j < 4; ++j) bj[j] = bv[h*64 + j*16 + lrow];
        __syncthreads();
        u16* vs = Xs;                          // [64 e][72 tok]
#pragma unroll
        for (int j = 0; j < 4; ++j)
#pragma unroll
            for (int r = 0; r < 4; ++r)
                vs[(j*16 + lrow)*72 + (w*16 + lk*4 + r)] = f2bf(acc[2][j][r] + bj[j]);
        __syncthreads();
        for (int idx = tid; idx < 4096; idx += 256) {
            int d = idx >> 6, tl = idx & 63;
            int t = c0 + tl;
            int bb = t / 197, s = t - bb * 197;
            vT[((size_t)(bb*NHH + h)*64 + d)*SQP + s] = vs[d*72 + tl];
        }
    }
}

// ---------------- attention: Q-in-regs, small LDS, no tokens write ----------------
__global__ __launch_bounds__(256) void attn_mfma(const u16* __restrict__ qb,
        const u16* __restrict__ kb, const u16* __restrict__ vT,
        const float* __restrict__ tokens, float* __restrict__ cls_out,
        float* __restrict__ part2) {
    __shared__ u16 sh[9216];                  // Q-stage[128][72] -> Ks[64][72]|VTs[64][72] -> Osh
    __shared__ float redp[8];

    const int bh = blockIdx.x;
    const int b = bh / NHH, h = bh % NHH;
    const int q0 = blockIdx.y * 128;
    const int tid = threadIdx.x;
    const int w = tid >> 6, l = tid & 63;
    const int g = l >> 4, lq = l & 15;

    {
        const u16* qbase = qb + (size_t)(b*197)*768 + h*64;
#pragma unroll
        for (int it = 0; it < 8; ++it) {
            int idx = tid + it*256;
            int r = idx >> 4, c = idx & 15;
            int gr = q0 + r; if (gr > 196) gr = 196;
            *(uint2*)&sh[r*72 + c*4] = *(const uint2*)(qbase + (size_t)gr*768 + c*4);
        }
    }
    __syncthreads();
    bf16x8 qfr[2][2];
#pragma unroll
    for (int s2 = 0; s2 < 2; ++s2)
#pragma unroll
        for (int s = 0; s < 2; ++s)
            qfr[s2][s] = *(const bf16x8*)&sh[(s2*64 + w*16 + lq)*72 + s*32 + g*8];

    u16* Ks  = sh;
    u16* VTs = sh + 4608;

    f32x4 acco[2][4];
#pragma unroll
    for (int s2 = 0; s2 < 2; ++s2)
#pragma unroll
        for (int i = 0; i < 4; ++i) acco[s2][i] = (f32x4){0.f,0.f,0.f,0.f};
    float S[2] = {0.f, 0.f};

    const int srcA = lq + ((l & 16) ? 32 : 0);
    const u16* krow = kb + (size_t)(b*197)*768 + h*64;
    const u16* vbase = vT + (size_t)bh*64*SQP;

    uint2 kreg[4], vreg[4];
    auto issueKV = [&](int tt) {
        const int t0 = tt * 64;
#pragma unroll
        for (int it = 0; it < 4; ++it) {
            int idx = tid + it*256;
            int r = idx >> 4, c = idx & 15;
            int gt = t0 + r; if (gt > 196) gt = 196;
            kreg[it] = *(const uint2*)(krow + (size_t)gt*768 + c*4);
            vreg[it] = *(const uint2*)(vbase + (size_t)r*SQP + t0 + c*4);
        }
    };
    issueKV(0);

    for (int tt = 0; tt < 4; ++tt) {
        __syncthreads();
#pragma unroll
        for (int it = 0; it < 4; ++it) {
            int idx = tid + it*256;
            int r = idx >> 4, c = idx & 15;
            *(uint2*)&Ks[r*72 + c*4]  = kreg[it];
            *(uint2*)&VTs[r*72 + c*4] = vreg[it];
        }
        if (tt < 3) issueKV(tt + 1);
        __syncthreads();

        const int t0 = tt * 64;
#pragma unroll
        for (int s2 = 0; s2 < 2; ++s2) {
            f32x4 accp[4];
#pragma unroll
            for (int i = 0; i < 4; ++i) accp[i] = (f32x4){0.f,0.f,0.f,0.f};
#pragma unroll
            for (int s = 0; s < 2; ++s) {
#pragma unroll
                for (int tb = 0; tb < 4; ++tb) {
                    bf16x8 kf = *(const bf16x8*)&Ks[(tb*16 + lq)*72 + s*32 + g*8];
                    accp[tb] = __builtin_amdgcn_mfma_f32_16x16x32_bf16(kf, qfr[s2][s], accp[tb], 0, 0, 0);
                }
            }

            unsigned pk[4][2];
#pragma unroll
            for (int tb = 0; tb < 4; ++tb) {
                int tbase = t0 + tb*16 + g*4;
                float p0 = (tbase + 0 < 197) ? __expf(accp[tb][0] * 0.125f) : 0.f;
                float p1 = (tbase + 1 < 197) ? __expf(accp[tb][1] * 0.125f) : 0.f;
                float p2 = (tbase + 2 < 197) ? __expf(accp[tb][2] * 0.125f) : 0.f;
                float p3 = (tbase + 3 < 197) ? __expf(accp[tb][3] * 0.125f) : 0.f;
                S[s2] += (p0 + p1) + (p2 + p3);
                asm("v_cvt_pk_bf16_f32 %0, %1, %2" : "=v"(pk[tb][0]) : "v"(p0), "v"(p1));
                asm("v_cvt_pk_bf16_f32 %0, %1, %2" : "=v"(pk[tb][1]) : "v"(p2), "v"(p3));
            }

#pragma unroll
            for (int s = 0; s < 2; ++s) {
                union { unsigned u[4]; bf16x8 v; } bp;
#pragma unroll
                for (int c = 0; c < 4; ++c) {
                    int src = srcA + ((c >= 2) ? 16 : 0);
                    unsigned v0 = (unsigned)__shfl((int)pk[2*s + 0][c & 1], src);
                    unsigned v1 = (unsigned)__shfl((int)pk[2*s + 1][c & 1], src);
                    bp.u[c] = (l & 32) ? v1 : v0;
                }
#pragma unroll
                for (int dblk = 0; dblk < 4; ++dblk) {
                    bf16x8 vf = *(const bf16x8*)&VTs[(dblk*16 + lq)*72 + s*32 + g*8];
                    acco[s2][dblk] = __builtin_amdgcn_mfma_f32_16x16x32_bf16(vf, bp.v, acco[s2][dblk], 0, 0, 0);
                }
            }
        }
    }

    float invS[2];
#pragma unroll
    for (int s2 = 0; s2 < 2; ++s2) {
        S[s2] += __shfl_xor(S[s2], 16);
        S[s2] += __shfl_xor(S[s2], 32);
        invS[s2] = 1.f / S[s2];
    }

    float* Osh = (float*)sh;                  // 4 waves x [64][18] f32 = 18432 B
    float ps = 0.f, ps2v = 0.f;
    const int q_l = tid >> 2, dc = tid & 3;
#pragma unroll
    for (int s2 = 0; s2 < 2; ++s2) {
        __syncthreads();
        float* os = Osh + w * 1152;
#pragma unroll
        for (int dblk = 0; dblk < 4; ++dblk)
#pragma unroll
            for (int r = 0; r < 4; ++r)
                os[(dblk*16 + g*4 + r)*18 + lq] = acco[s2][dblk][r] * invS[s2];
        __syncthreads();

        const int s_tok = q0 + s2*64 + q_l;
        if (s_tok < 197) {
            const float* osr = Osh + (q_l >> 4)*1152;
            const int ql = q_l & 15;
            const float* trow = tokens + (size_t)(b*197 + s_tok)*768 + h*64 + dc*16;
            float* crow = cls_out + (size_t)b*768 + h*64 + dc*16;
#pragma unroll
            for (int c4 = 0; c4 < 4; ++c4) {
                float4 t = *(const float4*)(trow + c4*4);
                t.x += osr[(dc*16 + c4*4 + 0)*18 + ql];
                t.y += osr[(dc*16 + c4*4 + 1)*18 + ql];
                t.z += osr[(dc*16 + c4*4 + 2)*18 + ql];
                t.w += osr[(dc*16 + c4*4 + 3)*18 + ql];
                ps   += (t.x + t.y) + (t.z + t.w);
                ps2v += (t.x*t.x + t.y*t.y) + (t.z*t.z + t.w*t.w);
                if (s_tok == 0) *(float4*)(crow + c4*4) = t;
            }
        }
    }

#pragma unroll
    for (int off = 1; off < 64; off <<= 1) {
        ps   += __shfl_xor(ps,   off);
        ps2v += __shfl_xor(ps2v, off);
    }
    if (l == 0) { redp[w*2] = ps; redp[w*2 + 1] = ps2v; }
    __syncthreads();
    if (tid == 0) {
        float a = redp[0] + redp[2] + redp[4] + redp[6];
        float c = redp[1] + redp[3] + redp[5] + redp[7];
        int slot = bh*2 + blockIdx.y;
        part2[slot*2]     = a;
        part2[slot*2 + 1] = c;
    }
}

// ---------------- fused ln2(row0) + MLP(row0) + residual: cls rows only ----------------
__global__ __launch_bounds__(256) void mlp_cls(const float* __restrict__ cls_out,
        const float* __restrict__ part2, const float* __restrict__ ln2_g,
        const float* __restrict__ ln2_b, const float* __restrict__ w_enc,
        const float* __restrict__ b_enc, float* __restrict__ mlp_out) {
    __shared__ float y0[768];
    const int b = blockIdx.x, tid = threadIdx.x;
    float s1 = 0.f, s2 = 0.f;
    for (int i = 0; i < 24; ++i) {
        s1 += part2[(b*24 + i)*2];
        s2 += part2[(b*24 + i)*2 + 1];
    }
    float mu = s1 * (1.f / (float)LNN);
    float var = s2 * (1.f / (float)LNN) - mu*mu;
    float rstd = rsqrtf(var + 1e-5f);
    const float* crow = cls_out + (size_t)b * 768;
    for (int d = tid; d < 768; d += 256)
        y0[d] = (crow[d] - mu) * rstd * ln2_g[d] + ln2_b[d];
    __syncthreads();
    const int n = blockIdx.y * 256 + tid;                 // grid.y = 3 -> n < 768
    float acc = b_enc[n];
#pragma unroll 8
    for (int k = 0; k < 768; ++k) acc += y0[k] * w_enc[(size_t)k*768 + n];
    mlp_out[(size_t)b*768 + n] = crow[n] + fmaxf(acc, 0.f);
}

// ---------------- head: k-split, 4-sample-batched logits partials ----------------
// grid (16 b-groups, 4 o-tiles, 8 k-slices); each thread: 4 accumulators, 96-k loop.
__global__ __launch_bounds__(256) void logits_kernel(const float* __restrict__ xin,
        const float* __restrict__ w_head, float* __restrict__ lpart) {
    __shared__ float xr[4][96];
    const int bg = blockIdx.x;                // 16 -> samples 4bg..4bg+3
    const int o  = blockIdx.y * 256 + threadIdx.x;
    const int ks = blockIdx.z;                // 8 -> k0 = 96*ks
    const int k0 = ks * 96;
    if (threadIdx.x < 96) {
#pragma unroll
        for (int i = 0; i < 4; ++i)
            xr[i][threadIdx.x] = xin[(size_t)(bg*4 + i)*768 + k0 + threadIdx.x];
    }
    __syncthreads();
    if (o < NOUT) {
        float a0 = 0.f, a1 = 0.f, a2 = 0.f, a3 = 0.f;
#pragma unroll 8
        for (int k = 0; k < 96; ++k) {
            float wv = w_head[(size_t)(k0 + k)*NOUT + o];
            a0 += xr[0][k] * wv;
            a1 += xr[1][k] * wv;
            a2 += xr[2][k] * wv;
            a3 += xr[3][k] * wv;
        }
        lpart[((size_t)(bg*4 + 0)*8 + ks)*NOUT + o] = a0;
        lpart[((size_t)(bg*4 + 1)*8 + ks)*NOUT + o] = a1;
        lpart[((size_t)(bg*4 + 2)*8 + ks)*NOUT + o] = a2;
        lpart[((size_t)(bg*4 + 3)*8 + ks)*NOUT + o] = a3;
    }
}

__global__ __launch_bounds__(256) void softmax_kernel(const float* __restrict__ lpart,
        const float* __restrict__ b_head, float* __restrict__ outp) {
    __shared__ float red[8];
    const int b = blockIdx.x, tid = threadIdx.x;
    const int w = tid >> 6, l = tid & 63;
    float v[4];
    float mx = -1e30f;
#pragma unroll
    for (int i = 0; i < 4; ++i) {
        int t = tid + i*256;
        if (t < NOUT) {
            float a = b_head[t];
#pragma unroll
            for (int ks = 0; ks < 8; ++ks)
                a += lpart[((size_t)b*8 + ks)*NOUT + t];
            v[i] = a;
        } else v[i] = -1e30f;
        mx = fmaxf(mx, v[i]);
    }
    for (int off = 32; off; off >>= 1) mx = fmaxf(mx, __shfl_xor(mx, off));
    if (l == 0) red[w] = mx;
    __syncthreads();
    if (tid == 0) red[4] = fmaxf(fmaxf(red[0], red[1]), fmaxf(red[2], red[3]));
    __syncthreads();
    const float m = red[4];
    float s = 0.f;
#pragma unroll
    for (int i = 0; i < 4; ++i) { v[i] = __expf(v[i] - m); s += v[i]; }
    for (int off = 32; off; off >>= 1) s += __shfl_xor(s, off);
    if (l == 0) red[w] = s;
    __syncthreads();
    if (tid == 0) red[5] = red[0] + red[1] + red[2] + red[3];
    __syncthreads();
    const float inv = 1.f / red[5];
#pragma unroll
    for (int i = 0; i < 4; ++i) {
        int t = tid + i*256;
        if (t < NOUT) outp[(size_t)b*NOUT + t] = v[i] * inv;
    }
}

// ---------------- launch ----------------
extern "C" void kernel_launch(void* const* d_in, const int* in_sizes, int n_in,
                              void* d_out, int out_size, void* d_ws, size_t ws_size,
                              hipStream_t stream) {
    (void)in_sizes; (void)n_in; (void)out_size; (void)ws_size;
    const float* images = (const float*)d_in[0];
    const float* w_map  = (const float*)d_in[1];
    const float* b_map  = (const float*)d_in[2];
    const float* cls_tok= (const float*)d_in[3];
    const float* ln1_g  = (const float*)d_in[4];
    const float* ln1_b  = (const float*)d_in[5];
    const float* wq     = (const float*)d_in[6];
    const float* bq     = (const float*)d_in[7];
    const float* wk     = (const float*)d_in[8];
    const float* bk     = (const float*)d_in[9];
    const float* wv     = (const float*)d_in[10];
    const float* bv     = (const float*)d_in[11];
    const float* ln2_g  = (const float*)d_in[12];
    const float* ln2_b  = (const float*)d_in[13];
    const float* w_enc  = (const float*)d_in[14];
    const float* b_enc  = (const float*)d_in[15];
    const float* w_head = (const float*)d_in[16];
    const float* b_head = (const float*)d_in[17];
    float* out = (float*)d_out;
    float* ws = (float*)d_ws;

    float* pos    = ws;                     // 151296
    float* tokens = pos + 151296;           // 9682944 f32 (pre-attn residual, read-only in attn)
    float* x      = tokens + 9682944;       // spare (layout stability)
    float* q      = x + 9682944;            // imb overlay, then qb
    float* kk     = q + 9682944;            // wt(w_map) overlay, then kb
    float* vv     = kk + 9682944;           // vT bf16 [768][64][256]
    float* part   = vv + 9682944;           // 512 (ln1 stats, reduced)
    float* part2  = part + 512;             // 3072 (ln2 per-(b,h,qhalf) partials)
    float* mlp_o  = part2 + 3072;           // 49152 (final cls rows, f32)
    float* lpart  = mlp_o + 49152;          // 512000 (logit k-split partials)
    float* wqkvT  = lpart + 512000;         // 73728 f32-slots = 147456 u16 bf16
    float* gpart  = wqkvT + 73728;          // 2352 (gemm0 LN1 partials)
    float* cpart  = gpart + 2352;           // 384 (cls LN1 partials)
    float* cls_o  = cpart + 384;            // 49152 (post-attn cls rows, f32)

    u16* imb = (u16*)q;
    u16* wt  = (u16*)kk;
    u16* qbp = (u16*)q;
    u16* kbp = (u16*)kk;
    u16* vTp = (u16*)vv;
    u16* wTg = (u16*)wqkvT;

    pos_emb_kernel<<<(SQ*DD + 255)/256, 256, 0, stream>>>(pos);
    cls_kernel<<<BB_*DD/256, 256, 0, stream>>>(cls_tok, pos, tokens, cpart);
    conv_bf16_kernel<<<(MPATCH*768/8 + 255)/256, 256, 0, stream>>>(images, imb, MPATCH*768/8);
    transpose_bf16_kernel<<<dim3(24, 24), 256, 0, stream>>>(w_map, wt);
    wqkv_prep<<<dim3(NHH, 3), 256, 0, stream>>>(wq, wk, wv, wTg);
    gemm_mfma0<<<dim3(98, 6), 256, 0, stream>>>(imb, wt, b_map, pos, tokens, MPATCH, gpart);
    reduce_ln1<<<BB_, 64, 0, stream>>>(gpart, cpart, part);
    qkv_mfma<<<dim3(197, NHH), 256, 0, stream>>>(tokens, part, ln1_g, ln1_b, wTg,
                                                 bq, bk, bv, qbp, kbp, vTp);
    attn_mfma<<<dim3(BB_*NHH, 2), 256, 0, stream>>>(qbp, kbp, vTp, tokens, cls_o, part2);
    mlp_cls<<<dim3(BB_, 3), 256, 0, stream>>>(cls_o, part2, ln2_g, ln2_b, w_enc, b_enc, mlp_o);
    logits_kernel<<<dim3(16, 4, 8), 256, 0, stream>>>(mlp_o, w_head, lpart);
    softmax_kernel<<<BB_, 256, 0, stream>>>(lpart, b_head, out);
}

// Round 13
// 168.392 us; speedup vs baseline: 1.6154x; 1.1652x over previous
//
#include <hip/hip_runtime.h>
#include <math.h>

// ---------------- dims ----------------
#define SQ 197           // tokens
#define DD 768           // hidden
#define NHH 12
#define DHH 64
#define BB_ 64           // batch
#define MTOK (BB_*SQ)    // 12608
#define MPATCH (BB_*196) // 12544
#define NOUT 1000
#define LNN (SQ*DD)      // 151296 elems per sample
#define SQP 256          // padded seq for vT

typedef unsigned short u16;
typedef __attribute__((ext_vector_type(8))) short bf16x8;
typedef __attribute__((ext_vector_type(4))) float f32x4;

__device__ __forceinline__ u16 f2bf(float x) {      // RNE f32->bf16
    unsigned u = __float_as_uint(x);
    u = (u + 0x7FFF + ((u >> 16) & 1)) >> 16;
    return (u16)u;
}

// ---------------- pos emb (f64 for safety, tiny) ----------------
__global__ void pos_emb_kernel(float* __restrict__ pos) {
    int i = blockIdx.x * blockDim.x + threadIdx.x;
    if (i >= SQ * DD) return;
    int s = i / DD, d = i % DD;
    double e = (double)(d & ~1) / (double)DD;
    double ang = (double)s * pow(10000.0, -e);
    pos[i] = (d & 1) ? (float)cos(ang) : (float)sin(ang);
}

// ---------------- cls token row + LN1 partials ----------------
__global__ __launch_bounds__(256) void cls_kernel(const float* __restrict__ cls_tok,
                           const float* __restrict__ pos,
                           float* __restrict__ tokens, float* __restrict__ cpart) {
    __shared__ float red[8];
    const int i = blockIdx.x * 256 + threadIdx.x;   // 192 blocks, 3 per sample
    const int b = i / DD, d = i % DD;
    float v = cls_tok[d] + pos[d];
    tokens[(size_t)b * SQ * DD + d] = v;
    float ps = v, ps2 = v * v;
    const int w = threadIdx.x >> 6, l = threadIdx.x & 63;
#pragma unroll
    for (int off = 1; off < 64; off <<= 1) {
        ps  += __shfl_xor(ps,  off);
        ps2 += __shfl_xor(ps2, off);
    }
    if (l == 0) { red[w*2] = ps; red[w*2+1] = ps2; }
    __syncthreads();
    if (threadIdx.x == 0) {
        cpart[blockIdx.x*2]     = red[0] + red[2] + red[4] + red[6];
        cpart[blockIdx.x*2 + 1] = red[1] + red[3] + red[5] + red[7];
    }
}

// ---------------- f32 -> bf16 bulk convert (8 elems/thread) ----------------
__global__ __launch_bounds__(256) void conv_bf16_kernel(const float* __restrict__ in,
        u16* __restrict__ out, int n8) {
    int i = blockIdx.x * blockDim.x + threadIdx.x;
    if (i >= n8) return;
    float4 a = ((const float4*)in)[2*i];
    float4 b = ((const float4*)in)[2*i + 1];
    union { u16 u[8]; uint4 v; } r;
    r.u[0]=f2bf(a.x); r.u[1]=f2bf(a.y); r.u[2]=f2bf(a.z); r.u[3]=f2bf(a.w);
    r.u[4]=f2bf(b.x); r.u[5]=f2bf(b.y); r.u[6]=f2bf(b.z); r.u[7]=f2bf(b.w);
    ((uint4*)out)[i] = r.v;
}

// ---------------- 768x768 transpose + convert: out[n][k] = in[k][n] ----------------
__global__ __launch_bounds__(256) void transpose_bf16_kernel(const float* __restrict__ in,
        u16* __restrict__ out) {
    __shared__ float t[32][33];
    int bn = blockIdx.x * 32, bk = blockIdx.y * 32;
    int tx = threadIdx.x & 31;
#pragma unroll
    for (int r = 0; r < 4; ++r) {
        int kk = (threadIdx.x >> 5) * 4 + r;
        t[kk][tx] = in[(size_t)(bk + kk) * 768 + bn + tx];
    }
    __syncthreads();
#pragma unroll
    for (int r = 0; r < 4; ++r) {
        int nn = (threadIdx.x >> 5) * 4 + r;
        out[(size_t)(bn + nn) * 768 + bk + tx] = f2bf(t[tx][nn]);
    }
}

// ---------------- wqkv pre-transpose: wTg[m][h][e][d] bf16 ----------------
__global__ __launch_bounds__(256) void wqkv_prep(const float* __restrict__ wq,
        const float* __restrict__ wk, const float* __restrict__ wv,
        u16* __restrict__ wTg) {
    __shared__ float t[64][65];
    const int h = blockIdx.x, m = blockIdx.y;
    const float* src = ((m == 0) ? wq : (m == 1) ? wk : wv) + (size_t)h*4096;
    const int tid = threadIdx.x;
#pragma unroll
    for (int i = 0; i < 4; ++i) {
        int d = (tid >> 4) + i*16, e4 = (tid & 15) * 4;
        float4 v = *(const float4*)(src + d*64 + e4);
        t[d][e4+0] = v.x; t[d][e4+1] = v.y; t[d][e4+2] = v.z; t[d][e4+3] = v.w;
    }
    __syncthreads();
    u16* dst = wTg + ((size_t)(m*NHH + h)) * 4096;
#pragma unroll
    for (int i = 0; i < 4; ++i) {
        int e = (tid >> 4) + i*16, d4 = (tid & 15) * 4;
        union { u16 u[4]; uint2 v2; } o;
        o.u[0] = f2bf(t[d4+0][e]); o.u[1] = f2bf(t[d4+1][e]);
        o.u[2] = f2bf(t[d4+2][e]); o.u[3] = f2bf(t[d4+3][e]);
        *(uint2*)(dst + e*64 + d4) = o.v2;
    }
}

// ---------------- MFMA GEMM (embed) + fused LN1 partials ----------------
__global__ __launch_bounds__(256) void gemm_mfma0(const u16* __restrict__ A,
        const u16* __restrict__ BT, const float* __restrict__ bias,
        const float* __restrict__ pos, float* __restrict__ outp, int M,
        float* __restrict__ gpart) {
    __shared__ u16 As[2][4096];   // [128 rows][32 k] bf16
    __shared__ u16 Bs[2][4096];
    __shared__ float redg[16];
    const int tid = threadIdx.x;
    const int wv = tid >> 6, ln = tid & 63;
    const int m0 = blockIdx.x * 128, n0 = blockIdx.y * 128;
    const int wr = wv >> 1, wc = wv & 1;
    const int lrow = ln & 15, lk = ln >> 4;
    const int s0 = m0 / 196;

    f32x4 acc[4][4];
#pragma unroll
    for (int i = 0; i < 4; ++i)
#pragma unroll
        for (int j = 0; j < 4; ++j) acc[i][j] = (f32x4){0.f, 0.f, 0.f, 0.f};

    auto stage = [&](const u16* __restrict__ src, int rowBase, int rowMax,
                     u16* lbase, int k0) {
#pragma unroll
        for (int rep = 0; rep < 2; ++rep) {
            int c = rep * 256 + wv * 64 + ln;
            int row = rowBase + (c >> 2);
            if (row > rowMax) row = rowMax;
            const void* g = (const char*)src + ((size_t)row * 768 + k0) * 2 + ((c & 3) << 4);
            void* l = (char*)lbase + rep * 4096 + wv * 1024;
            __builtin_amdgcn_global_load_lds(
                (const __attribute__((address_space(1))) unsigned int*)g,
                (__attribute__((address_space(3))) unsigned int*)l, 16, 0, 0);
        }
    };

    stage(A,  m0, M - 1,   &As[0][0], 0);
    stage(BT, n0, 767,     &Bs[0][0], 0);
    __syncthreads();

    int cur = 0;
    for (int t = 0; t < 24; ++t) {
        if (t < 23) {
            stage(A,  m0, M - 1, &As[cur ^ 1][0], (t + 1) * 32);
            stage(BT, n0, 767,   &Bs[cur ^ 1][0], (t + 1) * 32);
        }
        bf16x8 af[4], bfr[4];
#pragma unroll
        for (int i = 0; i < 4; ++i) {
            af[i]  = *(const bf16x8*)&As[cur][(wr * 64 + i * 16 + lrow) * 32 + lk * 8];
            bfr[i] = *(const bf16x8*)&Bs[cur][(wc * 64 + i * 16 + lrow) * 32 + lk * 8];
        }
#pragma unroll
        for (int i = 0; i < 4; ++i)
#pragma unroll
            for (int j = 0; j < 4; ++j)
                acc[i][j] = __builtin_amdgcn_mfma_f32_16x16x32_bf16(af[i], bfr[j], acc[i][j], 0, 0, 0);
        __syncthreads();
        cur ^= 1;
    }

    float psA = 0.f, ps2A = 0.f, psB = 0.f, ps2B = 0.f;
#pragma unroll
    for (int i = 0; i < 4; ++i) {
        int gm = m0 + wr * 64 + i * 16 + (ln >> 4) * 4;
#pragma unroll
        for (int r = 0; r < 4; ++r) {
            int gmr = gm + r;
            if (gmr < M) {
                int bsmp = gmr / 196, p = gmr - bsmp * 196;
#pragma unroll
                for (int j = 0; j < 4; ++j) {
                    int n = n0 + wc * 64 + j * 16 + (ln & 15);
                    float v = acc[i][j][r] + bias[n] + pos[(size_t)(p + 1) * 768 + n];
                    outp[(size_t)(gmr + bsmp + 1) * 768 + n] = v;
                    if (bsmp == s0) { psA += v; ps2A += v*v; }
                    else            { psB += v; ps2B += v*v; }
                }
            }
        }
    }
#pragma unroll
    for (int off = 1; off < 64; off <<= 1) {
        psA  += __shfl_xor(psA,  off);  ps2A += __shfl_xor(ps2A, off);
        psB  += __shfl_xor(psB,  off);  ps2B += __shfl_xor(ps2B, off);
    }
    __syncthreads();
    if (ln == 0) {
        redg[wv*4+0] = psA; redg[wv*4+1] = ps2A;
        redg[wv*4+2] = psB; redg[wv*4+3] = ps2B;
    }
    __syncthreads();
    if (tid == 0) {
        float a = redg[0]+redg[4]+redg[8]+redg[12];
        float b = redg[1]+redg[5]+redg[9]+redg[13];
        float c = redg[2]+redg[6]+redg[10]+redg[14];
        float d = redg[3]+redg[7]+redg[11]+redg[15];
        float* gp = gpart + (size_t)(blockIdx.x*6 + blockIdx.y)*4;
        gp[0] = a; gp[1] = b; gp[2] = c; gp[3] = d;
    }
}

// ---------------- LN1 partial reducer: 64 blocks (1/sample), 64 threads ----------------
__global__ __launch_bounds__(64) void reduce_ln1(const float* __restrict__ gpart,
        const float* __restrict__ cpart, float* __restrict__ part) {
    const int b = blockIdx.x, t = threadIdx.x;
    float s1 = 0.f, s2 = 0.f;
    for (int grp = t; grp < 98*6; grp += 64) {
        int bx = grp / 6;
        int sA = (bx * 128) / 196;
        const float* gp = gpart + (size_t)grp*4;
        if (sA == b)     { s1 += gp[0]; s2 += gp[1]; }
        if (sA + 1 == b) { s1 += gp[2]; s2 += gp[3]; }
    }
#pragma unroll
    for (int off = 1; off < 64; off <<= 1) {
        s1 += __shfl_xor(s1, off);
        s2 += __shfl_xor(s2, off);
    }
    if (t == 0) {
#pragma unroll
        for (int i = 0; i < 3; ++i) {
            s1 += cpart[(b*3 + i)*2];
            s2 += cpart[(b*3 + i)*2 + 1];
        }
        part[b*8 + 0] = s1;
        part[b*8 + 1] = s2;
#pragma unroll
        for (int i = 2; i < 8; ++i) part[b*8 + i] = 0.f;
    }
}

// ---------------- QKV via MFMA: block = (64-token chunk, head), 4 waves ----------------
__global__ __launch_bounds__(256) void qkv_mfma(const float* __restrict__ tokens,
        const float* __restrict__ part,
        const float* __restrict__ ln1_g, const float* __restrict__ ln1_b,
        const u16* __restrict__ wTg,
        const float* __restrict__ bq, const float* __restrict__ bk,
        const float* __restrict__ bv,
        u16* __restrict__ qb, u16* __restrict__ kb, u16* __restrict__ vT) {
    __shared__ u16 Xs[64*72];          // 9216 u16; reused as vstage
    __shared__ u16 Ws[3*64*72];        // 13824 u16
    const int c0 = blockIdx.x * 64, h = blockIdx.y;
    const int tid = threadIdx.x;
    const int w = tid >> 6, ln = tid & 63;
    const int lrow = ln & 15, lk = ln >> 4;

    for (int c2 = tid; c2 < 512; c2 += 256) {
        int r = c2 >> 3, q8 = (c2 & 7) * 8;
        int t = c0 + r;
        int bb = t / 197, s = t - bb * 197;
        float S1 = part[bb*8+0] + part[bb*8+2] + part[bb*8+4] + part[bb*8+6];
        float S2 = part[bb*8+1] + part[bb*8+3] + part[bb*8+5] + part[bb*8+7];
        float mu = S1 * (1.f / (float)LNN);
        float rstd = rsqrtf(S2 * (1.f / (float)LNN) - mu*mu + 1e-5f);
        const float* tp = tokens + (size_t)t*768 + h*64 + q8;
        const float* gp = ln1_g + (size_t)s*768 + h*64 + q8;
        const float* bp = ln1_b + (size_t)s*768 + h*64 + q8;
        float4 t0 = *(const float4*)tp, t1 = *(const float4*)(tp+4);
        float4 g0 = *(const float4*)gp, g1 = *(const float4*)(gp+4);
        float4 b0 = *(const float4*)bp, b1 = *(const float4*)(bp+4);
        union { u16 u[8]; uint4 v; } o;
        o.u[0] = f2bf((t0.x - mu)*rstd*g0.x + b0.x);
        o.u[1] = f2bf((t0.y - mu)*rstd*g0.y + b0.y);
        o.u[2] = f2bf((t0.z - mu)*rstd*g0.z + b0.z);
        o.u[3] = f2bf((t0.w - mu)*rstd*g0.w + b0.w);
        o.u[4] = f2bf((t1.x - mu)*rstd*g1.x + b1.x);
        o.u[5] = f2bf((t1.y - mu)*rstd*g1.y + b1.y);
        o.u[6] = f2bf((t1.z - mu)*rstd*g1.z + b1.z);
        o.u[7] = f2bf((t1.w - mu)*rstd*g1.w + b1.w);
        *(uint4*)&Xs[r*72 + q8] = o.v;
    }
    for (int idx = tid; idx < 1536; idx += 256) {
        int m = idx >> 9, rem = idx & 511;
        int e = rem >> 3, c8 = (rem & 7) * 8;
        *(uint4*)&Ws[m*4608 + e*72 + c8] =
            *(const uint4*)(wTg + ((size_t)(m*NHH + h))*4096 + e*64 + c8);
    }
    __syncthreads();

    bf16x8 af[2];
    af[0] = *(const bf16x8*)&Xs[(w*16 + lrow)*72 + lk*8];
    af[1] = *(const bf16x8*)&Xs[(w*16 + lrow)*72 + 32 + lk*8];
    f32x4 acc[3][4];
#pragma unroll
    for (int m = 0; m < 3; ++m)
#pragma unroll
        for (int j = 0; j < 4; ++j) acc[m][j] = (f32x4){0.f,0.f,0.f,0.f};
#pragma unroll
    for (int m = 0; m < 3; ++m)
#pragma unroll
        for (int s = 0; s < 2; ++s)
#pragma unroll
            for (int j = 0; j < 4; ++j) {
                bf16x8 bfr = *(const bf16x8*)&Ws[m*4608 + (j*16 + lrow)*72 + s*32 + lk*8];
                acc[m][j] = __builtin_amdgcn_mfma_f32_16x16x32_bf16(af[s], bfr, acc[m][j], 0, 0, 0);
            }

#pragma unroll
    for (int m = 0; m < 2; ++m) {
        const float* bias = ((m == 0) ? bq : bk) + h*64;
        u16* dst = (m == 0) ? qb : kb;
        float bj[4];
#pragma unroll
        for (int j = 0; j < 4; ++j) bj[j] = bias[j*16 + lrow];
#pragma unroll
        for (int r = 0; r < 4; ++r) {
            int t = c0 + w*16 + lk*4 + r;
            size_t o = (size_t)t*768 + h*64;
#pragma unroll
            for (int j = 0; j < 4; ++j)
                dst[o + j*16 + lrow] = f2bf(acc[m][j][r] + bj[j]);
        }
    }

    {
        float bj[4];
#pragma unroll
        for (int j = 0; j < 4; ++j) bj[j] = bv[h*64 + j*16 + lrow];
        __syncthreads();
        u16* vs = Xs;                          // [64 e][72 tok]
#pragma unroll
        for (int j = 0; j < 4; ++j)
#pragma unroll
            for (int r = 0; r < 4; ++r)
                vs[(j*16 + lrow)*72 + (w*16 + lk*4 + r)] = f2bf(acc[2][j][r] + bj[j]);
        __syncthreads();
        for (int idx = tid; idx < 4096; idx += 256) {
            int d = idx >> 6, tl = idx & 63;
            int t = c0 + tl;
            int bb = t / 197, s = t - bb * 197;
            vT[((size_t)(bb*NHH + h)*64 + d)*SQP + s] = vs[d*72 + tl];
        }
    }
}

// ---------------- attention: Q-in-regs, small LDS, no tokens write ----------------
__global__ __launch_bounds__(256) void attn_mfma(const u16* __restrict__ qb,
        const u16* __restrict__ kb, const u16* __restrict__ vT,
        const float* __restrict__ tokens, float* __restrict__ cls_out,
        float* __restrict__ part2) {
    __shared__ u16 sh[9216];                  // Q-stage[128][72] -> Ks[64][72]|VTs[64][72] -> Osh
    __shared__ float redp[8];

    const int bh = blockIdx.x;
    const int b = bh / NHH, h = bh % NHH;
    const int q0 = blockIdx.y * 128;
    const int tid = threadIdx.x;
    const int w = tid >> 6, l = tid & 63;
    const int g = l >> 4, lq = l & 15;

    {
        const u16* qbase = qb + (size_t)(b*197)*768 + h*64;
#pragma unroll
        for (int it = 0; it < 8; ++it) {
            int idx = tid + it*256;
            int r = idx >> 4, c = idx & 15;
            int gr = q0 + r; if (gr > 196) gr = 196;
            *(uint2*)&sh[r*72 + c*4] = *(const uint2*)(qbase + (size_t)gr*768 + c*4);
        }
    }
    __syncthreads();
    bf16x8 qfr[2][2];
#pragma unroll
    for (int s2 = 0; s2 < 2; ++s2)
#pragma unroll
        for (int s = 0; s < 2; ++s)
            qfr[s2][s] = *(const bf16x8*)&sh[(s2*64 + w*16 + lq)*72 + s*32 + g*8];

    u16* Ks  = sh;
    u16* VTs = sh + 4608;

    f32x4 acco[2][4];
#pragma unroll
    for (int s2 = 0; s2 < 2; ++s2)
#pragma unroll
        for (int i = 0; i < 4; ++i) acco[s2][i] = (f32x4){0.f,0.f,0.f,0.f};
    float S[2] = {0.f, 0.f};

    const int srcA = lq + ((l & 16) ? 32 : 0);
    const u16* krow = kb + (size_t)(b*197)*768 + h*64;
    const u16* vbase = vT + (size_t)bh*64*SQP;

    uint2 kreg[4], vreg[4];
    auto issueKV = [&](int tt) {
        const int t0 = tt * 64;
#pragma unroll
        for (int it = 0; it < 4; ++it) {
            int idx = tid + it*256;
            int r = idx >> 4, c = idx & 15;
            int gt = t0 + r; if (gt > 196) gt = 196;
            kreg[it] = *(const uint2*)(krow + (size_t)gt*768 + c*4);
            vreg[it] = *(const uint2*)(vbase + (size_t)r*SQP + t0 + c*4);
        }
    };
    issueKV(0);

    for (int tt = 0; tt < 4; ++tt) {
        __syncthreads();
#pragma unroll
        for (int it = 0; it < 4; ++it) {
            int idx = tid + it*256;
            int r = idx >> 4, c = idx & 15;
            *(uint2*)&Ks[r*72 + c*4]  = kreg[it];
            *(uint2*)&VTs[r*72 + c*4] = vreg[it];
        }
        if (tt < 3) issueKV(tt + 1);
        __syncthreads();

        const int t0 = tt * 64;
#pragma unroll
        for (int s2 = 0; s2 < 2; ++s2) {
            f32x4 accp[4];
#pragma unroll
            for (int i = 0; i < 4; ++i) accp[i] = (f32x4){0.f,0.f,0.f,0.f};
#pragma unroll
            for (int s = 0; s < 2; ++s) {
#pragma unroll
                for (int tb = 0; tb < 4; ++tb) {
                    bf16x8 kf = *(const bf16x8*)&Ks[(tb*16 + lq)*72 + s*32 + g*8];
                    accp[tb] = __builtin_amdgcn_mfma_f32_16x16x32_bf16(kf, qfr[s2][s], accp[tb], 0, 0, 0);
                }
            }

            unsigned pk[4][2];
#pragma unroll
            for (int tb = 0; tb < 4; ++tb) {
                int tbase = t0 + tb*16 + g*4;
                float p0 = (tbase + 0 < 197) ? __expf(accp[tb][0] * 0.125f) : 0.f;
                float p1 = (tbase + 1 < 197) ? __expf(accp[tb][1] * 0.125f) : 0.f;
                float p2 = (tbase + 2 < 197) ? __expf(accp[tb][2] * 0.125f) : 0.f;
                float p3 = (tbase + 3 < 197) ? __expf(accp[tb][3] * 0.125f) : 0.f;
                S[s2] += (p0 + p1) + (p2 + p3);
                asm("v_cvt_pk_bf16_f32 %0, %1, %2" : "=v"(pk[tb][0]) : "v"(p0), "v"(p1));
                asm("v_cvt_pk_bf16_f32 %0, %1, %2" : "=v"(pk[tb][1]) : "v"(p2), "v"(p3));
            }

#pragma unroll
            for (int s = 0; s < 2; ++s) {
                union { unsigned u[4]; bf16x8 v; } bp;
#pragma unroll
                for (int c = 0; c < 4; ++c) {
                    int src = srcA + ((c >= 2) ? 16 : 0);
                    unsigned v0 = (unsigned)__shfl((int)pk[2*s + 0][c & 1], src);
                    unsigned v1 = (unsigned)__shfl((int)pk[2*s + 1][c & 1], src);
                    bp.u[c] = (l & 32) ? v1 : v0;
                }
#pragma unroll
                for (int dblk = 0; dblk < 4; ++dblk) {
                    bf16x8 vf = *(const bf16x8*)&VTs[(dblk*16 + lq)*72 + s*32 + g*8];
                    acco[s2][dblk] = __builtin_amdgcn_mfma_f32_16x16x32_bf16(vf, bp.v, acco[s2][dblk], 0, 0, 0);
                }
            }
        }
    }

    float invS[2];
#pragma unroll
    for (int s2 = 0; s2 < 2; ++s2) {
        S[s2] += __shfl_xor(S[s2], 16);
        S[s2] += __shfl_xor(S[s2], 32);
        invS[s2] = 1.f / S[s2];
    }

    float* Osh = (float*)sh;                  // 4 waves x [64][18] f32 = 18432 B
    float ps = 0.f, ps2v = 0.f;
    const int q_l = tid >> 2, dc = tid & 3;
#pragma unroll
    for (int s2 = 0; s2 < 2; ++s2) {
        __syncthreads();
        float* os = Osh + w * 1152;
#pragma unroll
        for (int dblk = 0; dblk < 4; ++dblk)
#pragma unroll
            for (int r = 0; r < 4; ++r)
                os[(dblk*16 + g*4 + r)*18 + lq] = acco[s2][dblk][r] * invS[s2];
        __syncthreads();

        const int s_tok = q0 + s2*64 + q_l;
        if (s_tok < 197) {
            const float* osr = Osh + (q_l >> 4)*1152;
            const int ql = q_l & 15;
            const float* trow = tokens + (size_t)(b*197 + s_tok)*768 + h*64 + dc*16;
            float* crow = cls_out + (size_t)b*768 + h*64 + dc*16;
#pragma unroll
            for (int c4 = 0; c4 < 4; ++c4) {
                float4 t = *(const float4*)(trow + c4*4);
                t.x += osr[(dc*16 + c4*4 + 0)*18 + ql];
                t.y += osr[(dc*16 + c4*4 + 1)*18 + ql];
                t.z += osr[(dc*16 + c4*4 + 2)*18 + ql];
                t.w += osr[(dc*16 + c4*4 + 3)*18 + ql];
                ps   += (t.x + t.y) + (t.z + t.w);
                ps2v += (t.x*t.x + t.y*t.y) + (t.z*t.z + t.w*t.w);
                if (s_tok == 0) *(float4*)(crow + c4*4) = t;
            }
        }
    }

#pragma unroll
    for (int off = 1; off < 64; off <<= 1) {
        ps   += __shfl_xor(ps,   off);
        ps2v += __shfl_xor(ps2v, off);
    }
    if (l == 0) { redp[w*2] = ps; redp[w*2 + 1] = ps2v; }
    __syncthreads();
    if (tid == 0) {
        float a = redp[0] + redp[2] + redp[4] + redp[6];
        float c = redp[1] + redp[3] + redp[5] + redp[7];
        int slot = bh*2 + blockIdx.y;
        part2[slot*2]     = a;
        part2[slot*2 + 1] = c;
    }
}

// ---------------- MLP(cls) k-split partials: grid (16 bgroups, 3 o-tiles, 8 k-slices) ----------------
__global__ __launch_bounds__(256) void mlp_part(const float* __restrict__ cls_out,
        const float* __restrict__ part2, const float* __restrict__ ln2_g,
        const float* __restrict__ ln2_b, const float* __restrict__ w_enc,
        float* __restrict__ mpart) {
    __shared__ float y0[4][96];
    __shared__ float mu4[4], rs4[4];
    const int bg = blockIdx.x;                // samples 4bg..4bg+3
    const int n  = blockIdx.y * 256 + threadIdx.x;
    const int ks = blockIdx.z;
    const int k0 = ks * 96;
    if (threadIdx.x < 4) {
        int b = bg*4 + threadIdx.x;
        float s1 = 0.f, s2 = 0.f;
        for (int i = 0; i < 24; ++i) {
            s1 += part2[(b*24 + i)*2];
            s2 += part2[(b*24 + i)*2 + 1];
        }
        float mu = s1 * (1.f / (float)LNN);
        float var = s2 * (1.f / (float)LNN) - mu*mu;
        mu4[threadIdx.x] = mu;
        rs4[threadIdx.x] = rsqrtf(var + 1e-5f);
    }
    __syncthreads();
    if (threadIdx.x < 96) {
        int k = k0 + threadIdx.x;
        float gk = ln2_g[k], bk_ = ln2_b[k];
#pragma unroll
        for (int i = 0; i < 4; ++i) {
            float c = cls_out[(size_t)(bg*4 + i)*768 + k];
            y0[i][threadIdx.x] = (c - mu4[i]) * rs4[i] * gk + bk_;
        }
    }
    __syncthreads();
    if (n < 768) {
        float a0 = 0.f, a1 = 0.f, a2 = 0.f, a3 = 0.f;
#pragma unroll 8
        for (int k = 0; k < 96; ++k) {
            float wv = w_enc[(size_t)(k0 + k)*768 + n];
            a0 += y0[0][k] * wv;
            a1 += y0[1][k] * wv;
            a2 += y0[2][k] * wv;
            a3 += y0[3][k] * wv;
        }
        mpart[((size_t)(bg*4 + 0)*8 + ks)*768 + n] = a0;
        mpart[((size_t)(bg*4 + 1)*8 + ks)*768 + n] = a1;
        mpart[((size_t)(bg*4 + 2)*8 + ks)*768 + n] = a2;
        mpart[((size_t)(bg*4 + 3)*8 + ks)*768 + n] = a3;
    }
}

// ---------------- MLP final: sum partials + bias, relu, + residual ----------------
__global__ __launch_bounds__(256) void mlp_fin(const float* __restrict__ mpart,
        const float* __restrict__ b_enc, const float* __restrict__ cls_out,
        float* __restrict__ mlp_out) {
    const int b = blockIdx.x;
    const int n = blockIdx.y * 256 + threadIdx.x;
    if (n >= 768) return;
    float acc = b_enc[n];
#pragma unroll
    for (int ks = 0; ks < 8; ++ks)
        acc += mpart[((size_t)b*8 + ks)*768 + n];
    mlp_out[(size_t)b*768 + n] = cls_out[(size_t)b*768 + n] + fmaxf(acc, 0.f);
}

// ---------------- head: k-split, 4-sample-batched logits partials ----------------
__global__ __launch_bounds__(256) void logits_kernel(const float* __restrict__ xin,
        const float* __restrict__ w_head, float* __restrict__ lpart) {
    __shared__ float xr[4][96];
    const int bg = blockIdx.x;                // 16 -> samples 4bg..4bg+3
    const int o  = blockIdx.y * 256 + threadIdx.x;
    const int ks = blockIdx.z;                // 8 -> k0 = 96*ks
    const int k0 = ks * 96;
    if (threadIdx.x < 96) {
#pragma unroll
        for (int i = 0; i < 4; ++i)
            xr[i][threadIdx.x] = xin[(size_t)(bg*4 + i)*768 + k0 + threadIdx.x];
    }
    __syncthreads();
    if (o < NOUT) {
        float a0 = 0.f, a1 = 0.f, a2 = 0.f, a3 = 0.f;
#pragma unroll 8
        for (int k = 0; k < 96; ++k) {
            float wv = w_head[(size_t)(k0 + k)*NOUT + o];
            a0 += xr[0][k] * wv;
            a1 += xr[1][k] * wv;
            a2 += xr[2][k] * wv;
            a3 += xr[3][k] * wv;
        }
        lpart[((size_t)(bg*4 + 0)*8 + ks)*NOUT + o] = a0;
        lpart[((size_t)(bg*4 + 1)*8 + ks)*NOUT + o] = a1;
        lpart[((size_t)(bg*4 + 2)*8 + ks)*NOUT + o] = a2;
        lpart[((size_t)(bg*4 + 3)*8 + ks)*NOUT + o] = a3;
    }
}

__global__ __launch_bounds__(256) void softmax_kernel(const float* __restrict__ lpart,
        const float* __restrict__ b_head, float* __restrict__ outp) {
    __shared__ float red[8];
    const int b = blockIdx.x, tid = threadIdx.x;
    const int w = tid >> 6, l = tid & 63;
    float v[4];
    float mx = -1e30f;
#pragma unroll
    for (int i = 0; i < 4; ++i) {
        int t = tid + i*256;
        if (t < NOUT) {
            float a = b_head[t];
#pragma unroll
            for (int ks = 0; ks < 8; ++ks)
                a += lpart[((size_t)b*8 + ks)*NOUT + t];
            v[i] = a;
        } else v[i] = -1e30f;
        mx = fmaxf(mx, v[i]);
    }
    for (int off = 32; off; off >>= 1) mx = fmaxf(mx, __shfl_xor(mx, off));
    if (l == 0) red[w] = mx;
    __syncthreads();
    if (tid == 0) red[4] = fmaxf(fmaxf(red[0], red[1]), fmaxf(red[2], red[3]));
    __syncthreads();
    const float m = red[4];
    float s = 0.f;
#pragma unroll
    for (int i = 0; i < 4; ++i) { v[i] = __expf(v[i] - m); s += v[i]; }
    for (int off = 32; off; off >>= 1) s += __shfl_xor(s, off);
    if (l == 0) red[w] = s;
    __syncthreads();
    if (tid == 0) red[5] = red[0] + red[1] + red[2] + red[3];
    __syncthreads();
    const float inv = 1.f / red[5];
#pragma unroll
    for (int i = 0; i < 4; ++i) {
        int t = tid + i*256;
        if (t < NOUT) outp[(size_t)b*NOUT + t] = v[i] * inv;
    }
}

// ---------------- launch ----------------
extern "C" void kernel_launch(void* const* d_in, const int* in_sizes, int n_in,
                              void* d_out, int out_size, void* d_ws, size_t ws_size,
                              hipStream_t stream) {
    (void)in_sizes; (void)n_in; (void)out_size; (void)ws_size;
    const float* images = (const float*)d_in[0];
    const float* w_map  = (const float*)d_in[1];
    const float* b_map  = (const float*)d_in[2];
    const float* cls_tok= (const float*)d_in[3];
    const float* ln1_g  = (const float*)d_in[4];
    const float* ln1_b  = (const float*)d_in[5];
    const float* wq     = (const float*)d_in[6];
    const float* bq     = (const float*)d_in[7];
    const float* wk     = (const float*)d_in[8];
    const float* bk     = (const float*)d_in[9];
    const float* wv     = (const float*)d_in[10];
    const float* bv     = (const float*)d_in[11];
    const float* ln2_g  = (const float*)d_in[12];
    const float* ln2_b  = (const float*)d_in[13];
    const float* w_enc  = (const float*)d_in[14];
    const float* b_enc  = (const float*)d_in[15];
    const float* w_head = (const float*)d_in[16];
    const float* b_head = (const float*)d_in[17];
    float* out = (float*)d_out;
    float* ws = (float*)d_ws;

    float* pos    = ws;                     // 151296
    float* tokens = pos + 151296;           // 9682944 f32 (pre-attn residual, read-only in attn)
    float* x      = tokens + 9682944;       // spare (layout stability)
    float* q      = x + 9682944;            // imb overlay, then qb
    float* kk     = q + 9682944;            // wt(w_map) overlay, then kb
    float* vv     = kk + 9682944;           // vT bf16 [768][64][256]
    float* part   = vv + 9682944;           // 512 (ln1 stats, reduced)
    float* part2  = part + 512;             // 3072 (ln2 per-(b,h,qhalf) partials)
    float* mlp_o  = part2 + 3072;           // 49152 (final cls rows, f32)
    float* lpart  = mlp_o + 49152;          // 512000 (logit k-split partials)
    float* wqkvT  = lpart + 512000;         // 73728 f32-slots = 147456 u16 bf16
    float* gpart  = wqkvT + 73728;          // 2352 (gemm0 LN1 partials)
    float* cpart  = gpart + 2352;           // 384 (cls LN1 partials)
    float* cls_o  = cpart + 384;            // 49152 (post-attn cls rows, f32)
    float* mpart  = cls_o + 49152;          // 393216 (mlp k-split partials)

    u16* imb = (u16*)q;
    u16* wt  = (u16*)kk;
    u16* qbp = (u16*)q;
    u16* kbp = (u16*)kk;
    u16* vTp = (u16*)vv;
    u16* wTg = (u16*)wqkvT;

    pos_emb_kernel<<<(SQ*DD + 255)/256, 256, 0, stream>>>(pos);
    cls_kernel<<<BB_*DD/256, 256, 0, stream>>>(cls_tok, pos, tokens, cpart);
    conv_bf16_kernel<<<(MPATCH*768/8 + 255)/256, 256, 0, stream>>>(images, imb, MPATCH*768/8);
    transpose_bf16_kernel<<<dim3(24, 24), 256, 0, stream>>>(w_map, wt);
    wqkv_prep<<<dim3(NHH, 3), 256, 0, stream>>>(wq, wk, wv, wTg);
    gemm_mfma0<<<dim3(98, 6), 256, 0, stream>>>(imb, wt, b_map, pos, tokens, MPATCH, gpart);
    reduce_ln1<<<BB_, 64, 0, stream>>>(gpart, cpart, part);
    qkv_mfma<<<dim3(197, NHH), 256, 0, stream>>>(tokens, part, ln1_g, ln1_b, wTg,
                                                 bq, bk, bv, qbp, kbp, vTp);
    attn_mfma<<<dim3(BB_*NHH, 2), 256, 0, stream>>>(qbp, kbp, vTp, tokens, cls_o, part2);
    mlp_part<<<dim3(16, 3, 8), 256, 0, stream>>>(cls_o, part2, ln2_g, ln2_b, w_enc, mpart);
    mlp_fin<<<dim3(BB_, 3), 256, 0, stream>>>(mpart, b_enc, cls_o, mlp_o);
    logits_kernel<<<dim3(16, 4, 8), 256, 0, stream>>>(mlp_o, w_head, lpart);
    softmax_kernel<<<BB_, 256, 0, stream>>>(lpart, b_head, out);
}